// Round 2
// baseline (2323.506 us; speedup 1.0000x reference)
//
#include <hip/hip_runtime.h>

#define NFEAT 128
#define NHID 64
#define NOUT 128
#define NHEADS 8
#define ALPHA_SLOPE 0.2f
#define EPS_DENOM 1e-16f

static __device__ __forceinline__ float elu_f(float v) {
  return v > 0.f ? v : __expf(v) - 1.f;
}
static __device__ __forceinline__ float edge_w(float sc) {
  float lr = sc > 0.f ? sc : ALPHA_SLOPE * sc;
  return __expf(-lr);
}

// ---------------- CSR build ----------------
__global__ void k_hist(const int* __restrict__ src, int* __restrict__ counts, int E) {
  int e = blockIdx.x * blockDim.x + threadIdx.x;
  if (e < E) atomicAdd(&counts[src[e]], 1);
}

__global__ void k_scan1(const int* __restrict__ counts, int* __restrict__ rp,
                        int* __restrict__ bsum, int N) {
  __shared__ int sh[1024];
  int tid = threadIdx.x;
  int idx = blockIdx.x * 1024 + tid;
  int v = (idx < N) ? counts[idx] : 0;
  sh[tid] = v;
  __syncthreads();
  for (int off = 1; off < 1024; off <<= 1) {
    int add = (tid >= off) ? sh[tid - off] : 0;
    __syncthreads();
    sh[tid] += add;
    __syncthreads();
  }
  if (idx < N) rp[idx] = sh[tid] - v;      // exclusive within block
  if (tid == 1023) bsum[blockIdx.x] = sh[1023];
}

__global__ void k_scan2(const int* __restrict__ bsum, int* __restrict__ boff, int nb) {
  if (blockIdx.x == 0 && threadIdx.x == 0) {
    int run = 0;
    for (int i = 0; i < nb; ++i) { boff[i] = run; run += bsum[i]; }
  }
}

__global__ void k_scan3(int* __restrict__ rp, int* __restrict__ cursor,
                        const int* __restrict__ boff, int N, int E) {
  int idx = blockIdx.x * 1024 + threadIdx.x;
  if (idx < N) {
    int v = rp[idx] + boff[blockIdx.x];
    rp[idx] = v;
    cursor[idx] = v;
  }
  if (idx == 0) rp[N] = E;
}

__global__ void k_fill(const int* __restrict__ src, const int* __restrict__ dst,
                       int* __restrict__ cursor, int* __restrict__ edge_dst, int E) {
  int e = blockIdx.x * blockDim.x + threadIdx.x;
  if (e < E) {
    int slot = atomicAdd(&cursor[src[e]], 1);
    edge_dst[slot] = dst[e];
  }
}

// ---------------- f32 tiled GEMM: C[M,ncols] (+)= A[M,K] @ B[K,ncols] ----------------
// tile: 128 rows x 64 cols, K-chunks of 64. 256 threads, each 4x8 outputs.
#define GTM 128
#define GTN 64
#define GBK 64

__global__ __launch_bounds__(256) void k_gemm(
    const float* __restrict__ A, const float* __restrict__ B, float* __restrict__ C,
    int M, int K, int lda, int ldb, int ldc, int accum) {
  __shared__ float As[GTM][GBK + 1];   // +1 pad: conflict-free column reads
  __shared__ float Bs[GBK][GTN];
  int t = threadIdx.x;
  int tx = t & 7, ty = t >> 3;
  int rowBase = blockIdx.x * GTM;
  int colBase = blockIdx.y * GTN;
  float acc[4][8];
#pragma unroll
  for (int r = 0; r < 4; ++r)
#pragma unroll
    for (int c = 0; c < 8; ++c) acc[r][c] = 0.f;

  for (int k0 = 0; k0 < K; k0 += GBK) {
#pragma unroll
    for (int i = 0; i < 8; ++i) {          // A tile: 128x64
      int q = t * 4 + i * 1024;
      int r = q >> 6, kk = q & 63;
      int gr = rowBase + r; if (gr > M - 1) gr = M - 1;
      const float4 v = *(const float4*)(A + (size_t)gr * lda + (k0 + kk));
      As[r][kk] = v.x; As[r][kk + 1] = v.y; As[r][kk + 2] = v.z; As[r][kk + 3] = v.w;
    }
#pragma unroll
    for (int i = 0; i < 4; ++i) {          // B tile: 64x64
      int q = t * 4 + i * 1024;
      int kk = q >> 6, c = q & 63;
      *(float4*)&Bs[kk][c] = *(const float4*)(B + (size_t)(k0 + kk) * ldb + (colBase + c));
    }
    __syncthreads();
#pragma unroll 8
    for (int kk = 0; kk < GBK; ++kk) {
      float4 b0 = *(const float4*)&Bs[kk][tx * 8];
      float4 b1 = *(const float4*)&Bs[kk][tx * 8 + 4];
#pragma unroll
      for (int r = 0; r < 4; ++r) {
        float a = As[ty * 4 + r][kk];
        acc[r][0] += a * b0.x; acc[r][1] += a * b0.y;
        acc[r][2] += a * b0.z; acc[r][3] += a * b0.w;
        acc[r][4] += a * b1.x; acc[r][5] += a * b1.y;
        acc[r][6] += a * b1.z; acc[r][7] += a * b1.w;
      }
    }
    __syncthreads();
  }
#pragma unroll
  for (int r = 0; r < 4; ++r) {
    int gr = rowBase + ty * 4 + r;
    if (gr < M) {
      float* cp = C + (size_t)gr * ldc + colBase + tx * 8;
      if (accum) {
        float4 o0 = *(const float4*)cp;
        float4 o1 = *(const float4*)(cp + 4);
        *(float4*)cp = make_float4(o0.x + acc[r][0], o0.y + acc[r][1],
                                   o0.z + acc[r][2], o0.w + acc[r][3]);
        *(float4*)(cp + 4) = make_float4(o1.x + acc[r][4], o1.y + acc[r][5],
                                         o1.z + acc[r][6], o1.w + acc[r][7]);
      } else {
        *(float4*)cp = make_float4(acc[r][0], acc[r][1], acc[r][2], acc[r][3]);
        *(float4*)(cp + 4) = make_float4(acc[r][4], acc[r][5], acc[r][6], acc[r][7]);
      }
    }
  }
}

// ---------------- attention score vectors ----------------
// wave per node: s_src = h . a[:F], s_dst = h . a[F:]
__global__ void k_s1(const float* __restrict__ h1t, const float* __restrict__ a1h,
                     float* __restrict__ ssrc, float* __restrict__ sdst, int N) {
  int wv = (blockIdx.x * blockDim.x + threadIdx.x) >> 6;
  int lane = threadIdx.x & 63;
  if (wv >= N) return;
  float h = h1t[(size_t)wv * 64 + lane];
  float p0 = h * a1h[lane];
  float p1 = h * a1h[64 + lane];
#pragma unroll
  for (int off = 32; off > 0; off >>= 1) {
    p0 += __shfl_xor(p0, off);
    p1 += __shfl_xor(p1, off);
  }
  if (lane == 0) { ssrc[wv] = p0; sdst[wv] = p1; }
}

__global__ void k_s2(const float* __restrict__ h2, const float* __restrict__ a2,
                     float* __restrict__ ssrc, float* __restrict__ sdst, int N) {
  int wv = (blockIdx.x * blockDim.x + threadIdx.x) >> 6;
  int lane = threadIdx.x & 63;
  if (wv >= N) return;
  float x0 = h2[(size_t)wv * 128 + lane];
  float x1 = h2[(size_t)wv * 128 + 64 + lane];
  float p0 = x0 * a2[lane] + x1 * a2[64 + lane];
  float p1 = x0 * a2[128 + lane] + x1 * a2[192 + lane];
#pragma unroll
  for (int off = 32; off > 0; off >>= 1) {
    p0 += __shfl_xor(p0, off);
    p1 += __shfl_xor(p1, off);
  }
  if (lane == 0) { ssrc[wv] = p0; sdst[wv] = p1; }
}

// ---------------- layer-1 aggregation (per head), wave per node, lane = column ----------------
// writes per-head output hout[N,64] (dense, stride 64)
__global__ void k_agg1(const int* __restrict__ rp, const int* __restrict__ edge_dst,
                       const float* __restrict__ h1t, const float* __restrict__ ssrc,
                       const float* __restrict__ sdst, float* __restrict__ hout, int N) {
  int wv = (blockIdx.x * blockDim.x + threadIdx.x) >> 6;
  int lane = threadIdx.x & 63;
  if (wv >= N) return;
  int e0 = rp[wv], e1 = rp[wv + 1];
  float ss = ssrc[wv];
  float acc = 0.f, rsum = 0.f;
  int e = e0;
  for (; e + 4 <= e1; e += 4) {
    int d0 = edge_dst[e], d1 = edge_dst[e + 1], d2 = edge_dst[e + 2], d3 = edge_dst[e + 3];
    float w0 = edge_w(ss + sdst[d0]);
    float w1 = edge_w(ss + sdst[d1]);
    float w2 = edge_w(ss + sdst[d2]);
    float w3 = edge_w(ss + sdst[d3]);
    float v0 = h1t[(size_t)d0 * 64 + lane];
    float v1 = h1t[(size_t)d1 * 64 + lane];
    float v2 = h1t[(size_t)d2 * 64 + lane];
    float v3 = h1t[(size_t)d3 * 64 + lane];
    acc += w0 * v0; acc += w1 * v1; acc += w2 * v2; acc += w3 * v3;
    rsum += w0 + w1 + w2 + w3;
  }
  for (; e < e1; ++e) {
    int d = edge_dst[e];
    float w = edge_w(ss + sdst[d]);
    acc += w * h1t[(size_t)d * 64 + lane];
    rsum += w;
  }
  float hp = acc / (rsum + EPS_DENOM);
  hout[(size_t)wv * 64 + lane] = elu_f(hp);
}

// ---------------- layer-2 aggregation + deg==0 fallback + final ELU ----------------
__global__ void k_agg2(const int* __restrict__ rp, const int* __restrict__ edge_dst,
                       const float* __restrict__ h2, const float* __restrict__ ssrc,
                       const float* __restrict__ sdst, const float* __restrict__ x,
                       float* __restrict__ out, int N) {
  int wv = (blockIdx.x * blockDim.x + threadIdx.x) >> 6;
  int lane = threadIdx.x & 63;
  if (wv >= N) return;
  int e0 = rp[wv], e1 = rp[wv + 1];
  if (e0 == e1) {   // zero out-degree: h row = x row
    out[(size_t)wv * 128 + lane] = elu_f(x[(size_t)wv * 128 + lane]);
    out[(size_t)wv * 128 + 64 + lane] = elu_f(x[(size_t)wv * 128 + 64 + lane]);
    return;
  }
  float ss = ssrc[wv];
  float a0 = 0.f, a1 = 0.f, rsum = 0.f;
  int e = e0;
  for (; e + 2 <= e1; e += 2) {
    int d0 = edge_dst[e], d1 = edge_dst[e + 1];
    float w0 = edge_w(ss + sdst[d0]);
    float w1 = edge_w(ss + sdst[d1]);
    a0 += w0 * h2[(size_t)d0 * 128 + lane];
    a1 += w0 * h2[(size_t)d0 * 128 + 64 + lane];
    a0 += w1 * h2[(size_t)d1 * 128 + lane];
    a1 += w1 * h2[(size_t)d1 * 128 + 64 + lane];
    rsum += w0 + w1;
  }
  for (; e < e1; ++e) {
    int d = edge_dst[e];
    float w = edge_w(ss + sdst[d]);
    a0 += w * h2[(size_t)d * 128 + lane];
    a1 += w * h2[(size_t)d * 128 + 64 + lane];
    rsum += w;
  }
  out[(size_t)wv * 128 + lane] = elu_f(a0 / (rsum + EPS_DENOM));
  out[(size_t)wv * 128 + 64 + lane] = elu_f(a1 / (rsum + EPS_DENOM));
}

extern "C" void kernel_launch(void* const* d_in, const int* in_sizes, int n_in,
                              void* d_out, int out_size, void* d_ws, size_t ws_size,
                              hipStream_t stream) {
  (void)n_in; (void)out_size; (void)ws_size;
  const float* x  = (const float*)d_in[0];
  const int*   ei = (const int*)d_in[1];
  const float* W1 = (const float*)d_in[2];
  const float* a1 = (const float*)d_in[3];
  const float* W2 = (const float*)d_in[4];
  const float* a2 = (const float*)d_in[5];
  float* out = (float*)d_out;
  const int N = in_sizes[0] / NFEAT;
  const int E = in_sizes[1] / 2;
  const int* src  = ei;
  const int* dstv = ei + E;

  // d_out doubles as per-head scratch during the head loop (dead before k_agg2):
  //   h1t  = d_out[0      : N*64)   per-head x@W1
  //   hout = d_out[N*64   : N*128)  per-head aggregated/ELU output
  float* h1t  = out;
  float* hout = out + (size_t)N * NHID;

  // workspace carve-up (~66 MB)
  char* wp = (char*)d_ws;
  size_t off = 0;
  auto mk = [&](size_t bytes) -> void* {
    void* p = wp + off;
    off += (bytes + 255) & ~(size_t)255;
    return p;
  };
  float* h2f    = (float*)mk((size_t)N * NOUT * 4);   // layer-2 accumulator [N,128]
  int*   edge_dst = (int*)mk((size_t)E * 4);
  float* ssrc   = (float*)mk((size_t)N * 4);
  float* sdst   = (float*)mk((size_t)N * 4);
  int*   rp     = (int*)mk((size_t)(N + 1) * 4);
  int*   cursor = (int*)mk((size_t)N * 4);
  int*   counts = (int*)mk((size_t)N * 4);
  int*   bsum   = (int*)mk(4096);
  int*   boff   = (int*)mk(4096);

  // CSR build
  hipMemsetAsync(counts, 0, (size_t)N * 4, stream);
  int eb = (E + 255) / 256;
  int nb = (N + 1023) / 1024;
  k_hist<<<eb, 256, 0, stream>>>(src, counts, E);
  k_scan1<<<nb, 1024, 0, stream>>>(counts, rp, bsum, N);
  k_scan2<<<1, 64, 0, stream>>>(bsum, boff, nb);
  k_scan3<<<nb, 1024, 0, stream>>>(rp, cursor, boff, N, E);
  k_fill<<<eb, 256, 0, stream>>>(src, dstv, cursor, edge_dst, E);

  // layer-2 accumulator must start at zero every call (replays!)
  hipMemsetAsync(h2f, 0, (size_t)N * NOUT * 4, stream);

  int wb = (N + 3) / 4;   // wave-per-node kernels: 4 nodes per 256-thread block
  dim3 g1((N + GTM - 1) / GTM, 1);
  dim3 g2((N + GTM - 1) / GTM, 2);

  // layer 1, per head; fold each head's contribution into h2f (K=64 GEMM, beta=1)
  for (int h = 0; h < NHEADS; ++h) {
    k_gemm<<<g1, 256, 0, stream>>>(x, W1 + (size_t)h * NFEAT * NHID, h1t,
                                   N, NFEAT, NFEAT, NHID, NHID, 0);
    k_s1<<<wb, 256, 0, stream>>>(h1t, a1 + (size_t)h * 2 * NHID, ssrc, sdst, N);
    k_agg1<<<wb, 256, 0, stream>>>(rp, edge_dst, h1t, ssrc, sdst, hout, N);
    k_gemm<<<g2, 256, 0, stream>>>(hout, W2 + (size_t)h * NHID * NOUT, h2f,
                                   N, NHID, NHID, NOUT, NOUT, 1);
  }

  // layer 2 scores + aggregation (reuse ssrc/sdst)
  k_s2<<<wb, 256, 0, stream>>>(h2f, a2, ssrc, sdst, N);
  k_agg2<<<wb, 256, 0, stream>>>(rp, edge_dst, h2f, ssrc, sdst, x, out, N);
}

// Round 3
// 1915.352 us; speedup vs baseline: 1.2131x; 1.2131x over previous
//
#include <hip/hip_runtime.h>

#define NFEAT 128
#define NHID 64
#define NOUT 128
#define NHEADS 8
#define ALPHA_SLOPE 0.2f
#define EPS_DENOM 1e-16f

#define MAXNB 1024      // max buckets (N/128 rounded up must fit)
#define BIN_EPB 12288   // edges per block in binning kernels
#define BIN_CAP 6144    // max pairs per bucket held in LDS (mean 4092, +32 sigma)

static __device__ __forceinline__ float elu_f(float v) {
  return v > 0.f ? v : __expf(v) - 1.f;
}
static __device__ __forceinline__ float edge_w(float sc) {
  float lr = sc > 0.f ? sc : ALPHA_SLOPE * sc;
  return __expf(-lr);
}

// ---------------- CSR build: 2-pass bucketed counting sort ----------------

// coarse bucket histogram (LDS pre-aggregation)
__global__ __launch_bounds__(256) void k_bhist(const int* __restrict__ src,
                                               int* __restrict__ bhist,
                                               int E, int NB, int shift) {
  __shared__ int h[MAXNB];
  int tid = threadIdx.x;
  for (int i = tid; i < NB; i += 256) h[i] = 0;
  __syncthreads();
  int base = blockIdx.x * BIN_EPB;
#pragma unroll 4
  for (int j = 0; j < BIN_EPB / 256; ++j) {
    int e = base + tid + j * 256;
    if (e < E) atomicAdd(&h[src[e] >> shift], 1);
  }
  __syncthreads();
  for (int i = tid; i < NB; i += 256)
    if (h[i]) atomicAdd(&bhist[i], h[i]);
}

// exclusive scan of bucket sizes -> bucket_base[NB+1]; init bucket_cursor; rp[N]=E
__global__ __launch_bounds__(1024) void k_bscan(const int* __restrict__ bhist,
                                                int* __restrict__ bucket_base,
                                                int* __restrict__ bucket_cursor,
                                                int* __restrict__ rp,
                                                int NB, int N, int E) {
  __shared__ int sh[1024];
  int i = threadIdx.x;
  int v = (i < NB) ? bhist[i] : 0;
  sh[i] = v;
  __syncthreads();
  for (int off = 1; off < 1024; off <<= 1) {
    int add = (i >= off) ? sh[i - off] : 0;
    __syncthreads();
    sh[i] += add;
    __syncthreads();
  }
  if (i < NB) {
    int ex = sh[i] - v;
    bucket_base[i] = ex;
    bucket_cursor[i] = ex;
  }
  if (i == 0) {
    bucket_base[NB] = E;
    rp[N] = E;
  }
}

// scatter (src,dst) pairs into bucket-grouped staging, contiguous run per (block,bucket)
__global__ __launch_bounds__(256) void k_binA(const int* __restrict__ src,
                                              const int* __restrict__ dst,
                                              int* __restrict__ bucket_cursor,
                                              int2* __restrict__ staging,
                                              int E, int NB, int shift) {
  __shared__ int h[MAXNB];
  int tid = threadIdx.x;
  for (int i = tid; i < NB; i += 256) h[i] = 0;
  __syncthreads();
  int base = blockIdx.x * BIN_EPB;
#pragma unroll 4
  for (int j = 0; j < BIN_EPB / 256; ++j) {
    int e = base + tid + j * 256;
    if (e < E) atomicAdd(&h[src[e] >> shift], 1);
  }
  __syncthreads();
  for (int i = tid; i < NB; i += 256)
    if (h[i]) h[i] = atomicAdd(&bucket_cursor[i], h[i]);   // h[i] = block's base slot
  __syncthreads();
#pragma unroll 4
  for (int j = 0; j < BIN_EPB / 256; ++j) {
    int e = base + tid + j * 256;
    if (e < E) {
      int s = src[e];
      int slot = atomicAdd(&h[s >> shift], 1);
      staging[slot] = make_int2(s, dst[e]);
    }
  }
}

// per-bucket exact counting sort: emits rp + final CSR edge_dst (coalesced region)
__global__ __launch_bounds__(256) void k_binB(const int2* __restrict__ staging,
                                              const int* __restrict__ bucket_base,
                                              int* __restrict__ rp,
                                              int* __restrict__ edge_dst,
                                              int N, int shift) {
  __shared__ int2 buf[BIN_CAP];
  __shared__ int rcnt[256], rsc[256];
  int tid = threadIdx.x;
  int b = blockIdx.x;
  int lo = bucket_base[b], hi = bucket_base[b + 1];
  int S = hi - lo;
  if (S > BIN_CAP) S = BIN_CAP;   // tripwire (never for this input)
  int R = 1 << shift;             // rows per bucket (<=256)
  int rmask = R - 1;
  for (int i = tid; i < S; i += 256) buf[i] = staging[lo + i];
  if (tid < R) rcnt[tid] = 0;
  __syncthreads();
  for (int i = tid; i < S; i += 256) atomicAdd(&rcnt[buf[i].x & rmask], 1);
  __syncthreads();
  if (tid < R) rsc[tid] = rcnt[tid];
  __syncthreads();
  for (int off = 1; off < 256; off <<= 1) {
    int add = (tid >= off && tid < R) ? rsc[tid - off] : 0;
    __syncthreads();
    if (tid < R) rsc[tid] += add;
    __syncthreads();
  }
  int row0 = b << shift;
  if (tid < R) {
    int ex = rsc[tid] - rcnt[tid];
    rcnt[tid] = ex;                       // becomes the within-bucket cursor
    if (row0 + tid < N) rp[row0 + tid] = lo + ex;
  }
  __syncthreads();
  for (int i = tid; i < S; i += 256) {
    int r = buf[i].x & rmask;
    int k = atomicAdd(&rcnt[r], 1);
    edge_dst[lo + k] = buf[i].y;
  }
}

// ---------------- f32 tiled GEMM: C[M,ncols] (+)= A[M,K] @ B[K,ncols] ----------------
// tile: 128 rows x 64 cols, K-chunks of 64. 256 threads, each 4x8 outputs.
// optional fused epilogue (layer 1): ssrc/sdst row-dots with attention vector avec[128].
#define GTM 128
#define GTN 64
#define GBK 64

__global__ __launch_bounds__(256) void k_gemm(
    const float* __restrict__ A, const float* __restrict__ B, float* __restrict__ C,
    int M, int K, int lda, int ldb, int ldc, int accum,
    const float* __restrict__ avec, float* __restrict__ ssrc, float* __restrict__ sdst,
    int fuse) {
  __shared__ float As[GTM][GBK + 1];   // +1 pad: conflict-free column reads
  __shared__ float Bs[GBK][GTN];
  int t = threadIdx.x;
  int tx = t & 7, ty = t >> 3;
  int rowBase = blockIdx.x * GTM;
  int colBase = blockIdx.y * GTN;
  float acc[4][8];
#pragma unroll
  for (int r = 0; r < 4; ++r)
#pragma unroll
    for (int c = 0; c < 8; ++c) acc[r][c] = 0.f;

  for (int k0 = 0; k0 < K; k0 += GBK) {
#pragma unroll
    for (int i = 0; i < 8; ++i) {          // A tile: 128x64
      int q = t * 4 + i * 1024;
      int r = q >> 6, kk = q & 63;
      int gr = rowBase + r; if (gr > M - 1) gr = M - 1;
      const float4 v = *(const float4*)(A + (size_t)gr * lda + (k0 + kk));
      As[r][kk] = v.x; As[r][kk + 1] = v.y; As[r][kk + 2] = v.z; As[r][kk + 3] = v.w;
    }
#pragma unroll
    for (int i = 0; i < 4; ++i) {          // B tile: 64x64
      int q = t * 4 + i * 1024;
      int kk = q >> 6, c = q & 63;
      *(float4*)&Bs[kk][c] = *(const float4*)(B + (size_t)(k0 + kk) * ldb + (colBase + c));
    }
    __syncthreads();
#pragma unroll 8
    for (int kk = 0; kk < GBK; ++kk) {
      float4 b0 = *(const float4*)&Bs[kk][tx * 8];
      float4 b1 = *(const float4*)&Bs[kk][tx * 8 + 4];
#pragma unroll
      for (int r = 0; r < 4; ++r) {
        float a = As[ty * 4 + r][kk];
        acc[r][0] += a * b0.x; acc[r][1] += a * b0.y;
        acc[r][2] += a * b0.z; acc[r][3] += a * b0.w;
        acc[r][4] += a * b1.x; acc[r][5] += a * b1.y;
        acc[r][6] += a * b1.z; acc[r][7] += a * b1.w;
      }
    }
    __syncthreads();
  }
#pragma unroll
  for (int r = 0; r < 4; ++r) {
    int gr = rowBase + ty * 4 + r;
    if (gr < M) {
      float* cp = C + (size_t)gr * ldc + colBase + tx * 8;
      if (accum) {
        float4 o0 = *(const float4*)cp;
        float4 o1 = *(const float4*)(cp + 4);
        *(float4*)cp = make_float4(o0.x + acc[r][0], o0.y + acc[r][1],
                                   o0.z + acc[r][2], o0.w + acc[r][3]);
        *(float4*)(cp + 4) = make_float4(o1.x + acc[r][4], o1.y + acc[r][5],
                                         o1.z + acc[r][6], o1.w + acc[r][7]);
      } else {
        *(float4*)cp = make_float4(acc[r][0], acc[r][1], acc[r][2], acc[r][3]);
        *(float4*)(cp + 4) = make_float4(acc[r][4], acc[r][5], acc[r][6], acc[r][7]);
      }
    }
  }
  if (fuse) {   // layer-1 attention row dots: only valid when gridDim.y==1, ncols==64
#pragma unroll
    for (int r = 0; r < 4; ++r) {
      float p0 = 0.f, p1 = 0.f;
#pragma unroll
      for (int j = 0; j < 8; ++j) {
        float hv = acc[r][j];
        p0 += hv * avec[tx * 8 + j];
        p1 += hv * avec[64 + tx * 8 + j];
      }
      p0 += __shfl_xor(p0, 1); p0 += __shfl_xor(p0, 2); p0 += __shfl_xor(p0, 4);
      p1 += __shfl_xor(p1, 1); p1 += __shfl_xor(p1, 2); p1 += __shfl_xor(p1, 4);
      int gr = rowBase + ty * 4 + r;
      if (tx == 0 && gr < M) { ssrc[gr] = p0; sdst[gr] = p1; }
    }
  }
}

// ---------------- layer-2 attention scores ----------------
__global__ void k_s2(const float* __restrict__ h2, const float* __restrict__ a2,
                     float* __restrict__ ssrc, float* __restrict__ sdst, int N) {
  int wv = (blockIdx.x * blockDim.x + threadIdx.x) >> 6;
  int lane = threadIdx.x & 63;
  if (wv >= N) return;
  float x0 = h2[(size_t)wv * 128 + lane];
  float x1 = h2[(size_t)wv * 128 + 64 + lane];
  float p0 = x0 * a2[lane] + x1 * a2[64 + lane];
  float p1 = x0 * a2[128 + lane] + x1 * a2[192 + lane];
#pragma unroll
  for (int off = 32; off > 0; off >>= 1) {
    p0 += __shfl_xor(p0, off);
    p1 += __shfl_xor(p1, off);
  }
  if (lane == 0) { ssrc[wv] = p0; sdst[wv] = p1; }
}

// ---------------- layer-1 aggregation (per head), wave per node, lane = column ----------------
__global__ void k_agg1(const int* __restrict__ rp, const int* __restrict__ edge_dst,
                       const float* __restrict__ h1t, const float* __restrict__ ssrc,
                       const float* __restrict__ sdst, float* __restrict__ hout, int N) {
  int wv = (blockIdx.x * blockDim.x + threadIdx.x) >> 6;
  int lane = threadIdx.x & 63;
  if (wv >= N) return;
  int e0 = rp[wv], e1 = rp[wv + 1];
  float ss = ssrc[wv];
  float acc = 0.f, rsum = 0.f;
  int e = e0;
  for (; e + 4 <= e1; e += 4) {
    int d0 = edge_dst[e], d1 = edge_dst[e + 1], d2 = edge_dst[e + 2], d3 = edge_dst[e + 3];
    float w0 = edge_w(ss + sdst[d0]);
    float w1 = edge_w(ss + sdst[d1]);
    float w2 = edge_w(ss + sdst[d2]);
    float w3 = edge_w(ss + sdst[d3]);
    float v0 = h1t[(size_t)d0 * 64 + lane];
    float v1 = h1t[(size_t)d1 * 64 + lane];
    float v2 = h1t[(size_t)d2 * 64 + lane];
    float v3 = h1t[(size_t)d3 * 64 + lane];
    acc += w0 * v0; acc += w1 * v1; acc += w2 * v2; acc += w3 * v3;
    rsum += w0 + w1 + w2 + w3;
  }
  for (; e < e1; ++e) {
    int d = edge_dst[e];
    float w = edge_w(ss + sdst[d]);
    acc += w * h1t[(size_t)d * 64 + lane];
    rsum += w;
  }
  float hp = acc / (rsum + EPS_DENOM);
  hout[(size_t)wv * 64 + lane] = elu_f(hp);
}

// ---------------- layer-2 aggregation + deg==0 fallback + final ELU ----------------
__global__ void k_agg2(const int* __restrict__ rp, const int* __restrict__ edge_dst,
                       const float* __restrict__ h2, const float* __restrict__ ssrc,
                       const float* __restrict__ sdst, const float* __restrict__ x,
                       float* __restrict__ out, int N) {
  int wv = (blockIdx.x * blockDim.x + threadIdx.x) >> 6;
  int lane = threadIdx.x & 63;
  if (wv >= N) return;
  int e0 = rp[wv], e1 = rp[wv + 1];
  if (e0 == e1) {   // zero out-degree: h row = x row
    out[(size_t)wv * 128 + lane] = elu_f(x[(size_t)wv * 128 + lane]);
    out[(size_t)wv * 128 + 64 + lane] = elu_f(x[(size_t)wv * 128 + 64 + lane]);
    return;
  }
  float ss = ssrc[wv];
  float a0 = 0.f, a1 = 0.f, rsum = 0.f;
  int e = e0;
  for (; e + 2 <= e1; e += 2) {
    int d0 = edge_dst[e], d1 = edge_dst[e + 1];
    float w0 = edge_w(ss + sdst[d0]);
    float w1 = edge_w(ss + sdst[d1]);
    a0 += w0 * h2[(size_t)d0 * 128 + lane];
    a1 += w0 * h2[(size_t)d0 * 128 + 64 + lane];
    a0 += w1 * h2[(size_t)d1 * 128 + lane];
    a1 += w1 * h2[(size_t)d1 * 128 + 64 + lane];
    rsum += w0 + w1;
  }
  for (; e < e1; ++e) {
    int d = edge_dst[e];
    float w = edge_w(ss + sdst[d]);
    a0 += w * h2[(size_t)d * 128 + lane];
    a1 += w * h2[(size_t)d * 128 + 64 + lane];
    rsum += w;
  }
  out[(size_t)wv * 128 + lane] = elu_f(a0 / (rsum + EPS_DENOM));
  out[(size_t)wv * 128 + 64 + lane] = elu_f(a1 / (rsum + EPS_DENOM));
}

extern "C" void kernel_launch(void* const* d_in, const int* in_sizes, int n_in,
                              void* d_out, int out_size, void* d_ws, size_t ws_size,
                              hipStream_t stream) {
  (void)n_in; (void)out_size; (void)ws_size;
  const float* x  = (const float*)d_in[0];
  const int*   ei = (const int*)d_in[1];
  const float* W1 = (const float*)d_in[2];
  const float* a1 = (const float*)d_in[3];
  const float* W2 = (const float*)d_in[4];
  const float* a2 = (const float*)d_in[5];
  float* out = (float*)d_out;
  const int N = in_sizes[0] / NFEAT;
  const int E = in_sizes[1] / 2;
  const int* src  = ei;
  const int* dstv = ei + E;

  // bucket geometry: rows-per-bucket = 1<<shift, NB <= MAXNB buckets
  int shift = 7;
  while ((((N - 1) >> shift) + 1) > MAXNB) ++shift;
  const int NB = ((N - 1) >> shift) + 1;

  // d_out doubles as per-head scratch during the head loop (dead before k_agg2):
  float* h1t  = out;                       // [N,64] per-head x@W1
  float* hout = out + (size_t)N * NHID;    // [N,64] per-head aggregated/ELU output

  // workspace carve-up (~91 MB)
  char* wp = (char*)d_ws;
  size_t off = 0;
  auto mk = [&](size_t bytes) -> void* {
    void* p = wp + off;
    off += (bytes + 255) & ~(size_t)255;
    return p;
  };
  float* h2f      = (float*)mk((size_t)N * NOUT * 4);   // layer-2 accumulator [N,128]
  int2*  staging  = (int2*)mk((size_t)E * 8);           // bucket-grouped (src,dst)
  int*   edge_dst = (int*)mk((size_t)E * 4);            // final CSR columns
  float* ssrc     = (float*)mk((size_t)N * 4);
  float* sdst     = (float*)mk((size_t)N * 4);
  int*   rp       = (int*)mk((size_t)(N + 1) * 4);
  int*   bhist    = (int*)mk((size_t)(NB + 1) * 4);
  int*   bbase    = (int*)mk((size_t)(NB + 1) * 4);
  int*   bcur     = (int*)mk((size_t)(NB + 1) * 4);

  // ---- CSR build (2-pass bucket sort) ----
  hipMemsetAsync(bhist, 0, (size_t)NB * 4, stream);
  int binBlocks = (E + BIN_EPB - 1) / BIN_EPB;
  k_bhist<<<binBlocks, 256, 0, stream>>>(src, bhist, E, NB, shift);
  k_bscan<<<1, 1024, 0, stream>>>(bhist, bbase, bcur, rp, NB, N, E);
  k_binA<<<binBlocks, 256, 0, stream>>>(src, dstv, bcur, staging, E, NB, shift);
  k_binB<<<NB, 256, 0, stream>>>(staging, bbase, rp, edge_dst, N, shift);

  // layer-2 accumulator must start at zero every call (graph replays!)
  hipMemsetAsync(h2f, 0, (size_t)N * NOUT * 4, stream);

  int wb = (N + 3) / 4;   // wave-per-node kernels: 4 nodes per 256-thread block
  dim3 g1((N + GTM - 1) / GTM, 1);
  dim3 g2((N + GTM - 1) / GTM, 2);

  // layer 1, per head; fold each head's contribution into h2f (K=64 GEMM, beta=1)
  for (int h = 0; h < NHEADS; ++h) {
    k_gemm<<<g1, 256, 0, stream>>>(x, W1 + (size_t)h * NFEAT * NHID, h1t,
                                   N, NFEAT, NFEAT, NHID, NHID, 0,
                                   a1 + (size_t)h * 2 * NHID, ssrc, sdst, 1);
    k_agg1<<<wb, 256, 0, stream>>>(rp, edge_dst, h1t, ssrc, sdst, hout, N);
    k_gemm<<<g2, 256, 0, stream>>>(hout, W2 + (size_t)h * NHID * NOUT, h2f,
                                   N, NHID, NHID, NOUT, NOUT, 1,
                                   nullptr, nullptr, nullptr, 0);
  }

  // layer 2 scores + aggregation (reuse ssrc/sdst)
  k_s2<<<wb, 256, 0, stream>>>(h2f, a2, ssrc, sdst, N);
  k_agg2<<<wb, 256, 0, stream>>>(rp, edge_dst, h2f, ssrc, sdst, x, out, N);
}

// Round 4
// 1770.011 us; speedup vs baseline: 1.3127x; 1.0821x over previous
//
#include <hip/hip_runtime.h>
#include <hip/hip_fp16.h>

#define NFEAT 128
#define NHID 64
#define NOUT 128
#define NHEADS 8
#define ALPHA_SLOPE 0.2f
#define EPS_DENOM 1e-16f

#define MAXNB 1024      // max buckets (N/128 rounded up must fit)
#define BIN_EPB 12288   // edges per block in binning kernels
#define BIN_CAP 6144    // max pairs per bucket held in LDS (mean 4092, +32 sigma)

static __device__ __forceinline__ float elu_f(float v) {
  return v > 0.f ? v : __expf(v) - 1.f;
}
static __device__ __forceinline__ float edge_w(float sc) {
  float lr = sc > 0.f ? sc : ALPHA_SLOPE * sc;
  return __expf(-lr);
}

// ---------------- CSR build: 2-pass bucketed counting sort ----------------

__global__ __launch_bounds__(256) void k_bhist(const int* __restrict__ src,
                                               int* __restrict__ bhist,
                                               int E, int NB, int shift) {
  __shared__ int h[MAXNB];
  int tid = threadIdx.x;
  for (int i = tid; i < NB; i += 256) h[i] = 0;
  __syncthreads();
  int base = blockIdx.x * BIN_EPB;
#pragma unroll 4
  for (int j = 0; j < BIN_EPB / 256; ++j) {
    int e = base + tid + j * 256;
    if (e < E) atomicAdd(&h[src[e] >> shift], 1);
  }
  __syncthreads();
  for (int i = tid; i < NB; i += 256)
    if (h[i]) atomicAdd(&bhist[i], h[i]);
}

__global__ __launch_bounds__(1024) void k_bscan(const int* __restrict__ bhist,
                                                int* __restrict__ bucket_base,
                                                int* __restrict__ bucket_cursor,
                                                int* __restrict__ rp,
                                                int NB, int N, int E) {
  __shared__ int sh[1024];
  int i = threadIdx.x;
  int v = (i < NB) ? bhist[i] : 0;
  sh[i] = v;
  __syncthreads();
  for (int off = 1; off < 1024; off <<= 1) {
    int add = (i >= off) ? sh[i - off] : 0;
    __syncthreads();
    sh[i] += add;
    __syncthreads();
  }
  if (i < NB) {
    int ex = sh[i] - v;
    bucket_base[i] = ex;
    bucket_cursor[i] = ex;
  }
  if (i == 0) {
    bucket_base[NB] = E;
    rp[N] = E;
  }
}

__global__ __launch_bounds__(256) void k_binA(const int* __restrict__ src,
                                              const int* __restrict__ dst,
                                              int* __restrict__ bucket_cursor,
                                              int2* __restrict__ staging,
                                              int E, int NB, int shift) {
  __shared__ int h[MAXNB];
  int tid = threadIdx.x;
  for (int i = tid; i < NB; i += 256) h[i] = 0;
  __syncthreads();
  int base = blockIdx.x * BIN_EPB;
#pragma unroll 4
  for (int j = 0; j < BIN_EPB / 256; ++j) {
    int e = base + tid + j * 256;
    if (e < E) atomicAdd(&h[src[e] >> shift], 1);
  }
  __syncthreads();
  for (int i = tid; i < NB; i += 256)
    if (h[i]) h[i] = atomicAdd(&bucket_cursor[i], h[i]);   // h[i] = block's base slot
  __syncthreads();
#pragma unroll 4
  for (int j = 0; j < BIN_EPB / 256; ++j) {
    int e = base + tid + j * 256;
    if (e < E) {
      int s = src[e];
      int slot = atomicAdd(&h[s >> shift], 1);
      staging[slot] = make_int2(s, dst[e]);
    }
  }
}

__global__ __launch_bounds__(256) void k_binB(const int2* __restrict__ staging,
                                              const int* __restrict__ bucket_base,
                                              int* __restrict__ rp,
                                              int* __restrict__ edge_dst,
                                              int N, int shift) {
  __shared__ int2 buf[BIN_CAP];
  __shared__ int rcnt[256], rsc[256];
  int tid = threadIdx.x;
  int b = blockIdx.x;
  int lo = bucket_base[b], hi = bucket_base[b + 1];
  int S = hi - lo;
  if (S > BIN_CAP) S = BIN_CAP;   // tripwire (never for this input)
  int R = 1 << shift;             // rows per bucket (<=256)
  int rmask = R - 1;
  for (int i = tid; i < S; i += 256) buf[i] = staging[lo + i];
  if (tid < R) rcnt[tid] = 0;
  __syncthreads();
  for (int i = tid; i < S; i += 256) atomicAdd(&rcnt[buf[i].x & rmask], 1);
  __syncthreads();
  if (tid < R) rsc[tid] = rcnt[tid];
  __syncthreads();
  for (int off = 1; off < 256; off <<= 1) {
    int add = (tid >= off && tid < R) ? rsc[tid - off] : 0;
    __syncthreads();
    if (tid < R) rsc[tid] += add;
    __syncthreads();
  }
  int row0 = b << shift;
  if (tid < R) {
    int ex = rsc[tid] - rcnt[tid];
    rcnt[tid] = ex;                       // becomes the within-bucket cursor
    if (row0 + tid < N) rp[row0 + tid] = lo + ex;
  }
  __syncthreads();
  for (int i = tid; i < S; i += 256) {
    int r = buf[i].x & rmask;
    int k = atomicAdd(&rcnt[r], 1);
    edge_dst[lo + k] = buf[i].y;
  }
}

// ---------------- f32 tiled GEMM: C[M,ncols] (+)= A[M,K] @ B[K,ncols] ----------------
// tile: 128 rows x 64 cols, K-chunks of 64. 256 threads, each 4x8 outputs.
// f16out: write C as __half (layer-1 h1t). fuse: also emit ssrc/sdst row dots (f32).
#define GTM 128
#define GTN 64
#define GBK 64

__global__ __launch_bounds__(256) void k_gemm(
    const float* __restrict__ A, const float* __restrict__ B, void* __restrict__ C,
    int M, int K, int lda, int ldb, int ldc, int accum, int f16out,
    const float* __restrict__ avec, float* __restrict__ ssrc, float* __restrict__ sdst,
    int fuse) {
  __shared__ float As[GTM][GBK + 1];   // +1 pad: conflict-free column reads
  __shared__ float Bs[GBK][GTN];
  int t = threadIdx.x;
  int tx = t & 7, ty = t >> 3;
  int rowBase = blockIdx.x * GTM;
  int colBase = blockIdx.y * GTN;
  float acc[4][8];
#pragma unroll
  for (int r = 0; r < 4; ++r)
#pragma unroll
    for (int c = 0; c < 8; ++c) acc[r][c] = 0.f;

  for (int k0 = 0; k0 < K; k0 += GBK) {
#pragma unroll
    for (int i = 0; i < 8; ++i) {          // A tile: 128x64
      int q = t * 4 + i * 1024;
      int r = q >> 6, kk = q & 63;
      int gr = rowBase + r; if (gr > M - 1) gr = M - 1;
      const float4 v = *(const float4*)(A + (size_t)gr * lda + (k0 + kk));
      As[r][kk] = v.x; As[r][kk + 1] = v.y; As[r][kk + 2] = v.z; As[r][kk + 3] = v.w;
    }
#pragma unroll
    for (int i = 0; i < 4; ++i) {          // B tile: 64x64
      int q = t * 4 + i * 1024;
      int kk = q >> 6, c = q & 63;
      *(float4*)&Bs[kk][c] = *(const float4*)(B + (size_t)(k0 + kk) * ldb + (colBase + c));
    }
    __syncthreads();
#pragma unroll 8
    for (int kk = 0; kk < GBK; ++kk) {
      float4 b0 = *(const float4*)&Bs[kk][tx * 8];
      float4 b1 = *(const float4*)&Bs[kk][tx * 8 + 4];
#pragma unroll
      for (int r = 0; r < 4; ++r) {
        float a = As[ty * 4 + r][kk];
        acc[r][0] += a * b0.x; acc[r][1] += a * b0.y;
        acc[r][2] += a * b0.z; acc[r][3] += a * b0.w;
        acc[r][4] += a * b1.x; acc[r][5] += a * b1.y;
        acc[r][6] += a * b1.z; acc[r][7] += a * b1.w;
      }
    }
    __syncthreads();
  }
#pragma unroll
  for (int r = 0; r < 4; ++r) {
    int gr = rowBase + ty * 4 + r;
    if (gr < M) {
      if (f16out) {
        __half* cp = (__half*)C + (size_t)gr * ldc + colBase + tx * 8;
        __half tmp[8];
#pragma unroll
        for (int j = 0; j < 8; ++j) tmp[j] = __float2half(acc[r][j]);
        *(float4*)cp = *(const float4*)tmp;
      } else {
        float* cp = (float*)C + (size_t)gr * ldc + colBase + tx * 8;
        if (accum) {
          float4 o0 = *(const float4*)cp;
          float4 o1 = *(const float4*)(cp + 4);
          *(float4*)cp = make_float4(o0.x + acc[r][0], o0.y + acc[r][1],
                                     o0.z + acc[r][2], o0.w + acc[r][3]);
          *(float4*)(cp + 4) = make_float4(o1.x + acc[r][4], o1.y + acc[r][5],
                                           o1.z + acc[r][6], o1.w + acc[r][7]);
        } else {
          *(float4*)cp = make_float4(acc[r][0], acc[r][1], acc[r][2], acc[r][3]);
          *(float4*)(cp + 4) = make_float4(acc[r][4], acc[r][5], acc[r][6], acc[r][7]);
        }
      }
    }
  }
  if (fuse) {   // layer-1 attention row dots from f32 acc (gridDim.y==1, ncols==64)
#pragma unroll
    for (int r = 0; r < 4; ++r) {
      float p0 = 0.f, p1 = 0.f;
#pragma unroll
      for (int j = 0; j < 8; ++j) {
        float hv = acc[r][j];
        p0 += hv * avec[tx * 8 + j];
        p1 += hv * avec[64 + tx * 8 + j];
      }
      p0 += __shfl_xor(p0, 1); p0 += __shfl_xor(p0, 2); p0 += __shfl_xor(p0, 4);
      p1 += __shfl_xor(p1, 1); p1 += __shfl_xor(p1, 2); p1 += __shfl_xor(p1, 4);
      int gr = rowBase + ty * 4 + r;
      if (tx == 0 && gr < M) { ssrc[gr] = p0; sdst[gr] = p1; }
    }
  }
}

// ---------------- layer-2 attention scores + fp16 mirror of h2 ----------------
__global__ void k_s2(const float* __restrict__ h2, const float* __restrict__ a2,
                     float* __restrict__ ssrc, float* __restrict__ sdst,
                     __half* __restrict__ h2h, int N) {
  int wv = (blockIdx.x * blockDim.x + threadIdx.x) >> 6;
  int lane = threadIdx.x & 63;
  if (wv >= N) return;
  float x0 = h2[(size_t)wv * 128 + lane];
  float x1 = h2[(size_t)wv * 128 + 64 + lane];
  h2h[(size_t)wv * 128 + lane] = __float2half(x0);
  h2h[(size_t)wv * 128 + 64 + lane] = __float2half(x1);
  float p0 = x0 * a2[lane] + x1 * a2[64 + lane];
  float p1 = x0 * a2[128 + lane] + x1 * a2[192 + lane];
#pragma unroll
  for (int off = 32; off > 0; off >>= 1) {
    p0 += __shfl_xor(p0, off);
    p1 += __shfl_xor(p1, off);
  }
  if (lane == 0) { ssrc[wv] = p0; sdst[wv] = p1; }
}

// ---------------- layer-1 aggregation (per head), wave per node, lane = column ----------------
__global__ void k_agg1(const int* __restrict__ rp, const int* __restrict__ edge_dst,
                       const __half* __restrict__ h1t, const float* __restrict__ ssrc,
                       const float* __restrict__ sdst, float* __restrict__ hout, int N) {
  int wv = (blockIdx.x * blockDim.x + threadIdx.x) >> 6;
  int lane = threadIdx.x & 63;
  if (wv >= N) return;
  int e0 = rp[wv], e1 = rp[wv + 1];
  float ss = ssrc[wv];
  float acc = 0.f, rsum = 0.f;
  int e = e0;
  for (; e + 4 <= e1; e += 4) {
    int d0 = edge_dst[e], d1 = edge_dst[e + 1], d2 = edge_dst[e + 2], d3 = edge_dst[e + 3];
    float w0 = edge_w(ss + sdst[d0]);
    float w1 = edge_w(ss + sdst[d1]);
    float w2 = edge_w(ss + sdst[d2]);
    float w3 = edge_w(ss + sdst[d3]);
    float v0 = __half2float(h1t[(size_t)d0 * 64 + lane]);
    float v1 = __half2float(h1t[(size_t)d1 * 64 + lane]);
    float v2 = __half2float(h1t[(size_t)d2 * 64 + lane]);
    float v3 = __half2float(h1t[(size_t)d3 * 64 + lane]);
    acc += w0 * v0; acc += w1 * v1; acc += w2 * v2; acc += w3 * v3;
    rsum += w0 + w1 + w2 + w3;
  }
  for (; e < e1; ++e) {
    int d = edge_dst[e];
    float w = edge_w(ss + sdst[d]);
    acc += w * __half2float(h1t[(size_t)d * 64 + lane]);
    rsum += w;
  }
  float hp = acc / (rsum + EPS_DENOM);
  hout[(size_t)wv * 64 + lane] = elu_f(hp);
}

// ---------------- layer-2 aggregation + deg==0 fallback + final ELU ----------------
// lane covers cols 2*lane, 2*lane+1 (half2 gather, float2 store)
__global__ void k_agg2(const int* __restrict__ rp, const int* __restrict__ edge_dst,
                       const __half* __restrict__ h2h, const float* __restrict__ ssrc,
                       const float* __restrict__ sdst, const float* __restrict__ x,
                       float* __restrict__ out, int N) {
  int wv = (blockIdx.x * blockDim.x + threadIdx.x) >> 6;
  int lane = threadIdx.x & 63;
  if (wv >= N) return;
  int e0 = rp[wv], e1 = rp[wv + 1];
  if (e0 == e1) {   // zero out-degree: h row = x row
    float2 xv = *(const float2*)(x + (size_t)wv * 128 + 2 * lane);
    *(float2*)(out + (size_t)wv * 128 + 2 * lane) = make_float2(elu_f(xv.x), elu_f(xv.y));
    return;
  }
  float ss = ssrc[wv];
  float a0 = 0.f, a1 = 0.f, rsum = 0.f;
  int e = e0;
  for (; e + 2 <= e1; e += 2) {
    int d0 = edge_dst[e], d1 = edge_dst[e + 1];
    float w0 = edge_w(ss + sdst[d0]);
    float w1 = edge_w(ss + sdst[d1]);
    float2 v0 = __half22float2(*((const __half2*)(h2h + (size_t)d0 * 128) + lane));
    float2 v1 = __half22float2(*((const __half2*)(h2h + (size_t)d1 * 128) + lane));
    a0 += w0 * v0.x; a1 += w0 * v0.y;
    a0 += w1 * v1.x; a1 += w1 * v1.y;
    rsum += w0 + w1;
  }
  for (; e < e1; ++e) {
    int d = edge_dst[e];
    float w = edge_w(ss + sdst[d]);
    float2 v = __half22float2(*((const __half2*)(h2h + (size_t)d * 128) + lane));
    a0 += w * v.x; a1 += w * v.y;
    rsum += w;
  }
  float inv = 1.f / (rsum + EPS_DENOM);
  *(float2*)(out + (size_t)wv * 128 + 2 * lane) =
      make_float2(elu_f(a0 * inv), elu_f(a1 * inv));
}

extern "C" void kernel_launch(void* const* d_in, const int* in_sizes, int n_in,
                              void* d_out, int out_size, void* d_ws, size_t ws_size,
                              hipStream_t stream) {
  (void)n_in; (void)out_size; (void)ws_size;
  const float* x  = (const float*)d_in[0];
  const int*   ei = (const int*)d_in[1];
  const float* W1 = (const float*)d_in[2];
  const float* a1 = (const float*)d_in[3];
  const float* W2 = (const float*)d_in[4];
  const float* a2 = (const float*)d_in[5];
  float* out = (float*)d_out;
  const int N = in_sizes[0] / NFEAT;
  const int E = in_sizes[1] / 2;
  const int* src  = ei;
  const int* dstv = ei + E;

  // bucket geometry: rows-per-bucket = 1<<shift, NB <= MAXNB buckets
  int shift = 7;
  while ((((N - 1) >> shift) + 1) > MAXNB) ++shift;
  const int NB = ((N - 1) >> shift) + 1;

  // d_out doubles as per-head scratch during the head loop (dead before k_agg2):
  //   h1t fp16 [N,64] (12.8 MB)  then  hout f32 [N,64] (25.6 MB) at offset N*64 floats
  __half* h1t = (__half*)out;              // fp16 per-head x@W1
  float*  hout = out + (size_t)N * NHID;   // f32 per-head aggregated/ELU output

  // workspace carve-up (~91 MB)
  char* wp = (char*)d_ws;
  size_t off = 0;
  auto mk = [&](size_t bytes) -> void* {
    void* p = wp + off;
    off += (bytes + 255) & ~(size_t)255;
    return p;
  };
  float* h2f      = (float*)mk((size_t)N * NOUT * 4);   // layer-2 accumulator [N,128]
  int2*  staging  = (int2*)mk((size_t)E * 8);           // CSR staging; later aliased as h2h
  int*   edge_dst = (int*)mk((size_t)E * 4);            // final CSR columns
  float* ssrc     = (float*)mk((size_t)N * 4);
  float* sdst     = (float*)mk((size_t)N * 4);
  int*   rp       = (int*)mk((size_t)(N + 1) * 4);
  int*   bhist    = (int*)mk((size_t)(NB + 1) * 4);
  int*   bbase    = (int*)mk((size_t)(NB + 1) * 4);
  int*   bcur     = (int*)mk((size_t)(NB + 1) * 4);
  __half* h2h = (__half*)staging;   // fp16 mirror of h2f [N,128] = 25.6 MB (staging is dead)

  // ---- CSR build (2-pass bucket sort) ----
  hipMemsetAsync(bhist, 0, (size_t)NB * 4, stream);
  int binBlocks = (E + BIN_EPB - 1) / BIN_EPB;
  k_bhist<<<binBlocks, 256, 0, stream>>>(src, bhist, E, NB, shift);
  k_bscan<<<1, 1024, 0, stream>>>(bhist, bbase, bcur, rp, NB, N, E);
  k_binA<<<binBlocks, 256, 0, stream>>>(src, dstv, bcur, staging, E, NB, shift);
  k_binB<<<NB, 256, 0, stream>>>(staging, bbase, rp, edge_dst, N, shift);

  // layer-2 accumulator must start at zero every call (graph replays!)
  hipMemsetAsync(h2f, 0, (size_t)N * NOUT * 4, stream);

  int wb = (N + 3) / 4;   // wave-per-node kernels: 4 nodes per 256-thread block
  dim3 g1((N + GTM - 1) / GTM, 1);
  dim3 g2((N + GTM - 1) / GTM, 2);

  // layer 1, per head; fold each head's contribution into h2f (K=64 GEMM, beta=1)
  for (int h = 0; h < NHEADS; ++h) {
    k_gemm<<<g1, 256, 0, stream>>>(x, W1 + (size_t)h * NFEAT * NHID, h1t,
                                   N, NFEAT, NFEAT, NHID, NHID, 0, 1,
                                   a1 + (size_t)h * 2 * NHID, ssrc, sdst, 1);
    k_agg1<<<wb, 256, 0, stream>>>(rp, edge_dst, h1t, ssrc, sdst, hout, N);
    k_gemm<<<g2, 256, 0, stream>>>(hout, W2 + (size_t)h * NHID * NOUT, h2f,
                                   N, NHID, NHID, NOUT, NOUT, 1, 0,
                                   nullptr, nullptr, nullptr, 0);
  }

  // layer 2 scores (+ fp16 mirror) + aggregation (reuse ssrc/sdst)
  k_s2<<<wb, 256, 0, stream>>>(h2f, a2, ssrc, sdst, h2h, N);
  k_agg2<<<wb, 256, 0, stream>>>(rp, edge_dst, h2h, ssrc, sdst, x, out, N);
}

// Round 5
// 1689.092 us; speedup vs baseline: 1.3756x; 1.0479x over previous
//
#include <hip/hip_runtime.h>
#include <hip/hip_fp16.h>

#define NFEAT 128
#define NHID 64
#define NOUT 128
#define NHEADS 8
#define ALPHA_SLOPE 0.2f
#define EPS_DENOM 1e-16f

#define MAXNB 1024      // max buckets (N/128 rounded up must fit)
#define BIN_EPB 12288   // edges per block in binning kernels
#define BIN_CAP 6144    // max pairs per bucket held in LDS (mean 4092, +32 sigma)

static __device__ __forceinline__ float elu_f(float v) {
  return v > 0.f ? v : __expf(v) - 1.f;
}
static __device__ __forceinline__ float edge_w(float sc) {
  float lr = sc > 0.f ? sc : ALPHA_SLOPE * sc;
  return __expf(-lr);
}

// ---------------- CSR build: 2-pass bucketed counting sort ----------------

__global__ __launch_bounds__(256) void k_bhist(const int* __restrict__ src,
                                               int* __restrict__ bhist,
                                               int E, int NB, int shift) {
  __shared__ int h[MAXNB];
  int tid = threadIdx.x;
  for (int i = tid; i < NB; i += 256) h[i] = 0;
  __syncthreads();
  int base = blockIdx.x * BIN_EPB;
#pragma unroll 4
  for (int j = 0; j < BIN_EPB / 256; ++j) {
    int e = base + tid + j * 256;
    if (e < E) atomicAdd(&h[src[e] >> shift], 1);
  }
  __syncthreads();
  for (int i = tid; i < NB; i += 256)
    if (h[i]) atomicAdd(&bhist[i], h[i]);
}

__global__ __launch_bounds__(1024) void k_bscan(const int* __restrict__ bhist,
                                                int* __restrict__ bucket_base,
                                                int* __restrict__ bucket_cursor,
                                                int* __restrict__ rp,
                                                int NB, int N, int E) {
  __shared__ int sh[1024];
  int i = threadIdx.x;
  int v = (i < NB) ? bhist[i] : 0;
  sh[i] = v;
  __syncthreads();
  for (int off = 1; off < 1024; off <<= 1) {
    int add = (i >= off) ? sh[i - off] : 0;
    __syncthreads();
    sh[i] += add;
    __syncthreads();
  }
  if (i < NB) {
    int ex = sh[i] - v;
    bucket_base[i] = ex;
    bucket_cursor[i] = ex;
  }
  if (i == 0) {
    bucket_base[NB] = E;
    rp[N] = E;
  }
}

__global__ __launch_bounds__(256) void k_binA(const int* __restrict__ src,
                                              const int* __restrict__ dst,
                                              int* __restrict__ bucket_cursor,
                                              int2* __restrict__ staging,
                                              int E, int NB, int shift) {
  __shared__ int h[MAXNB];
  int tid = threadIdx.x;
  for (int i = tid; i < NB; i += 256) h[i] = 0;
  __syncthreads();
  int base = blockIdx.x * BIN_EPB;
#pragma unroll 4
  for (int j = 0; j < BIN_EPB / 256; ++j) {
    int e = base + tid + j * 256;
    if (e < E) atomicAdd(&h[src[e] >> shift], 1);
  }
  __syncthreads();
  for (int i = tid; i < NB; i += 256)
    if (h[i]) h[i] = atomicAdd(&bucket_cursor[i], h[i]);   // h[i] = block's base slot
  __syncthreads();
#pragma unroll 4
  for (int j = 0; j < BIN_EPB / 256; ++j) {
    int e = base + tid + j * 256;
    if (e < E) {
      int s = src[e];
      int slot = atomicAdd(&h[s >> shift], 1);
      staging[slot] = make_int2(s, dst[e]);
    }
  }
}

__global__ __launch_bounds__(256) void k_binB(const int2* __restrict__ staging,
                                              const int* __restrict__ bucket_base,
                                              int* __restrict__ rp,
                                              int* __restrict__ edge_dst,
                                              int N, int shift) {
  __shared__ int2 buf[BIN_CAP];
  __shared__ int rcnt[256], rsc[256];
  int tid = threadIdx.x;
  int b = blockIdx.x;
  int lo = bucket_base[b], hi = bucket_base[b + 1];
  int S = hi - lo;
  if (S > BIN_CAP) S = BIN_CAP;   // tripwire (never for this input)
  int R = 1 << shift;             // rows per bucket (<=256)
  int rmask = R - 1;
  for (int i = tid; i < S; i += 256) buf[i] = staging[lo + i];
  if (tid < R) rcnt[tid] = 0;
  __syncthreads();
  for (int i = tid; i < S; i += 256) atomicAdd(&rcnt[buf[i].x & rmask], 1);
  __syncthreads();
  if (tid < R) rsc[tid] = rcnt[tid];
  __syncthreads();
  for (int off = 1; off < 256; off <<= 1) {
    int add = (tid >= off && tid < R) ? rsc[tid - off] : 0;
    __syncthreads();
    if (tid < R) rsc[tid] += add;
    __syncthreads();
  }
  int row0 = b << shift;
  if (tid < R) {
    int ex = rsc[tid] - rcnt[tid];
    rcnt[tid] = ex;                       // becomes the within-bucket cursor
    if (row0 + tid < N) rp[row0 + tid] = lo + ex;
  }
  __syncthreads();
  for (int i = tid; i < S; i += 256) {
    int r = buf[i].x & rmask;
    int k = atomicAdd(&rcnt[r], 1);
    edge_dst[lo + k] = buf[i].y;
  }
}

// ---------------- f32 tiled GEMM: C[M,ncols] (+)= A[M,K] @ B[K,ncols] ----------------
#define GTM 128
#define GTN 64
#define GBK 64

__global__ __launch_bounds__(256) void k_gemm(
    const float* __restrict__ A, const float* __restrict__ B, void* __restrict__ C,
    int M, int K, int lda, int ldb, int ldc, int accum, int f16out,
    const float* __restrict__ avec, float* __restrict__ ssrc, float* __restrict__ sdst,
    int fuse) {
  __shared__ float As[GTM][GBK + 1];   // +1 pad: conflict-free column reads
  __shared__ float Bs[GBK][GTN];
  int t = threadIdx.x;
  int tx = t & 7, ty = t >> 3;
  int rowBase = blockIdx.x * GTM;
  int colBase = blockIdx.y * GTN;
  float acc[4][8];
#pragma unroll
  for (int r = 0; r < 4; ++r)
#pragma unroll
    for (int c = 0; c < 8; ++c) acc[r][c] = 0.f;

  for (int k0 = 0; k0 < K; k0 += GBK) {
#pragma unroll
    for (int i = 0; i < 8; ++i) {          // A tile: 128x64
      int q = t * 4 + i * 1024;
      int r = q >> 6, kk = q & 63;
      int gr = rowBase + r; if (gr > M - 1) gr = M - 1;
      const float4 v = *(const float4*)(A + (size_t)gr * lda + (k0 + kk));
      As[r][kk] = v.x; As[r][kk + 1] = v.y; As[r][kk + 2] = v.z; As[r][kk + 3] = v.w;
    }
#pragma unroll
    for (int i = 0; i < 4; ++i) {          // B tile: 64x64
      int q = t * 4 + i * 1024;
      int kk = q >> 6, c = q & 63;
      *(float4*)&Bs[kk][c] = *(const float4*)(B + (size_t)(k0 + kk) * ldb + (colBase + c));
    }
    __syncthreads();
#pragma unroll 8
    for (int kk = 0; kk < GBK; ++kk) {
      float4 b0 = *(const float4*)&Bs[kk][tx * 8];
      float4 b1 = *(const float4*)&Bs[kk][tx * 8 + 4];
#pragma unroll
      for (int r = 0; r < 4; ++r) {
        float a = As[ty * 4 + r][kk];
        acc[r][0] += a * b0.x; acc[r][1] += a * b0.y;
        acc[r][2] += a * b0.z; acc[r][3] += a * b0.w;
        acc[r][4] += a * b1.x; acc[r][5] += a * b1.y;
        acc[r][6] += a * b1.z; acc[r][7] += a * b1.w;
      }
    }
    __syncthreads();
  }
#pragma unroll
  for (int r = 0; r < 4; ++r) {
    int gr = rowBase + ty * 4 + r;
    if (gr < M) {
      if (f16out) {
        __half* cp = (__half*)C + (size_t)gr * ldc + colBase + tx * 8;
        __half tmp[8];
#pragma unroll
        for (int j = 0; j < 8; ++j) tmp[j] = __float2half(acc[r][j]);
        *(float4*)cp = *(const float4*)tmp;
      } else {
        float* cp = (float*)C + (size_t)gr * ldc + colBase + tx * 8;
        if (accum) {
          float4 o0 = *(const float4*)cp;
          float4 o1 = *(const float4*)(cp + 4);
          *(float4*)cp = make_float4(o0.x + acc[r][0], o0.y + acc[r][1],
                                     o0.z + acc[r][2], o0.w + acc[r][3]);
          *(float4*)(cp + 4) = make_float4(o1.x + acc[r][4], o1.y + acc[r][5],
                                           o1.z + acc[r][6], o1.w + acc[r][7]);
        } else {
          *(float4*)cp = make_float4(acc[r][0], acc[r][1], acc[r][2], acc[r][3]);
          *(float4*)(cp + 4) = make_float4(acc[r][4], acc[r][5], acc[r][6], acc[r][7]);
        }
      }
    }
  }
  if (fuse) {   // layer-1 attention row dots from f32 acc (gridDim.y==1, ncols==64)
#pragma unroll
    for (int r = 0; r < 4; ++r) {
      float p0 = 0.f, p1 = 0.f;
#pragma unroll
      for (int j = 0; j < 8; ++j) {
        float hv = acc[r][j];
        p0 += hv * avec[tx * 8 + j];
        p1 += hv * avec[64 + tx * 8 + j];
      }
      p0 += __shfl_xor(p0, 1); p0 += __shfl_xor(p0, 2); p0 += __shfl_xor(p0, 4);
      p1 += __shfl_xor(p1, 1); p1 += __shfl_xor(p1, 2); p1 += __shfl_xor(p1, 4);
      int gr = rowBase + ty * 4 + r;
      if (tx == 0 && gr < M) { ssrc[gr] = p0; sdst[gr] = p1; }
    }
  }
}

// ---------------- layer-2 attention scores + fp16 mirror of h2 ----------------
__global__ void k_s2(const float* __restrict__ h2, const float* __restrict__ a2,
                     float* __restrict__ ssrc, float* __restrict__ sdst,
                     __half* __restrict__ h2h, int N) {
  int wv = (blockIdx.x * blockDim.x + threadIdx.x) >> 6;
  int lane = threadIdx.x & 63;
  if (wv >= N) return;
  float x0 = h2[(size_t)wv * 128 + lane];
  float x1 = h2[(size_t)wv * 128 + 64 + lane];
  h2h[(size_t)wv * 128 + lane] = __float2half(x0);
  h2h[(size_t)wv * 128 + 64 + lane] = __float2half(x1);
  float p0 = x0 * a2[lane] + x1 * a2[64 + lane];
  float p1 = x0 * a2[128 + lane] + x1 * a2[192 + lane];
#pragma unroll
  for (int off = 32; off > 0; off >>= 1) {
    p0 += __shfl_xor(p0, off);
    p1 += __shfl_xor(p1, off);
  }
  if (lane == 0) { ssrc[wv] = p0; sdst[wv] = p1; }
}

// ---------------- layer-1 aggregation: cooperative-edge, 2 edges/VMEM ----------------
// wave per node. chunk of 64 edges: lane e computes (d,w) once; then pairs of edges
// are gathered with half-wave 0 -> edge j, half-wave 1 -> edge j+1, half2 per lane.
__global__ void k_agg1(const int* __restrict__ rp, const int* __restrict__ edge_dst,
                       const __half* __restrict__ h1t, const float* __restrict__ ssrc,
                       const float* __restrict__ sdst, float* __restrict__ hout, int N) {
  int wv = (blockIdx.x * blockDim.x + threadIdx.x) >> 6;
  int lane = threadIdx.x & 63;
  if (wv >= N) return;
  int e0 = rp[wv], e1 = rp[wv + 1];
  float ss = ssrc[wv];
  int hi = lane >> 5;
  int colB = (lane & 31) << 1;          // 2 columns per lane
  float ax = 0.f, ay = 0.f, rsumL = 0.f;
  for (int base = e0; base < e1; base += 64) {
    int cnt = e1 - base; if (cnt > 64) cnt = 64;
    int d = 0; float w = 0.f;
    if (lane < cnt) {
      d = edge_dst[base + lane];
      w = edge_w(ss + sdst[d]);
    }
    rsumL += w;
    int jj = 0;
#pragma unroll 4
    for (; jj + 2 <= cnt; jj += 2) {
      int sel = jj + hi;
      int dj = __shfl(d, sel);
      float wj = __shfl(w, sel);
      float2 f = __half22float2(*(const __half2*)(h1t + ((size_t)dj << 6) + colB));
      ax += wj * f.x; ay += wj * f.y;
    }
    if (jj < cnt) {                      // odd remainder: half-wave 0 covers all cols
      int dj = __shfl(d, jj);
      float wj = __shfl(w, jj);
      if (hi == 0) {
        float2 f = __half22float2(*(const __half2*)(h1t + ((size_t)dj << 6) + colB));
        ax += wj * f.x; ay += wj * f.y;
      }
    }
  }
  ax += __shfl_xor(ax, 32);              // combine even/odd-edge halves (same cols)
  ay += __shfl_xor(ay, 32);
  float rsum = rsumL;
#pragma unroll
  for (int off = 32; off > 0; off >>= 1) rsum += __shfl_xor(rsum, off);
  float inv = 1.f / (rsum + EPS_DENOM);
  if (hi == 0) {
    *(float2*)(hout + ((size_t)wv << 6) + colB) =
        make_float2(elu_f(ax * inv), elu_f(ay * inv));
  }
}

// ---------------- layer-2 aggregation: cooperative-edge, 2 edges/VMEM ----------------
// row = 128 halfs; lane covers 4 cols (8B load), half-wave per edge.
__global__ void k_agg2(const int* __restrict__ rp, const int* __restrict__ edge_dst,
                       const __half* __restrict__ h2h, const float* __restrict__ ssrc,
                       const float* __restrict__ sdst, const float* __restrict__ x,
                       float* __restrict__ out, int N) {
  int wv = (blockIdx.x * blockDim.x + threadIdx.x) >> 6;
  int lane = threadIdx.x & 63;
  if (wv >= N) return;
  int e0 = rp[wv], e1 = rp[wv + 1];
  if (e0 == e1) {   // zero out-degree: h row = x row
    float2 xv = *(const float2*)(x + (size_t)wv * 128 + 2 * lane);
    *(float2*)(out + (size_t)wv * 128 + 2 * lane) = make_float2(elu_f(xv.x), elu_f(xv.y));
    return;
  }
  float ss = ssrc[wv];
  int hi = lane >> 5;
  int colB = (lane & 31) << 2;          // 4 columns per lane
  float a0 = 0.f, a1 = 0.f, a2v = 0.f, a3 = 0.f, rsumL = 0.f;
  for (int base = e0; base < e1; base += 64) {
    int cnt = e1 - base; if (cnt > 64) cnt = 64;
    int d = 0; float w = 0.f;
    if (lane < cnt) {
      d = edge_dst[base + lane];
      w = edge_w(ss + sdst[d]);
    }
    rsumL += w;
    int jj = 0;
#pragma unroll 4
    for (; jj + 2 <= cnt; jj += 2) {
      int sel = jj + hi;
      int dj = __shfl(d, sel);
      float wj = __shfl(w, sel);
      float2 raw = *(const float2*)(h2h + ((size_t)dj << 7) + colB);   // 4 halfs
      float2 f01 = __half22float2(*(const __half2*)&raw.x);
      float2 f23 = __half22float2(*(const __half2*)&raw.y);
      a0 += wj * f01.x; a1 += wj * f01.y; a2v += wj * f23.x; a3 += wj * f23.y;
    }
    if (jj < cnt) {
      int dj = __shfl(d, jj);
      float wj = __shfl(w, jj);
      if (hi == 0) {
        float2 raw = *(const float2*)(h2h + ((size_t)dj << 7) + colB);
        float2 f01 = __half22float2(*(const __half2*)&raw.x);
        float2 f23 = __half22float2(*(const __half2*)&raw.y);
        a0 += wj * f01.x; a1 += wj * f01.y; a2v += wj * f23.x; a3 += wj * f23.y;
      }
    }
  }
  a0 += __shfl_xor(a0, 32); a1 += __shfl_xor(a1, 32);
  a2v += __shfl_xor(a2v, 32); a3 += __shfl_xor(a3, 32);
  float rsum = rsumL;
#pragma unroll
  for (int off = 32; off > 0; off >>= 1) rsum += __shfl_xor(rsum, off);
  float inv = 1.f / (rsum + EPS_DENOM);
  if (hi == 0) {
    *(float4*)(out + (size_t)wv * 128 + colB) =
        make_float4(elu_f(a0 * inv), elu_f(a1 * inv), elu_f(a2v * inv), elu_f(a3 * inv));
  }
}

extern "C" void kernel_launch(void* const* d_in, const int* in_sizes, int n_in,
                              void* d_out, int out_size, void* d_ws, size_t ws_size,
                              hipStream_t stream) {
  (void)n_in; (void)out_size; (void)ws_size;
  const float* x  = (const float*)d_in[0];
  const int*   ei = (const int*)d_in[1];
  const float* W1 = (const float*)d_in[2];
  const float* a1 = (const float*)d_in[3];
  const float* W2 = (const float*)d_in[4];
  const float* a2 = (const float*)d_in[5];
  float* out = (float*)d_out;
  const int N = in_sizes[0] / NFEAT;
  const int E = in_sizes[1] / 2;
  const int* src  = ei;
  const int* dstv = ei + E;

  // bucket geometry: rows-per-bucket = 1<<shift, NB <= MAXNB buckets
  int shift = 7;
  while ((((N - 1) >> shift) + 1) > MAXNB) ++shift;
  const int NB = ((N - 1) >> shift) + 1;

  // d_out doubles as per-head scratch during the head loop (dead before k_agg2):
  __half* h1t = (__half*)out;              // fp16 per-head x@W1 [N,64]
  float*  hout = out + (size_t)N * NHID;   // f32 per-head aggregated/ELU output [N,64]

  // workspace carve-up (~91 MB)
  char* wp = (char*)d_ws;
  size_t off = 0;
  auto mk = [&](size_t bytes) -> void* {
    void* p = wp + off;
    off += (bytes + 255) & ~(size_t)255;
    return p;
  };
  float* h2f      = (float*)mk((size_t)N * NOUT * 4);   // layer-2 accumulator [N,128]
  int2*  staging  = (int2*)mk((size_t)E * 8);           // CSR staging; later aliased as h2h
  int*   edge_dst = (int*)mk((size_t)E * 4);            // final CSR columns
  float* ssrc     = (float*)mk((size_t)N * 4);
  float* sdst     = (float*)mk((size_t)N * 4);
  int*   rp       = (int*)mk((size_t)(N + 1) * 4);
  int*   bhist    = (int*)mk((size_t)(NB + 1) * 4);
  int*   bbase    = (int*)mk((size_t)(NB + 1) * 4);
  int*   bcur     = (int*)mk((size_t)(NB + 1) * 4);
  __half* h2h = (__half*)staging;   // fp16 mirror of h2f [N,128] (staging dead by then)

  // ---- CSR build (2-pass bucket sort) ----
  hipMemsetAsync(bhist, 0, (size_t)NB * 4, stream);
  int binBlocks = (E + BIN_EPB - 1) / BIN_EPB;
  k_bhist<<<binBlocks, 256, 0, stream>>>(src, bhist, E, NB, shift);
  k_bscan<<<1, 1024, 0, stream>>>(bhist, bbase, bcur, rp, NB, N, E);
  k_binA<<<binBlocks, 256, 0, stream>>>(src, dstv, bcur, staging, E, NB, shift);
  k_binB<<<NB, 256, 0, stream>>>(staging, bbase, rp, edge_dst, N, shift);

  // layer-2 accumulator must start at zero every call (graph replays!)
  hipMemsetAsync(h2f, 0, (size_t)N * NOUT * 4, stream);

  int wb = (N + 3) / 4;   // wave-per-node kernels: 4 nodes per 256-thread block
  dim3 g1((N + GTM - 1) / GTM, 1);
  dim3 g2((N + GTM - 1) / GTM, 2);

  // layer 1, per head; fold each head's contribution into h2f (K=64 GEMM, beta=1)
  for (int h = 0; h < NHEADS; ++h) {
    k_gemm<<<g1, 256, 0, stream>>>(x, W1 + (size_t)h * NFEAT * NHID, h1t,
                                   N, NFEAT, NFEAT, NHID, NHID, 0, 1,
                                   a1 + (size_t)h * 2 * NHID, ssrc, sdst, 1);
    k_agg1<<<wb, 256, 0, stream>>>(rp, edge_dst, h1t, ssrc, sdst, hout, N);
    k_gemm<<<g2, 256, 0, stream>>>(hout, W2 + (size_t)h * NHID * NOUT, h2f,
                                   N, NHID, NHID, NOUT, NOUT, 1, 0,
                                   nullptr, nullptr, nullptr, 0);
  }

  // layer 2 scores (+ fp16 mirror) + aggregation (reuse ssrc/sdst)
  k_s2<<<wb, 256, 0, stream>>>(h2f, a2, ssrc, sdst, h2h, N);
  k_agg2<<<wb, 256, 0, stream>>>(rp, edge_dst, h2h, ssrc, sdst, x, out, N);
}

// Round 6
// 1424.824 us; speedup vs baseline: 1.6307x; 1.1855x over previous
//
#include <hip/hip_runtime.h>
#include <hip/hip_fp16.h>

#define NFEAT 128
#define NHID 64
#define NOUT 128
#define NHEADS 8
#define ALPHA_SLOPE 0.2f
#define EPS_DENOM 1e-16f

#define MAXNB 1024      // max buckets
#define BIN_EPB 12288   // edges per block in binning kernels
#define BIN_CAP 6144    // max pairs per bucket held in LDS

typedef _Float16 f16;
typedef f16 f16x8 __attribute__((ext_vector_type(8)));
typedef float f32x4 __attribute__((ext_vector_type(4)));

static __device__ __forceinline__ float elu_f(float v) {
  return v > 0.f ? v : __expf(v) - 1.f;
}
static __device__ __forceinline__ float edge_w(float sc) {
  float lr = sc > 0.f ? sc : ALPHA_SLOPE * sc;
  return __expf(-lr);
}

// ---------------- dtype prep ----------------
__global__ void k_cvt_x(const float* __restrict__ x, f16* __restrict__ xh, long n8) {
  long i = (long)blockIdx.x * blockDim.x + threadIdx.x;
  long stride = (long)gridDim.x * blockDim.x;
  for (; i < n8; i += stride) {
    const float* p = x + i * 8;
    float4 v0 = *(const float4*)p;
    float4 v1 = *(const float4*)(p + 4);
    f16x8 o;
    o[0] = (f16)v0.x; o[1] = (f16)v0.y; o[2] = (f16)v0.z; o[3] = (f16)v0.w;
    o[4] = (f16)v1.x; o[5] = (f16)v1.y; o[6] = (f16)v1.z; o[7] = (f16)v1.w;
    *(f16x8*)(xh + i * 8) = o;
  }
}

// W1 [8][128][64] -> w1t [8][64][128] fp16 (c-major); W2 [512][128] -> w2t [128][512] fp16
__global__ void k_cvt_w(const float* __restrict__ W1, const float* __restrict__ W2,
                        f16* __restrict__ w1t, f16* __restrict__ w2t) {
  int idx = blockIdx.x * 256 + threadIdx.x;
  if (idx < NHEADS * 128 * 64) {
    int h = idx >> 13, rem = idx & 8191, c = rem >> 7, k = rem & 127;
    w1t[idx] = (f16)W1[h * 8192 + k * 64 + c];
  } else {
    int j = idx - NHEADS * 128 * 64;
    if (j < 128 * 512) {
      int c = j >> 9, k = j & 511;
      w2t[j] = (f16)W2[k * 128 + c];
    }
  }
}

// ---------------- CSR build: 2-pass bucketed counting sort ----------------
__global__ __launch_bounds__(256) void k_bhist(const int* __restrict__ src,
                                               int* __restrict__ bhist,
                                               int E, int NB, int shift) {
  __shared__ int h[MAXNB];
  int tid = threadIdx.x;
  for (int i = tid; i < NB; i += 256) h[i] = 0;
  __syncthreads();
  int base = blockIdx.x * BIN_EPB;
#pragma unroll 4
  for (int j = 0; j < BIN_EPB / 256; ++j) {
    int e = base + tid + j * 256;
    if (e < E) atomicAdd(&h[src[e] >> shift], 1);
  }
  __syncthreads();
  for (int i = tid; i < NB; i += 256)
    if (h[i]) atomicAdd(&bhist[i], h[i]);
}

__global__ __launch_bounds__(1024) void k_bscan(const int* __restrict__ bhist,
                                                int* __restrict__ bucket_base,
                                                int* __restrict__ bucket_cursor,
                                                int* __restrict__ rp,
                                                int NB, int N, int E) {
  __shared__ int sh[1024];
  int i = threadIdx.x;
  int v = (i < NB) ? bhist[i] : 0;
  sh[i] = v;
  __syncthreads();
  for (int off = 1; off < 1024; off <<= 1) {
    int add = (i >= off) ? sh[i - off] : 0;
    __syncthreads();
    sh[i] += add;
    __syncthreads();
  }
  if (i < NB) {
    int ex = sh[i] - v;
    bucket_base[i] = ex;
    bucket_cursor[i] = ex;
  }
  if (i == 0) {
    bucket_base[NB] = E;
    rp[N] = E;
  }
}

__global__ __launch_bounds__(256) void k_binA(const int* __restrict__ src,
                                              const int* __restrict__ dst,
                                              int* __restrict__ bucket_cursor,
                                              int2* __restrict__ staging,
                                              int E, int NB, int shift) {
  __shared__ int h[MAXNB];
  int tid = threadIdx.x;
  for (int i = tid; i < NB; i += 256) h[i] = 0;
  __syncthreads();
  int base = blockIdx.x * BIN_EPB;
#pragma unroll 4
  for (int j = 0; j < BIN_EPB / 256; ++j) {
    int e = base + tid + j * 256;
    if (e < E) atomicAdd(&h[src[e] >> shift], 1);
  }
  __syncthreads();
  for (int i = tid; i < NB; i += 256)
    if (h[i]) h[i] = atomicAdd(&bucket_cursor[i], h[i]);
  __syncthreads();
#pragma unroll 4
  for (int j = 0; j < BIN_EPB / 256; ++j) {
    int e = base + tid + j * 256;
    if (e < E) {
      int s = src[e];
      int slot = atomicAdd(&h[s >> shift], 1);
      staging[slot] = make_int2(s, dst[e]);
    }
  }
}

__global__ __launch_bounds__(256) void k_binB(const int2* __restrict__ staging,
                                              const int* __restrict__ bucket_base,
                                              int* __restrict__ rp,
                                              int* __restrict__ edge_dst,
                                              int N, int shift) {
  __shared__ int2 buf[BIN_CAP];
  __shared__ int rcnt[256], rsc[256];
  int tid = threadIdx.x;
  int b = blockIdx.x;
  int lo = bucket_base[b], hi = bucket_base[b + 1];
  int S = hi - lo;
  if (S > BIN_CAP) S = BIN_CAP;
  int R = 1 << shift;
  int rmask = R - 1;
  for (int i = tid; i < S; i += 256) buf[i] = staging[lo + i];
  if (tid < R) rcnt[tid] = 0;
  __syncthreads();
  for (int i = tid; i < S; i += 256) atomicAdd(&rcnt[buf[i].x & rmask], 1);
  __syncthreads();
  if (tid < R) rsc[tid] = rcnt[tid];
  __syncthreads();
  for (int off = 1; off < 256; off <<= 1) {
    int add = (tid >= off && tid < R) ? rsc[tid - off] : 0;
    __syncthreads();
    if (tid < R) rsc[tid] += add;
    __syncthreads();
  }
  int row0 = b << shift;
  if (tid < R) {
    int ex = rsc[tid] - rcnt[tid];
    rcnt[tid] = ex;
    if (row0 + tid < N) rp[row0 + tid] = lo + ex;
  }
  __syncthreads();
  for (int i = tid; i < S; i += 256) {
    int r = buf[i].x & rmask;
    int k = atomicAdd(&rcnt[r], 1);
    edge_dst[lo + k] = buf[i].y;
  }
}

// ---------------- MFMA GEMM1 (per head): h1t[N,64] f16 = xh[N,128] @ W1t^T ----------------
// + fused attention scores ssrc/sdst (f32). 256 thr = 4 waves; wave = 16 rows x 64 cols.
__global__ __launch_bounds__(256) void k_gemm1(
    const f16* __restrict__ xh, const f16* __restrict__ w1t,   // w1t: [64][128]
    const float* __restrict__ avec,                            // [128]
    f16* __restrict__ h1t, float* __restrict__ ssrc, float* __restrict__ sdst, int N) {
  int wave = threadIdx.x >> 6;
  int lane = threadIdx.x & 63;
  int c = lane & 15, g = lane >> 4;
  int row0 = blockIdx.x * 64 + wave * 16;

  // B fragments (loop-invariant): B[k][col]=W1[k][col]=w1t[col][k]; col=c, k=ks*32+g*8+j
  f16x8 bf[4][4];
#pragma unroll
  for (int t = 0; t < 4; ++t)
#pragma unroll
    for (int ks = 0; ks < 4; ++ks)
      bf[t][ks] = *(const f16x8*)(w1t + (t * 16 + c) * 128 + ks * 32 + g * 8);

  int arow = row0 + c; if (arow > N - 1) arow = N - 1;
  const f16* ap = xh + (size_t)arow * 128 + g * 8;

  f32x4 acc[4];
#pragma unroll
  for (int t = 0; t < 4; ++t) acc[t] = (f32x4){0.f, 0.f, 0.f, 0.f};
#pragma unroll
  for (int ks = 0; ks < 4; ++ks) {
    f16x8 af = *(const f16x8*)(ap + ks * 32);
#pragma unroll
    for (int t = 0; t < 4; ++t)
      acc[t] = __builtin_amdgcn_mfma_f32_16x16x32_f16(af, bf[t][ks], acc[t], 0, 0, 0);
  }

  float av0[4], av1[4];
#pragma unroll
  for (int t = 0; t < 4; ++t) {
    av0[t] = avec[t * 16 + c];
    av1[t] = avec[64 + t * 16 + c];
  }
#pragma unroll
  for (int j = 0; j < 4; ++j) {
    int r = row0 + g * 4 + j;
    float s0 = 0.f, s1 = 0.f;
#pragma unroll
    for (int t = 0; t < 4; ++t) {
      float v = acc[t][j];
      if (r < N) h1t[(size_t)r * 64 + t * 16 + c] = (f16)v;
      s0 += v * av0[t];
      s1 += v * av1[t];
    }
    s0 += __shfl_xor(s0, 1); s0 += __shfl_xor(s0, 2);
    s0 += __shfl_xor(s0, 4); s0 += __shfl_xor(s0, 8);
    s1 += __shfl_xor(s1, 1); s1 += __shfl_xor(s1, 2);
    s1 += __shfl_xor(s1, 4); s1 += __shfl_xor(s1, 8);
    if (c == 0 && r < N) { ssrc[r] = s0; sdst[r] = s1; }
  }
}

// ---------------- MFMA GEMM2 (per 2-head group): h2f[N,128] (+)= hout2[N,128] @ W2grp ----
// accum: read-modify h2f. fuse (last group): skip h2f store; emit s2 scores + fp16 h2h.
__global__ __launch_bounds__(256) void k_gemm2(
    const f16* __restrict__ hout2, const f16* __restrict__ w2t,   // w2t: [128][512]
    float* __restrict__ h2f, int kbase, int accum, int fuse,
    const float* __restrict__ a2, f16* __restrict__ h2h,
    float* __restrict__ s2src, float* __restrict__ s2dst, int N) {
  int wave = threadIdx.x >> 6;
  int lane = threadIdx.x & 63;
  int c = lane & 15, g = lane >> 4;
  int row0 = blockIdx.x * 64 + wave * 16;

  f32x4 acc[8];
  if (accum) {
#pragma unroll
    for (int t = 0; t < 8; ++t)
#pragma unroll
      for (int j = 0; j < 4; ++j) {
        int r = row0 + g * 4 + j;
        acc[t][j] = (r < N) ? h2f[(size_t)r * 128 + t * 16 + c] : 0.f;
      }
  } else {
#pragma unroll
    for (int t = 0; t < 8; ++t) acc[t] = (f32x4){0.f, 0.f, 0.f, 0.f};
  }

  int arow = row0 + c; if (arow > N - 1) arow = N - 1;
  const f16* ap = hout2 + (size_t)arow * 128 + g * 8;
#pragma unroll
  for (int ks = 0; ks < 4; ++ks) {
    f16x8 af = *(const f16x8*)(ap + ks * 32);
#pragma unroll
    for (int t = 0; t < 8; ++t) {
      f16x8 bfr = *(const f16x8*)(w2t + (size_t)(t * 16 + c) * 512 + kbase + ks * 32 + g * 8);
      acc[t] = __builtin_amdgcn_mfma_f32_16x16x32_f16(af, bfr, acc[t], 0, 0, 0);
    }
  }

  if (!fuse) {
#pragma unroll
    for (int t = 0; t < 8; ++t)
#pragma unroll
      for (int j = 0; j < 4; ++j) {
        int r = row0 + g * 4 + j;
        if (r < N) h2f[(size_t)r * 128 + t * 16 + c] = acc[t][j];
      }
  } else {
    float av0[8], av1[8];
#pragma unroll
    for (int t = 0; t < 8; ++t) {
      av0[t] = a2[t * 16 + c];
      av1[t] = a2[128 + t * 16 + c];
    }
#pragma unroll
    for (int j = 0; j < 4; ++j) {
      int r = row0 + g * 4 + j;
      float s0 = 0.f, s1 = 0.f;
#pragma unroll
      for (int t = 0; t < 8; ++t) {
        float v = acc[t][j];
        if (r < N) h2h[(size_t)r * 128 + t * 16 + c] = (f16)v;
        s0 += v * av0[t];
        s1 += v * av1[t];
      }
      s0 += __shfl_xor(s0, 1); s0 += __shfl_xor(s0, 2);
      s0 += __shfl_xor(s0, 4); s0 += __shfl_xor(s0, 8);
      s1 += __shfl_xor(s1, 1); s1 += __shfl_xor(s1, 2);
      s1 += __shfl_xor(s1, 4); s1 += __shfl_xor(s1, 8);
      if (c == 0 && r < N) { s2src[r] = s0; s2dst[r] = s1; }
    }
  }
}

// ---------------- layer-1 aggregation: cooperative-edge, fp16 out into hout2 ----------------
__global__ void k_agg1(const int* __restrict__ rp, const int* __restrict__ edge_dst,
                       const __half* __restrict__ h1t, const float* __restrict__ ssrc,
                       const float* __restrict__ sdst, __half* __restrict__ houtp, int N) {
  int wv = (blockIdx.x * blockDim.x + threadIdx.x) >> 6;
  int lane = threadIdx.x & 63;
  if (wv >= N) return;
  int e0 = rp[wv], e1 = rp[wv + 1];
  float ss = ssrc[wv];
  int hi = lane >> 5;
  int colB = (lane & 31) << 1;
  float ax = 0.f, ay = 0.f, rsumL = 0.f;
  for (int base = e0; base < e1; base += 64) {
    int cnt = e1 - base; if (cnt > 64) cnt = 64;
    int d = 0; float w = 0.f;
    if (lane < cnt) {
      d = edge_dst[base + lane];
      w = edge_w(ss + sdst[d]);
    }
    rsumL += w;
    int jj = 0;
#pragma unroll 4
    for (; jj + 2 <= cnt; jj += 2) {
      int sel = jj + hi;
      int dj = __shfl(d, sel);
      float wj = __shfl(w, sel);
      float2 f = __half22float2(*(const __half2*)(h1t + ((size_t)dj << 6) + colB));
      ax += wj * f.x; ay += wj * f.y;
    }
    if (jj < cnt) {
      int dj = __shfl(d, jj);
      float wj = __shfl(w, jj);
      if (hi == 0) {
        float2 f = __half22float2(*(const __half2*)(h1t + ((size_t)dj << 6) + colB));
        ax += wj * f.x; ay += wj * f.y;
      }
    }
  }
  ax += __shfl_xor(ax, 32);
  ay += __shfl_xor(ay, 32);
  float rsum = rsumL;
#pragma unroll
  for (int off = 32; off > 0; off >>= 1) rsum += __shfl_xor(rsum, off);
  float inv = 1.f / (rsum + EPS_DENOM);
  if (hi == 0) {
    *(__half2*)(houtp + (size_t)wv * 128 + colB) =
        __float22half2_rn(make_float2(elu_f(ax * inv), elu_f(ay * inv)));
  }
}

// ---------------- layer-2 aggregation: cooperative-edge + deg==0 fallback + ELU ----------------
__global__ void k_agg2(const int* __restrict__ rp, const int* __restrict__ edge_dst,
                       const __half* __restrict__ h2h, const float* __restrict__ ssrc,
                       const float* __restrict__ sdst, const float* __restrict__ x,
                       float* __restrict__ out, int N) {
  int wv = (blockIdx.x * blockDim.x + threadIdx.x) >> 6;
  int lane = threadIdx.x & 63;
  if (wv >= N) return;
  int e0 = rp[wv], e1 = rp[wv + 1];
  if (e0 == e1) {
    float2 xv = *(const float2*)(x + (size_t)wv * 128 + 2 * lane);
    *(float2*)(out + (size_t)wv * 128 + 2 * lane) = make_float2(elu_f(xv.x), elu_f(xv.y));
    return;
  }
  float ss = ssrc[wv];
  int hi = lane >> 5;
  int colB = (lane & 31) << 2;
  float a0 = 0.f, a1 = 0.f, a2v = 0.f, a3 = 0.f, rsumL = 0.f;
  for (int base = e0; base < e1; base += 64) {
    int cnt = e1 - base; if (cnt > 64) cnt = 64;
    int d = 0; float w = 0.f;
    if (lane < cnt) {
      d = edge_dst[base + lane];
      w = edge_w(ss + sdst[d]);
    }
    rsumL += w;
    int jj = 0;
#pragma unroll 4
    for (; jj + 2 <= cnt; jj += 2) {
      int sel = jj + hi;
      int dj = __shfl(d, sel);
      float wj = __shfl(w, sel);
      float2 raw = *(const float2*)(h2h + ((size_t)dj << 7) + colB);
      float2 f01 = __half22float2(*(const __half2*)&raw.x);
      float2 f23 = __half22float2(*(const __half2*)&raw.y);
      a0 += wj * f01.x; a1 += wj * f01.y; a2v += wj * f23.x; a3 += wj * f23.y;
    }
    if (jj < cnt) {
      int dj = __shfl(d, jj);
      float wj = __shfl(w, jj);
      if (hi == 0) {
        float2 raw = *(const float2*)(h2h + ((size_t)dj << 7) + colB);
        float2 f01 = __half22float2(*(const __half2*)&raw.x);
        float2 f23 = __half22float2(*(const __half2*)&raw.y);
        a0 += wj * f01.x; a1 += wj * f01.y; a2v += wj * f23.x; a3 += wj * f23.y;
      }
    }
  }
  a0 += __shfl_xor(a0, 32); a1 += __shfl_xor(a1, 32);
  a2v += __shfl_xor(a2v, 32); a3 += __shfl_xor(a3, 32);
  float rsum = rsumL;
#pragma unroll
  for (int off = 32; off > 0; off >>= 1) rsum += __shfl_xor(rsum, off);
  float inv = 1.f / (rsum + EPS_DENOM);
  if (hi == 0) {
    *(float4*)(out + (size_t)wv * 128 + colB) =
        make_float4(elu_f(a0 * inv), elu_f(a1 * inv), elu_f(a2v * inv), elu_f(a3 * inv));
  }
}

extern "C" void kernel_launch(void* const* d_in, const int* in_sizes, int n_in,
                              void* d_out, int out_size, void* d_ws, size_t ws_size,
                              hipStream_t stream) {
  (void)n_in; (void)out_size; (void)ws_size;
  const float* x  = (const float*)d_in[0];
  const int*   ei = (const int*)d_in[1];
  const float* W1 = (const float*)d_in[2];
  const float* a1 = (const float*)d_in[3];
  const float* W2 = (const float*)d_in[4];
  const float* a2 = (const float*)d_in[5];
  float* out = (float*)d_out;
  const int N = in_sizes[0] / NFEAT;
  const int E = in_sizes[1] / 2;
  const int* src  = ei;
  const int* dstv = ei + E;

  int shift = 7;
  while ((((N - 1) >> shift) + 1) > MAXNB) ++shift;
  const int NB = ((N - 1) >> shift) + 1;

  // d_out = h2f f32 [N,128] during GEMM2 accumulation (dead before agg2 writes out)
  float* h2f = out;

  // workspace carve-up (~92 MB)
  char* wp = (char*)d_ws;
  size_t off = 0;
  auto mk = [&](size_t bytes) -> void* {
    void* p = wp + off;
    off += (bytes + 255) & ~(size_t)255;
    return p;
  };
  size_t szR0 = (size_t)N * 128 * 2;
  if ((size_t)E * 8 > szR0) szR0 = (size_t)E * 8;
  f16*  hout2    = (f16*)mk(szR0);                    // [N,128] f16; staging aliases
  int2* staging  = (int2*)hout2;
  f16*  h2x      = (f16*)mk((size_t)N * 128 * 2);     // h1t [N,64] then h2h [N,128]
  f16*  h1t      = h2x;
  f16*  h2h      = h2x;
  int*  edge_dst = (int*)mk((size_t)E * 4);
  f16*  xh       = (f16*)mk((size_t)N * 128 * 2);
  float* ssrc    = (float*)mk((size_t)N * 4);
  float* sdst    = (float*)mk((size_t)N * 4);
  float* s2src   = (float*)mk((size_t)N * 4);
  float* s2dst   = (float*)mk((size_t)N * 4);
  int*  rp       = (int*)mk((size_t)(N + 1) * 4);
  int*  bhist    = (int*)mk((size_t)(NB + 1) * 4);
  int*  bbase    = (int*)mk((size_t)(NB + 1) * 4);
  int*  bcur     = (int*)mk((size_t)(NB + 1) * 4);
  f16*  w1t      = (f16*)mk((size_t)NHEADS * 64 * 128 * 2);
  f16*  w2t      = (f16*)mk((size_t)128 * 512 * 2);

  // dtype prep
  k_cvt_x<<<1024, 256, 0, stream>>>(x, xh, (long)N * 16);
  k_cvt_w<<<512, 256, 0, stream>>>(W1, W2, w1t, w2t);

  // CSR build
  hipMemsetAsync(bhist, 0, (size_t)NB * 4, stream);
  int binBlocks = (E + BIN_EPB - 1) / BIN_EPB;
  k_bhist<<<binBlocks, 256, 0, stream>>>(src, bhist, E, NB, shift);
  k_bscan<<<1, 1024, 0, stream>>>(bhist, bbase, bcur, rp, NB, N, E);
  k_binA<<<binBlocks, 256, 0, stream>>>(src, dstv, bcur, staging, E, NB, shift);
  k_binB<<<NB, 256, 0, stream>>>(staging, bbase, rp, edge_dst, N, shift);

  int wb = (N + 3) / 4;
  int gb = (N + 63) / 64;

  for (int h = 0; h < NHEADS; ++h) {
    k_gemm1<<<gb, 256, 0, stream>>>(xh, w1t + (size_t)h * 64 * 128, a1 + (size_t)h * 128,
                                    h1t, ssrc, sdst, N);
    k_agg1<<<wb, 256, 0, stream>>>(rp, edge_dst, (const __half*)h1t, ssrc, sdst,
                                   (__half*)(hout2 + (h & 1) * 64), N);
    if (h & 1) {
      int g = h >> 1;
      k_gemm2<<<gb, 256, 0, stream>>>(hout2, w2t, h2f, g * 128, g > 0 ? 1 : 0,
                                      g == 3 ? 1 : 0, a2, h2h, s2src, s2dst, N);
    }
  }

  k_agg2<<<wb, 256, 0, stream>>>(rp, edge_dst, (const __half*)h2h, s2src, s2dst, x, out, N);
}

// Round 7
// 1096.545 us; speedup vs baseline: 2.1189x; 1.2994x over previous
//
#include <hip/hip_runtime.h>
#include <hip/hip_fp16.h>

#define NFEAT 128
#define NHID 64
#define NOUT 128
#define NHEADS 8
#define ALPHA_SLOPE 0.2f
#define EPS_DENOM 1e-16f

#define MAXNB 1024      // max buckets
#define BIN_EPB 12288   // edges per block in binning kernels
#define BIN_CAP 6144    // max pairs per bucket held in LDS

typedef _Float16 f16;
typedef f16 f16x8 __attribute__((ext_vector_type(8)));
typedef float f32x4 __attribute__((ext_vector_type(4)));

static __device__ __forceinline__ float elu_f(float v) {
  return v > 0.f ? v : __expf(v) - 1.f;
}
static __device__ __forceinline__ float edge_w(float sc) {
  float lr = sc > 0.f ? sc : ALPHA_SLOPE * sc;
  return __expf(-lr);
}

// ---------------- dtype prep ----------------
__global__ void k_cvt_x(const float* __restrict__ x, f16* __restrict__ xh, long n8) {
  long i = (long)blockIdx.x * blockDim.x + threadIdx.x;
  long stride = (long)gridDim.x * blockDim.x;
  for (; i < n8; i += stride) {
    const float* p = x + i * 8;
    float4 v0 = *(const float4*)p;
    float4 v1 = *(const float4*)(p + 4);
    f16x8 o;
    o[0] = (f16)v0.x; o[1] = (f16)v0.y; o[2] = (f16)v0.z; o[3] = (f16)v0.w;
    o[4] = (f16)v1.x; o[5] = (f16)v1.y; o[6] = (f16)v1.z; o[7] = (f16)v1.w;
    *(f16x8*)(xh + i * 8) = o;
  }
}

// W1 [8][128][64] -> w1t [8][64][128] fp16 (c-major); W2 [512][128] -> w2t [128][512] fp16
__global__ void k_cvt_w(const float* __restrict__ W1, const float* __restrict__ W2,
                        f16* __restrict__ w1t, f16* __restrict__ w2t) {
  int idx = blockIdx.x * 256 + threadIdx.x;
  if (idx < NHEADS * 128 * 64) {
    int h = idx >> 13, rem = idx & 8191, c = rem >> 7, k = rem & 127;
    w1t[idx] = (f16)W1[h * 8192 + k * 64 + c];
  } else {
    int j = idx - NHEADS * 128 * 64;
    if (j < 128 * 512) {
      int c = j >> 9, k = j & 511;
      w2t[j] = (f16)W2[k * 128 + c];
    }
  }
}

// ---------------- CSR build: 2-pass bucketed counting sort ----------------
__global__ __launch_bounds__(256) void k_bhist(const int* __restrict__ src,
                                               int* __restrict__ bhist,
                                               int E, int NB, int shift) {
  __shared__ int h[MAXNB];
  int tid = threadIdx.x;
  for (int i = tid; i < NB; i += 256) h[i] = 0;
  __syncthreads();
  int base = blockIdx.x * BIN_EPB;
#pragma unroll 4
  for (int j = 0; j < BIN_EPB / 256; ++j) {
    int e = base + tid + j * 256;
    if (e < E) atomicAdd(&h[src[e] >> shift], 1);
  }
  __syncthreads();
  for (int i = tid; i < NB; i += 256)
    if (h[i]) atomicAdd(&bhist[i], h[i]);
}

__global__ __launch_bounds__(1024) void k_bscan(const int* __restrict__ bhist,
                                                int* __restrict__ bucket_base,
                                                int* __restrict__ bucket_cursor,
                                                int* __restrict__ rp,
                                                int NB, int N, int E) {
  __shared__ int sh[1024];
  int i = threadIdx.x;
  int v = (i < NB) ? bhist[i] : 0;
  sh[i] = v;
  __syncthreads();
  for (int off = 1; off < 1024; off <<= 1) {
    int add = (i >= off) ? sh[i - off] : 0;
    __syncthreads();
    sh[i] += add;
    __syncthreads();
  }
  if (i < NB) {
    int ex = sh[i] - v;
    bucket_base[i] = ex;
    bucket_cursor[i] = ex;
  }
  if (i == 0) {
    bucket_base[NB] = E;
    rp[N] = E;
  }
}

__global__ __launch_bounds__(256) void k_binA(const int* __restrict__ src,
                                              const int* __restrict__ dst,
                                              int* __restrict__ bucket_cursor,
                                              int2* __restrict__ staging,
                                              int E, int NB, int shift) {
  __shared__ int h[MAXNB];
  int tid = threadIdx.x;
  for (int i = tid; i < NB; i += 256) h[i] = 0;
  __syncthreads();
  int base = blockIdx.x * BIN_EPB;
#pragma unroll 4
  for (int j = 0; j < BIN_EPB / 256; ++j) {
    int e = base + tid + j * 256;
    if (e < E) atomicAdd(&h[src[e] >> shift], 1);
  }
  __syncthreads();
  for (int i = tid; i < NB; i += 256)
    if (h[i]) h[i] = atomicAdd(&bucket_cursor[i], h[i]);
  __syncthreads();
#pragma unroll 4
  for (int j = 0; j < BIN_EPB / 256; ++j) {
    int e = base + tid + j * 256;
    if (e < E) {
      int s = src[e];
      int slot = atomicAdd(&h[s >> shift], 1);
      staging[slot] = make_int2(s, dst[e]);
    }
  }
}

__global__ __launch_bounds__(256) void k_binB(const int2* __restrict__ staging,
                                              const int* __restrict__ bucket_base,
                                              int* __restrict__ rp,
                                              int* __restrict__ edge_dst,
                                              int N, int shift) {
  __shared__ int2 buf[BIN_CAP];
  __shared__ int rcnt[256], rsc[256];
  int tid = threadIdx.x;
  int b = blockIdx.x;
  int lo = bucket_base[b], hi = bucket_base[b + 1];
  int S = hi - lo;
  if (S > BIN_CAP) S = BIN_CAP;
  int R = 1 << shift;
  int rmask = R - 1;
  for (int i = tid; i < S; i += 256) buf[i] = staging[lo + i];
  if (tid < R) rcnt[tid] = 0;
  __syncthreads();
  for (int i = tid; i < S; i += 256) atomicAdd(&rcnt[buf[i].x & rmask], 1);
  __syncthreads();
  if (tid < R) rsc[tid] = rcnt[tid];
  __syncthreads();
  for (int off = 1; off < 256; off <<= 1) {
    int add = (tid >= off && tid < R) ? rsc[tid - off] : 0;
    __syncthreads();
    if (tid < R) rsc[tid] += add;
    __syncthreads();
  }
  int row0 = b << shift;
  if (tid < R) {
    int ex = rsc[tid] - rcnt[tid];
    rcnt[tid] = ex;
    if (row0 + tid < N) rp[row0 + tid] = lo + ex;
  }
  __syncthreads();
  for (int i = tid; i < S; i += 256) {
    int r = buf[i].x & rmask;
    int k = atomicAdd(&rcnt[r], 1);
    edge_dst[lo + k] = buf[i].y;
  }
}

// ---------------- MFMA GEMM1 (per head): h1pair[N,128] cols hsel*64.. = xh @ W1h ------
// + fused attention scores into packed ssrc2/sdst2 [N][2].
__global__ __launch_bounds__(256) void k_gemm1(
    const f16* __restrict__ xh, const f16* __restrict__ w1t,   // w1t: [64][128]
    const float* __restrict__ avec,                            // [128]
    f16* __restrict__ h1p, int hsel,
    float* __restrict__ ssrc2, float* __restrict__ sdst2, int N) {
  int wave = threadIdx.x >> 6;
  int lane = threadIdx.x & 63;
  int c = lane & 15, g = lane >> 4;
  int row0 = blockIdx.x * 64 + wave * 16;

  f16x8 bf[4][4];
#pragma unroll
  for (int t = 0; t < 4; ++t)
#pragma unroll
    for (int ks = 0; ks < 4; ++ks)
      bf[t][ks] = *(const f16x8*)(w1t + (t * 16 + c) * 128 + ks * 32 + g * 8);

  int arow = row0 + c; if (arow > N - 1) arow = N - 1;
  const f16* ap = xh + (size_t)arow * 128 + g * 8;

  f32x4 acc[4];
#pragma unroll
  for (int t = 0; t < 4; ++t) acc[t] = (f32x4){0.f, 0.f, 0.f, 0.f};
#pragma unroll
  for (int ks = 0; ks < 4; ++ks) {
    f16x8 af = *(const f16x8*)(ap + ks * 32);
#pragma unroll
    for (int t = 0; t < 4; ++t)
      acc[t] = __builtin_amdgcn_mfma_f32_16x16x32_f16(af, bf[t][ks], acc[t], 0, 0, 0);
  }

  float av0[4], av1[4];
#pragma unroll
  for (int t = 0; t < 4; ++t) {
    av0[t] = avec[t * 16 + c];
    av1[t] = avec[64 + t * 16 + c];
  }
#pragma unroll
  for (int j = 0; j < 4; ++j) {
    int r = row0 + g * 4 + j;
    float s0 = 0.f, s1 = 0.f;
#pragma unroll
    for (int t = 0; t < 4; ++t) {
      float v = acc[t][j];
      if (r < N) h1p[(size_t)r * 128 + hsel * 64 + t * 16 + c] = (f16)v;
      s0 += v * av0[t];
      s1 += v * av1[t];
    }
    s0 += __shfl_xor(s0, 1); s0 += __shfl_xor(s0, 2);
    s0 += __shfl_xor(s0, 4); s0 += __shfl_xor(s0, 8);
    s1 += __shfl_xor(s1, 1); s1 += __shfl_xor(s1, 2);
    s1 += __shfl_xor(s1, 4); s1 += __shfl_xor(s1, 8);
    if (c == 0 && r < N) { ssrc2[r * 2 + hsel] = s0; sdst2[r * 2 + hsel] = s1; }
  }
}

// ---------------- MFMA GEMM2 (per 2-head group): h2f[N,128] (+)= hout2[N,128] @ W2grp --
__global__ __launch_bounds__(256) void k_gemm2(
    const f16* __restrict__ hout2, const f16* __restrict__ w2t,   // w2t: [128][512]
    float* __restrict__ h2f, int kbase, int accum, int fuse,
    const float* __restrict__ a2, f16* __restrict__ h2h,
    float* __restrict__ s2src, float* __restrict__ s2dst, int N) {
  int wave = threadIdx.x >> 6;
  int lane = threadIdx.x & 63;
  int c = lane & 15, g = lane >> 4;
  int row0 = blockIdx.x * 64 + wave * 16;

  f32x4 acc[8];
  if (accum) {
#pragma unroll
    for (int t = 0; t < 8; ++t)
#pragma unroll
      for (int j = 0; j < 4; ++j) {
        int r = row0 + g * 4 + j;
        acc[t][j] = (r < N) ? h2f[(size_t)r * 128 + t * 16 + c] : 0.f;
      }
  } else {
#pragma unroll
    for (int t = 0; t < 8; ++t) acc[t] = (f32x4){0.f, 0.f, 0.f, 0.f};
  }

  int arow = row0 + c; if (arow > N - 1) arow = N - 1;
  const f16* ap = hout2 + (size_t)arow * 128 + g * 8;
#pragma unroll
  for (int ks = 0; ks < 4; ++ks) {
    f16x8 af = *(const f16x8*)(ap + ks * 32);
#pragma unroll
    for (int t = 0; t < 8; ++t) {
      f16x8 bfr = *(const f16x8*)(w2t + (size_t)(t * 16 + c) * 512 + kbase + ks * 32 + g * 8);
      acc[t] = __builtin_amdgcn_mfma_f32_16x16x32_f16(af, bfr, acc[t], 0, 0, 0);
    }
  }

  if (!fuse) {
#pragma unroll
    for (int t = 0; t < 8; ++t)
#pragma unroll
      for (int j = 0; j < 4; ++j) {
        int r = row0 + g * 4 + j;
        if (r < N) h2f[(size_t)r * 128 + t * 16 + c] = acc[t][j];
      }
  } else {
    float av0[8], av1[8];
#pragma unroll
    for (int t = 0; t < 8; ++t) {
      av0[t] = a2[t * 16 + c];
      av1[t] = a2[128 + t * 16 + c];
    }
#pragma unroll
    for (int j = 0; j < 4; ++j) {
      int r = row0 + g * 4 + j;
      float s0 = 0.f, s1 = 0.f;
#pragma unroll
      for (int t = 0; t < 8; ++t) {
        float v = acc[t][j];
        if (r < N) h2h[(size_t)r * 128 + t * 16 + c] = (f16)v;
        s0 += v * av0[t];
        s1 += v * av1[t];
      }
      s0 += __shfl_xor(s0, 1); s0 += __shfl_xor(s0, 2);
      s0 += __shfl_xor(s0, 4); s0 += __shfl_xor(s0, 8);
      s1 += __shfl_xor(s1, 1); s1 += __shfl_xor(s1, 2);
      s1 += __shfl_xor(s1, 4); s1 += __shfl_xor(s1, 8);
      if (c == 0 && r < N) { s2src[r] = s0; s2dst[r] = s1; }
    }
  }
}

// ---------------- layer-1 head-PAIR aggregation: one edge walk, 2 heads ----------------
// phase 1: lane = (edge e = lane>>1, head = lane&1), 32 edges/chunk, one exp each.
// phase 2: half-wave per edge; 32 lanes x 8 B = full 256 B h1pair row.
__global__ void k_agg1pair(const int* __restrict__ rp, const int* __restrict__ edge_dst,
                           const __half* __restrict__ h1p, const float* __restrict__ ssrc2,
                           const float* __restrict__ sdst2, __half* __restrict__ houtp,
                           int N) {
  int wv = (blockIdx.x * blockDim.x + threadIdx.x) >> 6;
  int lane = threadIdx.x & 63;
  if (wv >= N) return;
  int e0 = rp[wv], e1 = rp[wv + 1];
  int hi = lane >> 5;            // payload: which edge of the pair
  int li = lane & 31;            // payload: 4-half col group
  int headP = li >> 4;           // payload head (cols 0-63 -> 0, 64-127 -> 1)
  int hW = lane & 1;             // phase-1 head
  float ssW = ssrc2[(size_t)wv * 2 + hW];
  float a0 = 0.f, a1 = 0.f, a2v = 0.f, a3 = 0.f, rsumL = 0.f;

  for (int base = e0; base < e1; base += 32) {
    int cnt = e1 - base; if (cnt > 32) cnt = 32;
    int d = 0; float w = 0.f;
    int eIdx = lane >> 1;
    if (eIdx < cnt) {
      d = edge_dst[base + eIdx];
      w = edge_w(ssW + sdst2[(size_t)d * 2 + hW]);
    }
    rsumL += w;
    int jj = 0;
#pragma unroll 4
    for (; jj + 2 <= cnt; jj += 2) {
      int e = jj + hi;
      int dj = __shfl(d, e * 2);
      float wj = __shfl(w, e * 2 + headP);
      float2 raw = *(const float2*)(h1p + ((size_t)dj << 7) + li * 4);
      float2 f01 = __half22float2(*(const __half2*)&raw.x);
      float2 f23 = __half22float2(*(const __half2*)&raw.y);
      a0 += wj * f01.x; a1 += wj * f01.y; a2v += wj * f23.x; a3 += wj * f23.y;
    }
    if (jj < cnt) {              // odd tail edge: half-wave 0 handles it
      int dj = __shfl(d, jj * 2);
      float wj = __shfl(w, jj * 2 + headP);
      if (hi == 0) {
        float2 raw = *(const float2*)(h1p + ((size_t)dj << 7) + li * 4);
        float2 f01 = __half22float2(*(const __half2*)&raw.x);
        float2 f23 = __half22float2(*(const __half2*)&raw.y);
        a0 += wj * f01.x; a1 += wj * f01.y; a2v += wj * f23.x; a3 += wj * f23.y;
      }
    }
  }
  a0 += __shfl_xor(a0, 32); a1 += __shfl_xor(a1, 32);
  a2v += __shfl_xor(a2v, 32); a3 += __shfl_xor(a3, 32);
  float rsum = rsumL;
#pragma unroll
  for (int s = 2; s <= 32; s <<= 1) rsum += __shfl_xor(rsum, s);  // per-parity sums
  float rh = __shfl(rsum, headP);       // rsum for this lane's payload head
  float inv = 1.f / (rh + EPS_DENOM);
  if (hi == 0) {
    float2 stv;
    ((__half2*)&stv)[0] = __float22half2_rn(make_float2(elu_f(a0 * inv), elu_f(a1 * inv)));
    ((__half2*)&stv)[1] = __float22half2_rn(make_float2(elu_f(a2v * inv), elu_f(a3 * inv)));
    *(float2*)(houtp + (size_t)wv * 128 + li * 4) = stv;
  }
}

// ---------------- layer-2 aggregation: cooperative-edge + deg==0 fallback + ELU --------
__global__ void k_agg2(const int* __restrict__ rp, const int* __restrict__ edge_dst,
                       const __half* __restrict__ h2h, const float* __restrict__ ssrc,
                       const float* __restrict__ sdst, const float* __restrict__ x,
                       float* __restrict__ out, int N) {
  int wv = (blockIdx.x * blockDim.x + threadIdx.x) >> 6;
  int lane = threadIdx.x & 63;
  if (wv >= N) return;
  int e0 = rp[wv], e1 = rp[wv + 1];
  if (e0 == e1) {
    float2 xv = *(const float2*)(x + (size_t)wv * 128 + 2 * lane);
    *(float2*)(out + (size_t)wv * 128 + 2 * lane) = make_float2(elu_f(xv.x), elu_f(xv.y));
    return;
  }
  float ss = ssrc[wv];
  int hi = lane >> 5;
  int colB = (lane & 31) << 2;
  float a0 = 0.f, a1 = 0.f, a2v = 0.f, a3 = 0.f, rsumL = 0.f;
  for (int base = e0; base < e1; base += 64) {
    int cnt = e1 - base; if (cnt > 64) cnt = 64;
    int d = 0; float w = 0.f;
    if (lane < cnt) {
      d = edge_dst[base + lane];
      w = edge_w(ss + sdst[d]);
    }
    rsumL += w;
    int jj = 0;
#pragma unroll 4
    for (; jj + 2 <= cnt; jj += 2) {
      int sel = jj + hi;
      int dj = __shfl(d, sel);
      float wj = __shfl(w, sel);
      float2 raw = *(const float2*)(h2h + ((size_t)dj << 7) + colB);
      float2 f01 = __half22float2(*(const __half2*)&raw.x);
      float2 f23 = __half22float2(*(const __half2*)&raw.y);
      a0 += wj * f01.x; a1 += wj * f01.y; a2v += wj * f23.x; a3 += wj * f23.y;
    }
    if (jj < cnt) {
      int dj = __shfl(d, jj);
      float wj = __shfl(w, jj);
      if (hi == 0) {
        float2 raw = *(const float2*)(h2h + ((size_t)dj << 7) + colB);
        float2 f01 = __half22float2(*(const __half2*)&raw.x);
        float2 f23 = __half22float2(*(const __half2*)&raw.y);
        a0 += wj * f01.x; a1 += wj * f01.y; a2v += wj * f23.x; a3 += wj * f23.y;
      }
    }
  }
  a0 += __shfl_xor(a0, 32); a1 += __shfl_xor(a1, 32);
  a2v += __shfl_xor(a2v, 32); a3 += __shfl_xor(a3, 32);
  float rsum = rsumL;
#pragma unroll
  for (int off = 32; off > 0; off >>= 1) rsum += __shfl_xor(rsum, off);
  float inv = 1.f / (rsum + EPS_DENOM);
  if (hi == 0) {
    *(float4*)(out + (size_t)wv * 128 + colB) =
        make_float4(elu_f(a0 * inv), elu_f(a1 * inv), elu_f(a2v * inv), elu_f(a3 * inv));
  }
}

extern "C" void kernel_launch(void* const* d_in, const int* in_sizes, int n_in,
                              void* d_out, int out_size, void* d_ws, size_t ws_size,
                              hipStream_t stream) {
  (void)n_in; (void)out_size; (void)ws_size;
  const float* x  = (const float*)d_in[0];
  const int*   ei = (const int*)d_in[1];
  const float* W1 = (const float*)d_in[2];
  const float* a1 = (const float*)d_in[3];
  const float* W2 = (const float*)d_in[4];
  const float* a2 = (const float*)d_in[5];
  float* out = (float*)d_out;
  const int N = in_sizes[0] / NFEAT;
  const int E = in_sizes[1] / 2;
  const int* src  = ei;
  const int* dstv = ei + E;

  int shift = 7;
  while ((((N - 1) >> shift) + 1) > MAXNB) ++shift;
  const int NB = ((N - 1) >> shift) + 1;

  // d_out = h2f f32 [N,128] during GEMM2 accumulation (dead before agg2 writes out)
  float* h2f = out;

  // workspace carve-up (~92 MB)
  char* wp = (char*)d_ws;
  size_t off = 0;
  auto mk = [&](size_t bytes) -> void* {
    void* p = wp + off;
    off += (bytes + 255) & ~(size_t)255;
    return p;
  };
  size_t szR0 = (size_t)N * 128 * 2;
  if ((size_t)E * 8 > szR0) szR0 = (size_t)E * 8;
  f16*  hout2    = (f16*)mk(szR0);                    // [N,128] f16; staging aliases
  int2* staging  = (int2*)hout2;
  f16*  h1pair   = (f16*)mk((size_t)N * 128 * 2);     // [N,128] pair tile; h2h aliases
  f16*  h2h      = h1pair;
  int*  edge_dst = (int*)mk((size_t)E * 4);
  f16*  xh       = (f16*)mk((size_t)N * 128 * 2);
  float* ssrc2   = (float*)mk((size_t)N * 8);
  float* sdst2   = (float*)mk((size_t)N * 8);
  float* s2src   = (float*)mk((size_t)N * 4);
  float* s2dst   = (float*)mk((size_t)N * 4);
  int*  rp       = (int*)mk((size_t)(N + 1) * 4);
  int*  bhist    = (int*)mk((size_t)(NB + 1) * 4);
  int*  bbase    = (int*)mk((size_t)(NB + 1) * 4);
  int*  bcur     = (int*)mk((size_t)(NB + 1) * 4);
  f16*  w1t      = (f16*)mk((size_t)NHEADS * 64 * 128 * 2);
  f16*  w2t      = (f16*)mk((size_t)128 * 512 * 2);

  // dtype prep
  k_cvt_x<<<1024, 256, 0, stream>>>(x, xh, (long)N * 16);
  k_cvt_w<<<512, 256, 0, stream>>>(W1, W2, w1t, w2t);

  // CSR build
  hipMemsetAsync(bhist, 0, (size_t)NB * 4, stream);
  int binBlocks = (E + BIN_EPB - 1) / BIN_EPB;
  k_bhist<<<binBlocks, 256, 0, stream>>>(src, bhist, E, NB, shift);
  k_bscan<<<1, 1024, 0, stream>>>(bhist, bbase, bcur, rp, NB, N, E);
  k_binA<<<binBlocks, 256, 0, stream>>>(src, dstv, bcur, staging, E, NB, shift);
  k_binB<<<NB, 256, 0, stream>>>(staging, bbase, rp, edge_dst, N, shift);

  int wb = (N + 3) / 4;
  int gb = (N + 63) / 64;

  for (int h = 0; h < NHEADS; ++h) {
    k_gemm1<<<gb, 256, 0, stream>>>(xh, w1t + (size_t)h * 64 * 128, a1 + (size_t)h * 128,
                                    h1pair, h & 1, ssrc2, sdst2, N);
    if (h & 1) {
      int g = h >> 1;
      k_agg1pair<<<wb, 256, 0, stream>>>(rp, edge_dst, (const __half*)h1pair,
                                         ssrc2, sdst2, (__half*)hout2, N);
      k_gemm2<<<gb, 256, 0, stream>>>(hout2, w2t, h2f, g * 128, g > 0 ? 1 : 0,
                                      g == 3 ? 1 : 0, a2, h2h, s2src, s2dst, N);
    }
  }

  k_agg2<<<wb, 256, 0, stream>>>(rp, edge_dst, (const __half*)h2h, s2src, s2dst, x, out, N);
}

// Round 8
// 1070.072 us; speedup vs baseline: 2.1714x; 1.0247x over previous
//
#include <hip/hip_runtime.h>
#include <hip/hip_fp16.h>

#define NFEAT 128
#define NHID 64
#define NOUT 128
#define NHEADS 8
#define ALPHA_SLOPE 0.2f
#define EPS_DENOM 1e-16f

#define MAXNB 1024      // max buckets
#define BIN_EPB 12288   // edges per block in binning kernels
#define BIN_CAP 6144    // max pairs per bucket held in LDS

typedef _Float16 f16;
typedef f16 f16x8 __attribute__((ext_vector_type(8)));
typedef float f32x4 __attribute__((ext_vector_type(4)));

static __device__ __forceinline__ float elu_f(float v) {
  return v > 0.f ? v : __expf(v) - 1.f;
}
static __device__ __forceinline__ float edge_w(float sc) {
  float lr = sc > 0.f ? sc : ALPHA_SLOPE * sc;
  return __expf(-lr);
}

// ---------------- dtype prep ----------------
__global__ void k_cvt_x(const float* __restrict__ x, f16* __restrict__ xh, long n8) {
  long i = (long)blockIdx.x * blockDim.x + threadIdx.x;
  long stride = (long)gridDim.x * blockDim.x;
  for (; i < n8; i += stride) {
    const float* p = x + i * 8;
    float4 v0 = *(const float4*)p;
    float4 v1 = *(const float4*)(p + 4);
    f16x8 o;
    o[0] = (f16)v0.x; o[1] = (f16)v0.y; o[2] = (f16)v0.z; o[3] = (f16)v0.w;
    o[4] = (f16)v1.x; o[5] = (f16)v1.y; o[6] = (f16)v1.z; o[7] = (f16)v1.w;
    *(f16x8*)(xh + i * 8) = o;
  }
}

// W1 [8][128][64] -> w1t [8][64][128] fp16 (c-major); W2 [512][128] -> w2t [128][512] fp16
__global__ void k_cvt_w(const float* __restrict__ W1, const float* __restrict__ W2,
                        f16* __restrict__ w1t, f16* __restrict__ w2t) {
  int idx = blockIdx.x * 256 + threadIdx.x;
  if (idx < NHEADS * 128 * 64) {
    int h = idx >> 13, rem = idx & 8191, c = rem >> 7, k = rem & 127;
    w1t[idx] = (f16)W1[h * 8192 + k * 64 + c];
  } else {
    int j = idx - NHEADS * 128 * 64;
    if (j < 128 * 512) {
      int c = j >> 9, k = j & 511;
      w2t[j] = (f16)W2[k * 128 + c];
    }
  }
}

// ---------------- CSR build: 2-pass bucketed counting sort ----------------
__global__ __launch_bounds__(256) void k_bhist(const int* __restrict__ src,
                                               int* __restrict__ bhist,
                                               int E, int NB, int shift) {
  __shared__ int h[MAXNB];
  int tid = threadIdx.x;
  for (int i = tid; i < NB; i += 256) h[i] = 0;
  __syncthreads();
  int base = blockIdx.x * BIN_EPB;
#pragma unroll 4
  for (int j = 0; j < BIN_EPB / 256; ++j) {
    int e = base + tid + j * 256;
    if (e < E) atomicAdd(&h[src[e] >> shift], 1);
  }
  __syncthreads();
  for (int i = tid; i < NB; i += 256)
    if (h[i]) atomicAdd(&bhist[i], h[i]);
}

__global__ __launch_bounds__(1024) void k_bscan(const int* __restrict__ bhist,
                                                int* __restrict__ bucket_base,
                                                int* __restrict__ bucket_cursor,
                                                int* __restrict__ rp,
                                                int NB, int N, int E) {
  __shared__ int sh[1024];
  int i = threadIdx.x;
  int v = (i < NB) ? bhist[i] : 0;
  sh[i] = v;
  __syncthreads();
  for (int off = 1; off < 1024; off <<= 1) {
    int add = (i >= off) ? sh[i - off] : 0;
    __syncthreads();
    sh[i] += add;
    __syncthreads();
  }
  if (i < NB) {
    int ex = sh[i] - v;
    bucket_base[i] = ex;
    bucket_cursor[i] = ex;
  }
  if (i == 0) {
    bucket_base[NB] = E;
    rp[N] = E;
  }
}

__global__ __launch_bounds__(256) void k_binA(const int* __restrict__ src,
                                              const int* __restrict__ dst,
                                              int* __restrict__ bucket_cursor,
                                              int2* __restrict__ staging,
                                              int E, int NB, int shift) {
  __shared__ int h[MAXNB];
  int tid = threadIdx.x;
  for (int i = tid; i < NB; i += 256) h[i] = 0;
  __syncthreads();
  int base = blockIdx.x * BIN_EPB;
#pragma unroll 4
  for (int j = 0; j < BIN_EPB / 256; ++j) {
    int e = base + tid + j * 256;
    if (e < E) atomicAdd(&h[src[e] >> shift], 1);
  }
  __syncthreads();
  for (int i = tid; i < NB; i += 256)
    if (h[i]) h[i] = atomicAdd(&bucket_cursor[i], h[i]);
  __syncthreads();
#pragma unroll 4
  for (int j = 0; j < BIN_EPB / 256; ++j) {
    int e = base + tid + j * 256;
    if (e < E) {
      int s = src[e];
      int slot = atomicAdd(&h[s >> shift], 1);
      staging[slot] = make_int2(s, dst[e]);
    }
  }
}

__global__ __launch_bounds__(256) void k_binB(const int2* __restrict__ staging,
                                              const int* __restrict__ bucket_base,
                                              int* __restrict__ rp,
                                              int* __restrict__ edge_dst,
                                              int N, int shift) {
  __shared__ int2 buf[BIN_CAP];
  __shared__ int rcnt[256], rsc[256];
  int tid = threadIdx.x;
  int b = blockIdx.x;
  int lo = bucket_base[b], hi = bucket_base[b + 1];
  int S = hi - lo;
  if (S > BIN_CAP) S = BIN_CAP;
  int R = 1 << shift;
  int rmask = R - 1;
  for (int i = tid; i < S; i += 256) buf[i] = staging[lo + i];
  if (tid < R) rcnt[tid] = 0;
  __syncthreads();
  for (int i = tid; i < S; i += 256) atomicAdd(&rcnt[buf[i].x & rmask], 1);
  __syncthreads();
  if (tid < R) rsc[tid] = rcnt[tid];
  __syncthreads();
  for (int off = 1; off < 256; off <<= 1) {
    int add = (tid >= off && tid < R) ? rsc[tid - off] : 0;
    __syncthreads();
    if (tid < R) rsc[tid] += add;
    __syncthreads();
  }
  int row0 = b << shift;
  if (tid < R) {
    int ex = rsc[tid] - rcnt[tid];
    rcnt[tid] = ex;
    if (row0 + tid < N) rp[row0 + tid] = lo + ex;
  }
  __syncthreads();
  for (int i = tid; i < S; i += 256) {
    int r = buf[i].x & rmask;
    int k = atomicAdd(&rcnt[r], 1);
    edge_dst[lo + k] = buf[i].y;
  }
}

// ---------------- MFMA GEMM1 head-pair: h1pair[N,128] = xh @ [W1h0 | W1h1] ------------
// cols 0..63 = head 2g, cols 64..127 = head 2g+1 (w1t stacked layout makes the address
// expression uniform: head1 base = head0 base + 8192). Fused packed scores [N][2].
__global__ __launch_bounds__(256) void k_gemm1pair(
    const f16* __restrict__ xh, const f16* __restrict__ w1p,   // w1p: [128][128] stacked
    const float* __restrict__ a1p,                             // [2][128]
    f16* __restrict__ h1p, float* __restrict__ ssrc2, float* __restrict__ sdst2, int N) {
  int wave = threadIdx.x >> 6;
  int lane = threadIdx.x & 63;
  int c = lane & 15, g = lane >> 4;
  int row0 = blockIdx.x * 64 + wave * 16;

  f32x4 acc[8];
#pragma unroll
  for (int t = 0; t < 8; ++t) acc[t] = (f32x4){0.f, 0.f, 0.f, 0.f};

  int arow = row0 + c; if (arow > N - 1) arow = N - 1;
  const f16* ap = xh + (size_t)arow * 128 + g * 8;
#pragma unroll
  for (int ks = 0; ks < 4; ++ks) {
    f16x8 af = *(const f16x8*)(ap + ks * 32);
#pragma unroll
    for (int t = 0; t < 8; ++t) {
      f16x8 bfr = *(const f16x8*)(w1p + (size_t)(t * 16 + c) * 128 + ks * 32 + g * 8);
      acc[t] = __builtin_amdgcn_mfma_f32_16x16x32_f16(af, bfr, acc[t], 0, 0, 0);
    }
  }

  // attention vectors: head0 -> t=0..3 (a1p[0..127]), head1 -> t=4..7 (a1p[128..255])
  float av0[8], av1[8];
#pragma unroll
  for (int t = 0; t < 8; ++t) {
    int hsel = t >> 2, tt = t & 3;
    av0[t] = a1p[hsel * 128 + tt * 16 + c];
    av1[t] = a1p[hsel * 128 + 64 + tt * 16 + c];
  }
#pragma unroll
  for (int j = 0; j < 4; ++j) {
    int r = row0 + g * 4 + j;
    float s0h0 = 0.f, s1h0 = 0.f, s0h1 = 0.f, s1h1 = 0.f;
#pragma unroll
    for (int t = 0; t < 8; ++t) {
      float v = acc[t][j];
      if (r < N) h1p[(size_t)r * 128 + t * 16 + c] = (f16)v;
      if (t < 4) { s0h0 += v * av0[t]; s1h0 += v * av1[t]; }
      else       { s0h1 += v * av0[t]; s1h1 += v * av1[t]; }
    }
#pragma unroll
    for (int off = 1; off <= 8; off <<= 1) {
      s0h0 += __shfl_xor(s0h0, off); s1h0 += __shfl_xor(s1h0, off);
      s0h1 += __shfl_xor(s0h1, off); s1h1 += __shfl_xor(s1h1, off);
    }
    if (c == 0 && r < N) {
      ssrc2[r * 2 + 0] = s0h0; sdst2[r * 2 + 0] = s1h0;
      ssrc2[r * 2 + 1] = s0h1; sdst2[r * 2 + 1] = s1h1;
    }
  }
}

// ---------------- MFMA GEMM2 (per 2-head group): h2f[N,128] (+)= hout2[N,128] @ W2grp --
__global__ __launch_bounds__(256) void k_gemm2(
    const f16* __restrict__ hout2, const f16* __restrict__ w2t,   // w2t: [128][512]
    float* __restrict__ h2f, int kbase, int accum, int fuse,
    const float* __restrict__ a2, f16* __restrict__ h2h,
    float* __restrict__ s2src, float* __restrict__ s2dst, int N) {
  int wave = threadIdx.x >> 6;
  int lane = threadIdx.x & 63;
  int c = lane & 15, g = lane >> 4;
  int row0 = blockIdx.x * 64 + wave * 16;

  f32x4 acc[8];
  if (accum) {
#pragma unroll
    for (int t = 0; t < 8; ++t)
#pragma unroll
      for (int j = 0; j < 4; ++j) {
        int r = row0 + g * 4 + j;
        acc[t][j] = (r < N) ? h2f[(size_t)r * 128 + t * 16 + c] : 0.f;
      }
  } else {
#pragma unroll
    for (int t = 0; t < 8; ++t) acc[t] = (f32x4){0.f, 0.f, 0.f, 0.f};
  }

  int arow = row0 + c; if (arow > N - 1) arow = N - 1;
  const f16* ap = hout2 + (size_t)arow * 128 + g * 8;
#pragma unroll
  for (int ks = 0; ks < 4; ++ks) {
    f16x8 af = *(const f16x8*)(ap + ks * 32);
#pragma unroll
    for (int t = 0; t < 8; ++t) {
      f16x8 bfr = *(const f16x8*)(w2t + (size_t)(t * 16 + c) * 512 + kbase + ks * 32 + g * 8);
      acc[t] = __builtin_amdgcn_mfma_f32_16x16x32_f16(af, bfr, acc[t], 0, 0, 0);
    }
  }

  if (!fuse) {
#pragma unroll
    for (int t = 0; t < 8; ++t)
#pragma unroll
      for (int j = 0; j < 4; ++j) {
        int r = row0 + g * 4 + j;
        if (r < N) h2f[(size_t)r * 128 + t * 16 + c] = acc[t][j];
      }
  } else {
    float av0[8], av1[8];
#pragma unroll
    for (int t = 0; t < 8; ++t) {
      av0[t] = a2[t * 16 + c];
      av1[t] = a2[128 + t * 16 + c];
    }
#pragma unroll
    for (int j = 0; j < 4; ++j) {
      int r = row0 + g * 4 + j;
      float s0 = 0.f, s1 = 0.f;
#pragma unroll
      for (int t = 0; t < 8; ++t) {
        float v = acc[t][j];
        if (r < N) h2h[(size_t)r * 128 + t * 16 + c] = (f16)v;
        s0 += v * av0[t];
        s1 += v * av1[t];
      }
      s0 += __shfl_xor(s0, 1); s0 += __shfl_xor(s0, 2);
      s0 += __shfl_xor(s0, 4); s0 += __shfl_xor(s0, 8);
      s1 += __shfl_xor(s1, 1); s1 += __shfl_xor(s1, 2);
      s1 += __shfl_xor(s1, 4); s1 += __shfl_xor(s1, 8);
      if (c == 0 && r < N) { s2src[r] = s0; s2dst[r] = s1; }
    }
  }
}

// ---------------- layer-1 head-PAIR aggregation: one edge walk, 2 heads ----------------
__global__ void k_agg1pair(const int* __restrict__ rp, const int* __restrict__ edge_dst,
                           const __half* __restrict__ h1p, const float* __restrict__ ssrc2,
                           const float* __restrict__ sdst2, __half* __restrict__ houtp,
                           int N) {
  int wv = (blockIdx.x * blockDim.x + threadIdx.x) >> 6;
  int lane = threadIdx.x & 63;
  if (wv >= N) return;
  int e0 = rp[wv], e1 = rp[wv + 1];
  int hi = lane >> 5;            // payload: which edge of the pair
  int li = lane & 31;            // payload: 4-half col group
  int headP = li >> 4;           // payload head (cols 0-63 -> 0, 64-127 -> 1)
  int hW = lane & 1;             // phase-1 head
  float ssW = ssrc2[(size_t)wv * 2 + hW];
  float a0 = 0.f, a1 = 0.f, a2v = 0.f, a3 = 0.f, rsumL = 0.f;

  for (int base = e0; base < e1; base += 32) {
    int cnt = e1 - base; if (cnt > 32) cnt = 32;
    int d = 0; float w = 0.f;
    int eIdx = lane >> 1;
    if (eIdx < cnt) {
      d = edge_dst[base + eIdx];
      w = edge_w(ssW + sdst2[(size_t)d * 2 + hW]);
    }
    rsumL += w;
    int jj = 0;
#pragma unroll 4
    for (; jj + 2 <= cnt; jj += 2) {
      int e = jj + hi;
      int dj = __shfl(d, e * 2);
      float wj = __shfl(w, e * 2 + headP);
      float2 raw = *(const float2*)(h1p + ((size_t)dj << 7) + li * 4);
      float2 f01 = __half22float2(*(const __half2*)&raw.x);
      float2 f23 = __half22float2(*(const __half2*)&raw.y);
      a0 += wj * f01.x; a1 += wj * f01.y; a2v += wj * f23.x; a3 += wj * f23.y;
    }
    if (jj < cnt) {              // odd tail edge: half-wave 0 handles it
      int dj = __shfl(d, jj * 2);
      float wj = __shfl(w, jj * 2 + headP);
      if (hi == 0) {
        float2 raw = *(const float2*)(h1p + ((size_t)dj << 7) + li * 4);
        float2 f01 = __half22float2(*(const __half2*)&raw.x);
        float2 f23 = __half22float2(*(const __half2*)&raw.y);
        a0 += wj * f01.x; a1 += wj * f01.y; a2v += wj * f23.x; a3 += wj * f23.y;
      }
    }
  }
  a0 += __shfl_xor(a0, 32); a1 += __shfl_xor(a1, 32);
  a2v += __shfl_xor(a2v, 32); a3 += __shfl_xor(a3, 32);
  float rsum = rsumL;
#pragma unroll
  for (int s = 2; s <= 32; s <<= 1) rsum += __shfl_xor(rsum, s);  // per-parity sums
  float rh = __shfl(rsum, headP);       // rsum for this lane's payload head
  float inv = 1.f / (rh + EPS_DENOM);
  if (hi == 0) {
    float2 stv;
    ((__half2*)&stv)[0] = __float22half2_rn(make_float2(elu_f(a0 * inv), elu_f(a1 * inv)));
    ((__half2*)&stv)[1] = __float22half2_rn(make_float2(elu_f(a2v * inv), elu_f(a3 * inv)));
    *(float2*)(houtp + (size_t)wv * 128 + li * 4) = stv;
  }
}

// ---------------- layer-2 aggregation: cooperative-edge + deg==0 fallback + ELU --------
__global__ void k_agg2(const int* __restrict__ rp, const int* __restrict__ edge_dst,
                       const __half* __restrict__ h2h, const float* __restrict__ ssrc,
                       const float* __restrict__ sdst, const float* __restrict__ x,
                       float* __restrict__ out, int N) {
  int wv = (blockIdx.x * blockDim.x + threadIdx.x) >> 6;
  int lane = threadIdx.x & 63;
  if (wv >= N) return;
  int e0 = rp[wv], e1 = rp[wv + 1];
  if (e0 == e1) {
    float2 xv = *(const float2*)(x + (size_t)wv * 128 + 2 * lane);
    *(float2*)(out + (size_t)wv * 128 + 2 * lane) = make_float2(elu_f(xv.x), elu_f(xv.y));
    return;
  }
  float ss = ssrc[wv];
  int hi = lane >> 5;
  int colB = (lane & 31) << 2;
  float a0 = 0.f, a1 = 0.f, a2v = 0.f, a3 = 0.f, rsumL = 0.f;
  for (int base = e0; base < e1; base += 64) {
    int cnt = e1 - base; if (cnt > 64) cnt = 64;
    int d = 0; float w = 0.f;
    if (lane < cnt) {
      d = edge_dst[base + lane];
      w = edge_w(ss + sdst[d]);
    }
    rsumL += w;
    int jj = 0;
#pragma unroll 4
    for (; jj + 2 <= cnt; jj += 2) {
      int sel = jj + hi;
      int dj = __shfl(d, sel);
      float wj = __shfl(w, sel);
      float2 raw = *(const float2*)(h2h + ((size_t)dj << 7) + colB);
      float2 f01 = __half22float2(*(const __half2*)&raw.x);
      float2 f23 = __half22float2(*(const __half2*)&raw.y);
      a0 += wj * f01.x; a1 += wj * f01.y; a2v += wj * f23.x; a3 += wj * f23.y;
    }
    if (jj < cnt) {
      int dj = __shfl(d, jj);
      float wj = __shfl(w, jj);
      if (hi == 0) {
        float2 raw = *(const float2*)(h2h + ((size_t)dj << 7) + colB);
        float2 f01 = __half22float2(*(const __half2*)&raw.x);
        float2 f23 = __half22float2(*(const __half2*)&raw.y);
        a0 += wj * f01.x; a1 += wj * f01.y; a2v += wj * f23.x; a3 += wj * f23.y;
      }
    }
  }
  a0 += __shfl_xor(a0, 32); a1 += __shfl_xor(a1, 32);
  a2v += __shfl_xor(a2v, 32); a3 += __shfl_xor(a3, 32);
  float rsum = rsumL;
#pragma unroll
  for (int off = 32; off > 0; off >>= 1) rsum += __shfl_xor(rsum, off);
  float inv = 1.f / (rsum + EPS_DENOM);
  if (hi == 0) {
    *(float4*)(out + (size_t)wv * 128 + colB) =
        make_float4(elu_f(a0 * inv), elu_f(a1 * inv), elu_f(a2v * inv), elu_f(a3 * inv));
  }
}

extern "C" void kernel_launch(void* const* d_in, const int* in_sizes, int n_in,
                              void* d_out, int out_size, void* d_ws, size_t ws_size,
                              hipStream_t stream) {
  (void)n_in; (void)out_size; (void)ws_size;
  const float* x  = (const float*)d_in[0];
  const int*   ei = (const int*)d_in[1];
  const float* W1 = (const float*)d_in[2];
  const float* a1 = (const float*)d_in[3];
  const float* W2 = (const float*)d_in[4];
  const float* a2 = (const float*)d_in[5];
  float* out = (float*)d_out;
  const int N = in_sizes[0] / NFEAT;
  const int E = in_sizes[1] / 2;
  const int* src  = ei;
  const int* dstv = ei + E;

  int shift = 7;
  while ((((N - 1) >> shift) + 1) > MAXNB) ++shift;
  const int NB = ((N - 1) >> shift) + 1;

  // d_out = h2f f32 [N,128] during GEMM2 accumulation (dead before agg2 writes out)
  float* h2f = out;

  // workspace carve-up (~92 MB)
  char* wp = (char*)d_ws;
  size_t off = 0;
  auto mk = [&](size_t bytes) -> void* {
    void* p = wp + off;
    off += (bytes + 255) & ~(size_t)255;
    return p;
  };
  size_t szR0 = (size_t)N * 128 * 2;
  if ((size_t)E * 8 > szR0) szR0 = (size_t)E * 8;
  f16*  hout2    = (f16*)mk(szR0);                    // [N,128] f16; staging aliases
  int2* staging  = (int2*)hout2;
  f16*  h1pair   = (f16*)mk((size_t)N * 128 * 2);     // [N,128] pair tile; h2h aliases
  f16*  h2h      = h1pair;
  int*  edge_dst = (int*)mk((size_t)E * 4);
  f16*  xh       = (f16*)mk((size_t)N * 128 * 2);
  float* ssrc2   = (float*)mk((size_t)N * 8);
  float* sdst2   = (float*)mk((size_t)N * 8);
  float* s2src   = (float*)mk((size_t)N * 4);
  float* s2dst   = (float*)mk((size_t)N * 4);
  int*  rp       = (int*)mk((size_t)(N + 1) * 4);
  int*  bhist    = (int*)mk((size_t)(NB + 1) * 4);
  int*  bbase    = (int*)mk((size_t)(NB + 1) * 4);
  int*  bcur     = (int*)mk((size_t)(NB + 1) * 4);
  f16*  w1t      = (f16*)mk((size_t)NHEADS * 64 * 128 * 2);
  f16*  w2t      = (f16*)mk((size_t)128 * 512 * 2);

  // dtype prep
  k_cvt_x<<<1024, 256, 0, stream>>>(x, xh, (long)N * 16);
  k_cvt_w<<<512, 256, 0, stream>>>(W1, W2, w1t, w2t);

  // CSR build
  hipMemsetAsync(bhist, 0, (size_t)NB * 4, stream);
  int binBlocks = (E + BIN_EPB - 1) / BIN_EPB;
  k_bhist<<<binBlocks, 256, 0, stream>>>(src, bhist, E, NB, shift);
  k_bscan<<<1, 1024, 0, stream>>>(bhist, bbase, bcur, rp, NB, N, E);
  k_binA<<<binBlocks, 256, 0, stream>>>(src, dstv, bcur, staging, E, NB, shift);
  k_binB<<<NB, 256, 0, stream>>>(staging, bbase, rp, edge_dst, N, shift);

  int wb = (N + 3) / 4;
  int gb = (N + 63) / 64;

  for (int g = 0; g < NHEADS / 2; ++g) {
    k_gemm1pair<<<gb, 256, 0, stream>>>(xh, w1t + (size_t)g * 2 * 64 * 128,
                                        a1 + (size_t)g * 2 * 128,
                                        h1pair, ssrc2, sdst2, N);
    k_agg1pair<<<wb, 256, 0, stream>>>(rp, edge_dst, (const __half*)h1pair,
                                       ssrc2, sdst2, (__half*)hout2, N);
    k_gemm2<<<gb, 256, 0, stream>>>(hout2, w2t, h2f, g * 128, g > 0 ? 1 : 0,
                                    g == 3 ? 1 : 0, a2, h2h, s2src, s2dst, N);
  }

  k_agg2<<<wb, 256, 0, stream>>>(rp, edge_dst, (const __half*)h2h, s2src, s2dst, x, out, N);
}

// Round 10
// 884.591 us; speedup vs baseline: 2.6266x; 1.2097x over previous
//
#include <hip/hip_runtime.h>
#include <hip/hip_fp16.h>

#define NFEAT 128
#define NHID 64
#define NOUT 128
#define NHEADS 8
#define ALPHA_SLOPE 0.2f
#define EPS_DENOM 1e-16f

#define MAXNB 1024
#define BIN_EPB 12288
#define BIN_CAP 6144

typedef _Float16 f16;
typedef f16 f16x8 __attribute__((ext_vector_type(8)));
typedef float f32x4 __attribute__((ext_vector_type(4)));

static __device__ __forceinline__ float elu_f(float v) {
  return v > 0.f ? v : __expf(v) - 1.f;
}
static __device__ __forceinline__ float edge_w(float sc) {
  float lr = sc > 0.f ? sc : ALPHA_SLOPE * sc;
  return __expf(-lr);
}

// ---------------- dtype prep ----------------
__global__ void k_cvt_x(const float* __restrict__ x, f16* __restrict__ xh, long n8) {
  long i = (long)blockIdx.x * blockDim.x + threadIdx.x;
  long stride = (long)gridDim.x * blockDim.x;
  for (; i < n8; i += stride) {
    const float* p = x + i * 8;
    float4 v0 = *(const float4*)p;
    float4 v1 = *(const float4*)(p + 4);
    f16x8 o;
    o[0] = (f16)v0.x; o[1] = (f16)v0.y; o[2] = (f16)v0.z; o[3] = (f16)v0.w;
    o[4] = (f16)v1.x; o[5] = (f16)v1.y; o[6] = (f16)v1.z; o[7] = (f16)v1.w;
    *(f16x8*)(xh + i * 8) = o;
  }
}

// W1 [8][128][64] -> w1t [8][64][128] fp16 (c-major); W2 [512][128] -> w2t [128][512] fp16
__global__ void k_cvt_w(const float* __restrict__ W1, const float* __restrict__ W2,
                        f16* __restrict__ w1t, f16* __restrict__ w2t) {
  int idx = blockIdx.x * 256 + threadIdx.x;
  if (idx < NHEADS * 128 * 64) {
    int h = idx >> 13, rem = idx & 8191, c = rem >> 7, k = rem & 127;
    w1t[idx] = (f16)W1[h * 8192 + k * 64 + c];
  } else {
    int j = idx - NHEADS * 128 * 64;
    if (j < 128 * 512) {
      int c = j >> 9, k = j & 511;
      w2t[j] = (f16)W2[k * 128 + c];
    }
  }
}

// u[h] = W1[h] @ a1[h][:64], v[h] = W1[h] @ a1[h][64:]  -> uv16 fp16 [16][128]
// (score identity: (x@W1)·a == x·(W1@a))
__global__ void k_prep_uv(const float* __restrict__ W1, const float* __restrict__ a1,
                          f16* __restrict__ uv16) {
  int id0 = threadIdx.x;
#pragma unroll
  for (int q = 0; q < 4; ++q) {
    int id = id0 * 4 + q;          // 0..1023 -> (h, k)
    int h = id >> 7, k = id & 127;
    const float* wrow = W1 + h * 8192 + k * 64;
    const float* ah = a1 + h * 128;
    float u = 0.f, v = 0.f;
    for (int c = 0; c < 64; ++c) {
      float wv_ = wrow[c];
      u += wv_ * ah[c];
      v += wv_ * ah[64 + c];
    }
    uv16[h * 128 + k] = (f16)u;
    uv16[(8 + h) * 128 + k] = (f16)v;
  }
}

// [N,128] @ [128,16] MFMA -> ssrc8/sdst8 [N][8] f32 (all 8 heads at once)
__global__ __launch_bounds__(256) void k_score8(
    const f16* __restrict__ xh, const f16* __restrict__ uv16,
    float* __restrict__ ssrc8, float* __restrict__ sdst8, int N) {
  int wave = threadIdx.x >> 6, lane = threadIdx.x & 63;
  int c = lane & 15, g = lane >> 4;
  int row0 = blockIdx.x * 64 + wave * 16;
  f16x8 bf[4];
#pragma unroll
  for (int ks = 0; ks < 4; ++ks)
    bf[ks] = *(const f16x8*)(uv16 + c * 128 + ks * 32 + g * 8);
  int arow = row0 + c; if (arow > N - 1) arow = N - 1;
  const f16* ap = xh + (size_t)arow * 128 + g * 8;
  f32x4 acc = (f32x4){0.f, 0.f, 0.f, 0.f};
#pragma unroll
  for (int ks = 0; ks < 4; ++ks) {
    f16x8 af = *(const f16x8*)(ap + ks * 32);
    acc = __builtin_amdgcn_mfma_f32_16x16x32_f16(af, bf[ks], acc, 0, 0, 0);
  }
#pragma unroll
  for (int j = 0; j < 4; ++j) {
    int r = row0 + g * 4 + j;
    if (r < N) {
      if (c < 8) ssrc8[(size_t)r * 8 + c] = acc[j];
      else       sdst8[(size_t)r * 8 + c - 8] = acc[j];
    }
  }
}

// ---------------- CSR build: 2-pass bucketed counting sort ----------------
__global__ __launch_bounds__(256) void k_bhist(const int* __restrict__ src,
                                               int* __restrict__ bhist,
                                               int E, int NB, int shift) {
  __shared__ int h[MAXNB];
  int tid = threadIdx.x;
  for (int i = tid; i < NB; i += 256) h[i] = 0;
  __syncthreads();
  int base = blockIdx.x * BIN_EPB;
#pragma unroll 4
  for (int j = 0; j < BIN_EPB / 256; ++j) {
    int e = base + tid + j * 256;
    if (e < E) atomicAdd(&h[src[e] >> shift], 1);
  }
  __syncthreads();
  for (int i = tid; i < NB; i += 256)
    if (h[i]) atomicAdd(&bhist[i], h[i]);
}

__global__ __launch_bounds__(1024) void k_bscan(const int* __restrict__ bhist,
                                                int* __restrict__ bucket_base,
                                                int* __restrict__ bucket_cursor,
                                                int* __restrict__ rp,
                                                int NB, int N, int E) {
  __shared__ int sh[1024];
  int i = threadIdx.x;
  int v = (i < NB) ? bhist[i] : 0;
  sh[i] = v;
  __syncthreads();
  for (int off = 1; off < 1024; off <<= 1) {
    int add = (i >= off) ? sh[i - off] : 0;
    __syncthreads();
    sh[i] += add;
    __syncthreads();
  }
  if (i < NB) {
    int ex = sh[i] - v;
    bucket_base[i] = ex;
    bucket_cursor[i] = ex;
  }
  if (i == 0) {
    bucket_base[NB] = E;
    rp[N] = E;
  }
}

__global__ __launch_bounds__(256) void k_binA(const int* __restrict__ src,
                                              const int* __restrict__ dst,
                                              int* __restrict__ bucket_cursor,
                                              int2* __restrict__ staging,
                                              int E, int NB, int shift) {
  __shared__ int h[MAXNB];
  int tid = threadIdx.x;
  for (int i = tid; i < NB; i += 256) h[i] = 0;
  __syncthreads();
  int base = blockIdx.x * BIN_EPB;
#pragma unroll 4
  for (int j = 0; j < BIN_EPB / 256; ++j) {
    int e = base + tid + j * 256;
    if (e < E) atomicAdd(&h[src[e] >> shift], 1);
  }
  __syncthreads();
  for (int i = tid; i < NB; i += 256)
    if (h[i]) h[i] = atomicAdd(&bucket_cursor[i], h[i]);
  __syncthreads();
#pragma unroll 4
  for (int j = 0; j < BIN_EPB / 256; ++j) {
    int e = base + tid + j * 256;
    if (e < E) {
      int s = src[e];
      int slot = atomicAdd(&h[s >> shift], 1);
      staging[slot] = make_int2(s, dst[e]);
    }
  }
}

__global__ __launch_bounds__(256) void k_binB(const int2* __restrict__ staging,
                                              const int* __restrict__ bucket_base,
                                              int* __restrict__ rp,
                                              int* __restrict__ edge_dst,
                                              int N, int shift) {
  __shared__ int2 buf[BIN_CAP];
  __shared__ int rcnt[256], rsc[256];
  int tid = threadIdx.x;
  int b = blockIdx.x;
  int lo = bucket_base[b], hi = bucket_base[b + 1];
  int S = hi - lo;
  if (S > BIN_CAP) S = BIN_CAP;
  int R = 1 << shift;
  int rmask = R - 1;
  for (int i = tid; i < S; i += 256) buf[i] = staging[lo + i];
  if (tid < R) rcnt[tid] = 0;
  __syncthreads();
  for (int i = tid; i < S; i += 256) atomicAdd(&rcnt[buf[i].x & rmask], 1);
  __syncthreads();
  if (tid < R) rsc[tid] = rcnt[tid];
  __syncthreads();
  for (int off = 1; off < 256; off <<= 1) {
    int add = (tid >= off && tid < R) ? rsc[tid - off] : 0;
    __syncthreads();
    if (tid < R) rsc[tid] += add;
    __syncthreads();
  }
  int row0 = b << shift;
  if (tid < R) {
    int ex = rsc[tid] - rcnt[tid];
    rcnt[tid] = ex;
    if (row0 + tid < N) rp[row0 + tid] = lo + ex;
  }
  __syncthreads();
  for (int i = tid; i < S; i += 256) {
    int r = buf[i].x & rmask;
    int k = atomicAdd(&rcnt[r], 1);
    edge_dst[lo + k] = buf[i].y;
  }
}

// ---------------- layer-1 shared-x aggregation: ALL 8 heads in one edge walk ----------
// wave per node. Per 64-edge chunk: phase1 lane=edge computes 8 weights (sdst8 gather
// 32 B) and stages them fp16 in per-wave LDS; phase2 half-wave per edge gathers x
// (lane = 4 x-cols, 8 B) and does 4col x 8head FMAs. Output msgx[n][8][128] fp16
// pre-scaled by 1/rsum (division commutes with the W1 GEMM that follows).
__global__ __launch_bounds__(256) void k_aggx(
    const int* __restrict__ rp, const int* __restrict__ edge_dst,
    const f16* __restrict__ xh, const float* __restrict__ ssrc8,
    const float* __restrict__ sdst8, f16* __restrict__ msgx, int c0, int c1) {
  __shared__ __half wbuf[4][64][8];   // per-wave slice, no cross-wave sharing
  int wv4 = threadIdx.x >> 6;
  int lane = threadIdx.x & 63;
  int node = c0 + blockIdx.x * 4 + wv4;
  if (node >= c1) return;             // safe: no __syncthreads below
  int e0 = rp[node], e1 = rp[node + 1];
  int hi = lane >> 5, li = lane & 31;
  float4 sA = *(const float4*)(ssrc8 + (size_t)node * 8);
  float4 sB = *(const float4*)(ssrc8 + (size_t)node * 8 + 4);
  float acc[8][4];
#pragma unroll
  for (int h = 0; h < 8; ++h)
#pragma unroll
    for (int cc = 0; cc < 4; ++cc) acc[h][cc] = 0.f;
  float rs[8];
#pragma unroll
  for (int h = 0; h < 8; ++h) rs[h] = 0.f;
  __half* wb = &wbuf[wv4][0][0];

  for (int base = e0; base < e1; base += 64) {
    int cnt = e1 - base; if (cnt > 64) cnt = 64;
    int d = 0;
    float w0 = 0.f, w1 = 0.f, w2 = 0.f, w3 = 0.f, w4 = 0.f, w5 = 0.f, w6 = 0.f, w7 = 0.f;
    if (lane < cnt) {
      d = edge_dst[base + lane];
      float4 dA = *(const float4*)(sdst8 + (size_t)d * 8);
      float4 dB = *(const float4*)(sdst8 + (size_t)d * 8 + 4);
      w0 = edge_w(sA.x + dA.x); w1 = edge_w(sA.y + dA.y);
      w2 = edge_w(sA.z + dA.z); w3 = edge_w(sA.w + dA.w);
      w4 = edge_w(sB.x + dB.x); w5 = edge_w(sB.y + dB.y);
      w6 = edge_w(sB.z + dB.z); w7 = edge_w(sB.w + dB.w);
      rs[0] += w0; rs[1] += w1; rs[2] += w2; rs[3] += w3;
      rs[4] += w4; rs[5] += w5; rs[6] += w6; rs[7] += w7;
    }
    float4 pk;
    ((__half2*)&pk)[0] = __float22half2_rn(make_float2(w0, w1));
    ((__half2*)&pk)[1] = __float22half2_rn(make_float2(w2, w3));
    ((__half2*)&pk)[2] = __float22half2_rn(make_float2(w4, w5));
    ((__half2*)&pk)[3] = __float22half2_rn(make_float2(w6, w7));
    *(float4*)(wb + lane * 8) = pk;
    __threadfence_block();            // order per-wave LDS write -> read

    int jj = 0;
    for (; jj + 2 <= cnt; jj += 2) {
      int e = jj + hi;                // half-wave 0 -> edge jj, 1 -> jj+1
      int de = __shfl(d, e);
      float4 wk = *(const float4*)(wb + e * 8);
      float2 wA = __half22float2(((__half2*)&wk)[0]);
      float2 wB = __half22float2(((__half2*)&wk)[1]);
      float2 wC = __half22float2(((__half2*)&wk)[2]);
      float2 wD = __half22float2(((__half2*)&wk)[3]);
      float2 xraw = *(const float2*)(xh + (size_t)de * 128 + li * 4);
      float2 x01 = __half22float2(((__half2*)&xraw)[0]);
      float2 x23 = __half22float2(((__half2*)&xraw)[1]);
      acc[0][0] += wA.x * x01.x; acc[0][1] += wA.x * x01.y; acc[0][2] += wA.x * x23.x; acc[0][3] += wA.x * x23.y;
      acc[1][0] += wA.y * x01.x; acc[1][1] += wA.y * x01.y; acc[1][2] += wA.y * x23.x; acc[1][3] += wA.y * x23.y;
      acc[2][0] += wB.x * x01.x; acc[2][1] += wB.x * x01.y; acc[2][2] += wB.x * x23.x; acc[2][3] += wB.x * x23.y;
      acc[3][0] += wB.y * x01.x; acc[3][1] += wB.y * x01.y; acc[3][2] += wB.y * x23.x; acc[3][3] += wB.y * x23.y;
      acc[4][0] += wC.x * x01.x; acc[4][1] += wC.x * x01.y; acc[4][2] += wC.x * x23.x; acc[4][3] += wC.x * x23.y;
      acc[5][0] += wC.y * x01.x; acc[5][1] += wC.y * x01.y; acc[5][2] += wC.y * x23.x; acc[5][3] += wC.y * x23.y;
      acc[6][0] += wD.x * x01.x; acc[6][1] += wD.x * x01.y; acc[6][2] += wD.x * x23.x; acc[6][3] += wD.x * x23.y;
      acc[7][0] += wD.y * x01.x; acc[7][1] += wD.y * x01.y; acc[7][2] += wD.y * x23.x; acc[7][3] += wD.y * x23.y;
    }
    if (jj < cnt) {                   // odd tail edge: half-wave 0 only
      int de = __shfl(d, jj);
      float4 wk = *(const float4*)(wb + jj * 8);
      if (hi == 0) {
        float2 wA = __half22float2(((__half2*)&wk)[0]);
        float2 wB = __half22float2(((__half2*)&wk)[1]);
        float2 wC = __half22float2(((__half2*)&wk)[2]);
        float2 wD = __half22float2(((__half2*)&wk)[3]);
        float2 xraw = *(const float2*)(xh + (size_t)de * 128 + li * 4);
        float2 x01 = __half22float2(((__half2*)&xraw)[0]);
        float2 x23 = __half22float2(((__half2*)&xraw)[1]);
        acc[0][0] += wA.x * x01.x; acc[0][1] += wA.x * x01.y; acc[0][2] += wA.x * x23.x; acc[0][3] += wA.x * x23.y;
        acc[1][0] += wA.y * x01.x; acc[1][1] += wA.y * x01.y; acc[1][2] += wA.y * x23.x; acc[1][3] += wA.y * x23.y;
        acc[2][0] += wB.x * x01.x; acc[2][1] += wB.x * x01.y; acc[2][2] += wB.x * x23.x; acc[2][3] += wB.x * x23.y;
        acc[3][0] += wB.y * x01.x; acc[3][1] += wB.y * x01.y; acc[3][2] += wB.y * x23.x; acc[3][3] += wB.y * x23.y;
        acc[4][0] += wC.x * x01.x; acc[4][1] += wC.x * x01.y; acc[4][2] += wC.x * x23.x; acc[4][3] += wC.x * x23.y;
        acc[5][0] += wC.y * x01.x; acc[5][1] += wC.y * x01.y; acc[5][2] += wC.y * x23.x; acc[5][3] += wC.y * x23.y;
        acc[6][0] += wD.x * x01.x; acc[6][1] += wD.x * x01.y; acc[6][2] += wD.x * x23.x; acc[6][3] += wD.x * x23.y;
        acc[7][0] += wD.y * x01.x; acc[7][1] += wD.y * x01.y; acc[7][2] += wD.y * x23.x; acc[7][3] += wD.y * x23.y;
      }
    }
  }

  // combine edge-parity halves (same cols both halves)
#pragma unroll
  for (int h = 0; h < 8; ++h)
#pragma unroll
    for (int cc = 0; cc < 4; ++cc) acc[h][cc] += __shfl_xor(acc[h][cc], 32);
  // full-wave rowsum reduce per head
#pragma unroll
  for (int off = 32; off > 0; off >>= 1)
#pragma unroll
    for (int h = 0; h < 8; ++h) rs[h] += __shfl_xor(rs[h], off);

  if (hi == 0) {
    f16* mp = msgx + (size_t)(node - c0) * 1024 + li * 4;
#pragma unroll
    for (int h = 0; h < 8; ++h) {
      float inv = 1.f / (rs[h] + EPS_DENOM);
      float2 st;
      ((__half2*)&st)[0] = __float22half2_rn(make_float2(acc[h][0] * inv, acc[h][1] * inv));
      ((__half2*)&st)[1] = __float22half2_rn(make_float2(acc[h][2] * inv, acc[h][3] * inv));
      *(float2*)(mp + h * 128) = st;
    }
  }
}

// ---------------- hout[n][h*64+c] = ELU( msgx[n][h] @ W1[h] ) (MFMA, per head) --------
__global__ __launch_bounds__(256) void k_houtgemm(
    const f16* __restrict__ msgx, const f16* __restrict__ w1t,
    f16* __restrict__ hout, int c0, int c1) {
  int h = blockIdx.y;
  int wave = threadIdx.x >> 6, lane = threadIdx.x & 63;
  int c = lane & 15, g = lane >> 4;
  int row0 = c0 + blockIdx.x * 64 + wave * 16;
  int arow = row0 + c; if (arow > c1 - 1) arow = c1 - 1;
  const f16* ap = msgx + ((size_t)(arow - c0) * 8 + h) * 128 + g * 8;
  const f16* bp = w1t + (size_t)h * 8192;
  f32x4 acc[4];
#pragma unroll
  for (int t = 0; t < 4; ++t) acc[t] = (f32x4){0.f, 0.f, 0.f, 0.f};
#pragma unroll
  for (int ks = 0; ks < 4; ++ks) {
    f16x8 af = *(const f16x8*)(ap + ks * 32);
#pragma unroll
    for (int t = 0; t < 4; ++t) {
      f16x8 bf = *(const f16x8*)(bp + (t * 16 + c) * 128 + ks * 32 + g * 8);
      acc[t] = __builtin_amdgcn_mfma_f32_16x16x32_f16(af, bf, acc[t], 0, 0, 0);
    }
  }
#pragma unroll
  for (int j = 0; j < 4; ++j) {
    int r = row0 + g * 4 + j;
    if (r < c1) {
#pragma unroll
      for (int t = 0; t < 4; ++t)
        hout[(size_t)(r - c0) * 512 + h * 64 + t * 16 + c] = (f16)elu_f(acc[t][j]);
    }
  }
}

// ---------------- h2 = hout @ W2 (K=512, MFMA) + fused s2 scores + fp16 h2h -----------
__global__ __launch_bounds__(256) void k_gemm2full(
    const f16* __restrict__ hout, const f16* __restrict__ w2t,
    const float* __restrict__ a2, f16* __restrict__ h2h,
    float* __restrict__ s2src, float* __restrict__ s2dst, int c0, int c1) {
  int wave = threadIdx.x >> 6, lane = threadIdx.x & 63;
  int c = lane & 15, g = lane >> 4;
  int row0 = c0 + blockIdx.x * 64 + wave * 16;
  int arow = row0 + c; if (arow > c1 - 1) arow = c1 - 1;
  const f16* ap = hout + (size_t)(arow - c0) * 512 + g * 8;
  f32x4 acc[8];
#pragma unroll
  for (int t = 0; t < 8; ++t) acc[t] = (f32x4){0.f, 0.f, 0.f, 0.f};
#pragma unroll
  for (int ks = 0; ks < 16; ++ks) {
    f16x8 af = *(const f16x8*)(ap + ks * 32);
#pragma unroll
    for (int t = 0; t < 8; ++t) {
      f16x8 bf = *(const f16x8*)(w2t + (size_t)(t * 16 + c) * 512 + ks * 32 + g * 8);
      acc[t] = __builtin_amdgcn_mfma_f32_16x16x32_f16(af, bf, acc[t], 0, 0, 0);
    }
  }
  float av0[8], av1[8];
#pragma unroll
  for (int t = 0; t < 8; ++t) {
    av0[t] = a2[t * 16 + c];
    av1[t] = a2[128 + t * 16 + c];
  }
#pragma unroll
  for (int j = 0; j < 4; ++j) {
    int r = row0 + g * 4 + j;
    float s0 = 0.f, s1 = 0.f;
#pragma unroll
    for (int t = 0; t < 8; ++t) {
      float v = acc[t][j];
      if (r < c1) h2h[(size_t)r * 128 + t * 16 + c] = (f16)v;
      s0 += v * av0[t];
      s1 += v * av1[t];
    }
    s0 += __shfl_xor(s0, 1); s0 += __shfl_xor(s0, 2);
    s0 += __shfl_xor(s0, 4); s0 += __shfl_xor(s0, 8);
    s1 += __shfl_xor(s1, 1); s1 += __shfl_xor(s1, 2);
    s1 += __shfl_xor(s1, 4); s1 += __shfl_xor(s1, 8);
    if (c == 0 && r < c1) { s2src[r] = s0; s2dst[r] = s1; }
  }
}

// ---------------- layer-2 aggregation: cooperative-edge + deg==0 fallback + ELU -------
__global__ void k_agg2(const int* __restrict__ rp, const int* __restrict__ edge_dst,
                       const __half* __restrict__ h2h, const float* __restrict__ ssrc,
                       const float* __restrict__ sdst, const float* __restrict__ x,
                       float* __restrict__ out, int N) {
  int wv = (blockIdx.x * blockDim.x + threadIdx.x) >> 6;
  int lane = threadIdx.x & 63;
  if (wv >= N) return;
  int e0 = rp[wv], e1 = rp[wv + 1];
  if (e0 == e1) {
    float2 xv = *(const float2*)(x + (size_t)wv * 128 + 2 * lane);
    *(float2*)(out + (size_t)wv * 128 + 2 * lane) = make_float2(elu_f(xv.x), elu_f(xv.y));
    return;
  }
  float ss = ssrc[wv];
  int hi = lane >> 5;
  int colB = (lane & 31) << 2;
  float a0 = 0.f, a1 = 0.f, a2v = 0.f, a3 = 0.f, rsumL = 0.f;
  for (int base = e0; base < e1; base += 64) {
    int cnt = e1 - base; if (cnt > 64) cnt = 64;
    int d = 0; float w = 0.f;
    if (lane < cnt) {
      d = edge_dst[base + lane];
      w = edge_w(ss + sdst[d]);
    }
    rsumL += w;
    int jj = 0;
#pragma unroll 4
    for (; jj + 2 <= cnt; jj += 2) {
      int sel = jj + hi;
      int dj = __shfl(d, sel);
      float wj = __shfl(w, sel);
      float2 raw = *(const float2*)(h2h + ((size_t)dj << 7) + colB);
      float2 f01 = __half22float2(*(const __half2*)&raw.x);
      float2 f23 = __half22float2(*(const __half2*)&raw.y);
      a0 += wj * f01.x; a1 += wj * f01.y; a2v += wj * f23.x; a3 += wj * f23.y;
    }
    if (jj < cnt) {
      int dj = __shfl(d, jj);
      float wj = __shfl(w, jj);
      if (hi == 0) {
        float2 raw = *(const float2*)(h2h + ((size_t)dj << 7) + colB);
        float2 f01 = __half22float2(*(const __half2*)&raw.x);
        float2 f23 = __half22float2(*(const __half2*)&raw.y);
        a0 += wj * f01.x; a1 += wj * f01.y; a2v += wj * f23.x; a3 += wj * f23.y;
      }
    }
  }
  a0 += __shfl_xor(a0, 32); a1 += __shfl_xor(a1, 32);
  a2v += __shfl_xor(a2v, 32); a3 += __shfl_xor(a3, 32);
  float rsum = rsumL;
#pragma unroll
  for (int off = 32; off > 0; off >>= 1) rsum += __shfl_xor(rsum, off);
  float inv = 1.f / (rsum + EPS_DENOM);
  if (hi == 0) {
    *(float4*)(out + (size_t)wv * 128 + colB) =
        make_float4(elu_f(a0 * inv), elu_f(a1 * inv), elu_f(a2v * inv), elu_f(a3 * inv));
  }
}

extern "C" void kernel_launch(void* const* d_in, const int* in_sizes, int n_in,
                              void* d_out, int out_size, void* d_ws, size_t ws_size,
                              hipStream_t stream) {
  (void)n_in; (void)out_size;
  const float* x  = (const float*)d_in[0];
  const int*   ei = (const int*)d_in[1];
  const float* W1 = (const float*)d_in[2];
  const float* a1 = (const float*)d_in[3];
  const float* W2 = (const float*)d_in[4];
  const float* a2 = (const float*)d_in[5];
  float* out = (float*)d_out;
  const int N = in_sizes[0] / NFEAT;
  const int E = in_sizes[1] / 2;
  const int* src  = ei;
  const int* dstv = ei + E;

  int shift = 7;
  while ((((N - 1) >> shift) + 1) > MAXNB) ++shift;
  const int NB = ((N - 1) >> shift) + 1;

  // adaptive chunk count: pick smallest nc in {8,16,32} whose footprint fits ws_size
  int nc = 8;
  size_t need = 0;
  for (;;) {
    int cN = (N + nc - 1) / nc;
    size_t sz[14] = {
      (size_t)E * 8 > (size_t)cN * 2048 ? (size_t)E * 8 : (size_t)cN * 2048, // msgx/staging
      (size_t)cN * 1024,              // hout (cN*512 fp16)
      (size_t)N * 256,                // h2h
      (size_t)N * 256,                // xh
      (size_t)E * 4,                  // edge_dst
      (size_t)N * 32, (size_t)N * 32, // ssrc8, sdst8
      (size_t)N * 4, (size_t)N * 4,   // s2src, s2dst
      (size_t)(N + 1) * 4,            // rp
      (size_t)(NB + 1) * 4 * 3,       // bhist+bbase+bcur
      (size_t)NHEADS * 64 * 128 * 2,  // w1t
      (size_t)128 * 512 * 2,          // w2t
      (size_t)16 * 128 * 2            // uv16
    };
    need = 0;
    for (int i = 0; i < 14; ++i) need += (sz[i] + 255) & ~(size_t)255;
    need += 4096;
    if (need <= ws_size || nc >= 32) break;
    nc <<= 1;
  }
  const int chunkN = (N + nc - 1) / nc;

  char* wp = (char*)d_ws;
  size_t off = 0;
  auto mk = [&](size_t bytes) -> void* {
    void* p = wp + off;
    off += (bytes + 255) & ~(size_t)255;
    return p;
  };
  size_t szR0 = (size_t)E * 8;
  if ((size_t)chunkN * 2048 > szR0) szR0 = (size_t)chunkN * 2048;
  f16*  msgx     = (f16*)mk(szR0);                   // aliases CSR staging
  int2* staging  = (int2*)msgx;
  f16*  hout     = (f16*)mk((size_t)chunkN * 512 * 2);
  f16*  h2h      = (f16*)mk((size_t)N * 128 * 2);
  f16*  xh       = (f16*)mk((size_t)N * 128 * 2);
  int*  edge_dst = (int*)mk((size_t)E * 4);
  float* ssrc8   = (float*)mk((size_t)N * 8 * 4);
  float* sdst8   = (float*)mk((size_t)N * 8 * 4);
  float* s2src   = (float*)mk((size_t)N * 4);
  float* s2dst   = (float*)mk((size_t)N * 4);
  int*  rp       = (int*)mk((size_t)(N + 1) * 4);
  int*  bhist    = (int*)mk((size_t)(NB + 1) * 4);
  int*  bbase    = (int*)mk((size_t)(NB + 1) * 4);
  int*  bcur     = (int*)mk((size_t)(NB + 1) * 4);
  f16*  w1t      = (f16*)mk((size_t)NHEADS * 64 * 128 * 2);
  f16*  w2t      = (f16*)mk((size_t)128 * 512 * 2);
  f16*  uv16     = (f16*)mk((size_t)16 * 128 * 2);

  // dtype prep + score precompute
  k_cvt_x<<<1024, 256, 0, stream>>>(x, xh, (long)N * 16);
  k_cvt_w<<<512, 256, 0, stream>>>(W1, W2, w1t, w2t);
  k_prep_uv<<<1, 256, 0, stream>>>(W1, a1, uv16);
  k_score8<<<(N + 63) / 64, 256, 0, stream>>>(xh, uv16, ssrc8, sdst8, N);

  // CSR build
  (void)hipMemsetAsync(bhist, 0, (size_t)NB * 4, stream);
  int binBlocks = (E + BIN_EPB - 1) / BIN_EPB;
  k_bhist<<<binBlocks, 256, 0, stream>>>(src, bhist, E, NB, shift);
  k_bscan<<<1, 1024, 0, stream>>>(bhist, bbase, bcur, rp, NB, N, E);
  k_binA<<<binBlocks, 256, 0, stream>>>(src, dstv, bcur, staging, E, NB, shift);
  k_binB<<<NB, 256, 0, stream>>>(staging, bbase, rp, edge_dst, N, shift);

  // layer 1 (all 8 heads) + layer-2 GEMM, per node-chunk
  for (int ch = 0; ch < nc; ++ch) {
    int c0 = ch * chunkN;
    if (c0 >= N) break;
    int c1 = c0 + chunkN; if (c1 > N) c1 = N;
    int cn = c1 - c0;
    k_aggx<<<(cn + 3) / 4, 256, 0, stream>>>(rp, edge_dst, xh, ssrc8, sdst8, msgx, c0, c1);
    k_houtgemm<<<dim3((cn + 63) / 64, NHEADS), 256, 0, stream>>>(msgx, w1t, hout, c0, c1);
    k_gemm2full<<<(cn + 63) / 64, 256, 0, stream>>>(hout, w2t, a2, h2h, s2src, s2dst, c0, c1);
  }

  // layer-2 aggregation
  int wb = (N + 3) / 4;
  k_agg2<<<wb, 256, 0, stream>>>(rp, edge_dst, (const __half*)h2h, s2src, s2dst, x, out, N);
}

// Round 11
// 827.819 us; speedup vs baseline: 2.8068x; 1.0686x over previous
//
#include <hip/hip_runtime.h>
#include <hip/hip_fp16.h>

#define NFEAT 128
#define NHID 64
#define NOUT 128
#define NHEADS 8
#define ALPHA_SLOPE 0.2f
#define EPS_DENOM 1e-16f

#define MAXNB 1024
#define BIN_EPB 12288
#define BIN_CAP 6144

typedef _Float16 f16;
typedef f16 f16x8 __attribute__((ext_vector_type(8)));
typedef float f32x4 __attribute__((ext_vector_type(4)));

static __device__ __forceinline__ float elu_f(float v) {
  return v > 0.f ? v : __expf(v) - 1.f;
}
static __device__ __forceinline__ float edge_w(float sc) {
  float lr = sc > 0.f ? sc : ALPHA_SLOPE * sc;
  return __expf(-lr);
}

// ---------------- dtype prep ----------------
__global__ void k_cvt_x(const float* __restrict__ x, f16* __restrict__ xh, long n8) {
  long i = (long)blockIdx.x * blockDim.x + threadIdx.x;
  long stride = (long)gridDim.x * blockDim.x;
  for (; i < n8; i += stride) {
    const float* p = x + i * 8;
    float4 v0 = *(const float4*)p;
    float4 v1 = *(const float4*)(p + 4);
    f16x8 o;
    o[0] = (f16)v0.x; o[1] = (f16)v0.y; o[2] = (f16)v0.z; o[3] = (f16)v0.w;
    o[4] = (f16)v1.x; o[5] = (f16)v1.y; o[6] = (f16)v1.z; o[7] = (f16)v1.w;
    *(f16x8*)(xh + i * 8) = o;
  }
}

// region 0: W1 [8][128][64] -> w1t [8][64][128] fp16; region 1: W2 -> w2t [128][512] fp16;
// region 2: uv16[16][128] = {W1[h]@a1[h][:64], W1[h]@a1[h][64:]} (score identity)
__global__ void k_cvt_w(const float* __restrict__ W1, const float* __restrict__ W2,
                        const float* __restrict__ a1,
                        f16* __restrict__ w1t, f16* __restrict__ w2t,
                        f16* __restrict__ uv16) {
  int idx = blockIdx.x * 256 + threadIdx.x;
  if (idx < NHEADS * 128 * 64) {
    int h = idx >> 13, rem = idx & 8191, c = rem >> 7, k = rem & 127;
    w1t[idx] = (f16)W1[h * 8192 + k * 64 + c];
  } else if (idx < 2 * NHEADS * 128 * 64) {
    int j = idx - NHEADS * 128 * 64;
    int c = j >> 9, k = j & 511;
    w2t[j] = (f16)W2[k * 128 + c];
  } else {
    int id = idx - 2 * NHEADS * 128 * 64;
    if (id < 1024) {
      int h = id >> 7, k = id & 127;
      const float* wrow = W1 + h * 8192 + k * 64;
      const float* ah = a1 + h * 128;
      float u = 0.f, v = 0.f;
      for (int c = 0; c < 64; ++c) {
        float wv_ = wrow[c];
        u += wv_ * ah[c];
        v += wv_ * ah[64 + c];
      }
      uv16[h * 128 + k] = (f16)u;
      uv16[(8 + h) * 128 + k] = (f16)v;
    }
  }
}

// [N,128] @ [128,16] MFMA -> ssrc8 [N][8] f32, sdst8h [N][8] fp16 (all 8 heads)
__global__ __launch_bounds__(256) void k_score8(
    const f16* __restrict__ xh, const f16* __restrict__ uv16,
    float* __restrict__ ssrc8, f16* __restrict__ sdst8h, int N) {
  int wave = threadIdx.x >> 6, lane = threadIdx.x & 63;
  int c = lane & 15, g = lane >> 4;
  int row0 = blockIdx.x * 64 + wave * 16;
  f16x8 bf[4];
#pragma unroll
  for (int ks = 0; ks < 4; ++ks)
    bf[ks] = *(const f16x8*)(uv16 + c * 128 + ks * 32 + g * 8);
  int arow = row0 + c; if (arow > N - 1) arow = N - 1;
  const f16* ap = xh + (size_t)arow * 128 + g * 8;
  f32x4 acc = (f32x4){0.f, 0.f, 0.f, 0.f};
#pragma unroll
  for (int ks = 0; ks < 4; ++ks) {
    f16x8 af = *(const f16x8*)(ap + ks * 32);
    acc = __builtin_amdgcn_mfma_f32_16x16x32_f16(af, bf[ks], acc, 0, 0, 0);
  }
#pragma unroll
  for (int j = 0; j < 4; ++j) {
    int r = row0 + g * 4 + j;
    if (r < N) {
      if (c < 8) ssrc8[(size_t)r * 8 + c] = acc[j];
      else       sdst8h[(size_t)r * 8 + c - 8] = (f16)acc[j];
    }
  }
}

// ---------------- CSR build: 2-pass bucketed counting sort ----------------
__global__ __launch_bounds__(256) void k_bhist(const int* __restrict__ src,
                                               int* __restrict__ bhist,
                                               int E, int NB, int shift) {
  __shared__ int h[MAXNB];
  int tid = threadIdx.x;
  for (int i = tid; i < NB; i += 256) h[i] = 0;
  __syncthreads();
  int base = blockIdx.x * BIN_EPB;
#pragma unroll 4
  for (int j = 0; j < BIN_EPB / 256; ++j) {
    int e = base + tid + j * 256;
    if (e < E) atomicAdd(&h[src[e] >> shift], 1);
  }
  __syncthreads();
  for (int i = tid; i < NB; i += 256)
    if (h[i]) atomicAdd(&bhist[i], h[i]);
}

__global__ __launch_bounds__(1024) void k_bscan(const int* __restrict__ bhist,
                                                int* __restrict__ bucket_base,
                                                int* __restrict__ bucket_cursor,
                                                int* __restrict__ rp,
                                                int NB, int N, int E) {
  __shared__ int sh[1024];
  int i = threadIdx.x;
  int v = (i < NB) ? bhist[i] : 0;
  sh[i] = v;
  __syncthreads();
  for (int off = 1; off < 1024; off <<= 1) {
    int add = (i >= off) ? sh[i - off] : 0;
    __syncthreads();
    sh[i] += add;
    __syncthreads();
  }
  if (i < NB) {
    int ex = sh[i] - v;
    bucket_base[i] = ex;
    bucket_cursor[i] = ex;
  }
  if (i == 0) {
    bucket_base[NB] = E;
    rp[N] = E;
  }
}

__global__ __launch_bounds__(256) void k_binA(const int* __restrict__ src,
                                              const int* __restrict__ dst,
                                              int* __restrict__ bucket_cursor,
                                              int2* __restrict__ staging,
                                              int E, int NB, int shift) {
  __shared__ int h[MAXNB];
  int tid = threadIdx.x;
  for (int i = tid; i < NB; i += 256) h[i] = 0;
  __syncthreads();
  int base = blockIdx.x * BIN_EPB;
#pragma unroll 4
  for (int j = 0; j < BIN_EPB / 256; ++j) {
    int e = base + tid + j * 256;
    if (e < E) atomicAdd(&h[src[e] >> shift], 1);
  }
  __syncthreads();
  for (int i = tid; i < NB; i += 256)
    if (h[i]) h[i] = atomicAdd(&bucket_cursor[i], h[i]);
  __syncthreads();
#pragma unroll 4
  for (int j = 0; j < BIN_EPB / 256; ++j) {
    int e = base + tid + j * 256;
    if (e < E) {
      int s = src[e];
      int slot = atomicAdd(&h[s >> shift], 1);
      staging[slot] = make_int2(s, dst[e]);
    }
  }
}

__global__ __launch_bounds__(256) void k_binB(const int2* __restrict__ staging,
                                              const int* __restrict__ bucket_base,
                                              int* __restrict__ rp,
                                              int* __restrict__ edge_dst,
                                              int N, int shift) {
  __shared__ int2 buf[BIN_CAP];
  __shared__ int rcnt[256], rsc[256];
  int tid = threadIdx.x;
  int b = blockIdx.x;
  int lo = bucket_base[b], hi = bucket_base[b + 1];
  int S = hi - lo;
  if (S > BIN_CAP) S = BIN_CAP;
  int R = 1 << shift;
  int rmask = R - 1;
  for (int i = tid; i < S; i += 256) buf[i] = staging[lo + i];
  if (tid < R) rcnt[tid] = 0;
  __syncthreads();
  for (int i = tid; i < S; i += 256) atomicAdd(&rcnt[buf[i].x & rmask], 1);
  __syncthreads();
  if (tid < R) rsc[tid] = rcnt[tid];
  __syncthreads();
  for (int off = 1; off < 256; off <<= 1) {
    int add = (tid >= off && tid < R) ? rsc[tid - off] : 0;
    __syncthreads();
    if (tid < R) rsc[tid] += add;
    __syncthreads();
  }
  int row0 = b << shift;
  if (tid < R) {
    int ex = rsc[tid] - rcnt[tid];
    rcnt[tid] = ex;
    if (row0 + tid < N) rp[row0 + tid] = lo + ex;
  }
  __syncthreads();
  for (int i = tid; i < S; i += 256) {
    int r = buf[i].x & rmask;
    int k = atomicAdd(&rcnt[r], 1);
    edge_dst[lo + k] = buf[i].y;
  }
}

// ---------------- layer-1 shared-x aggregation: ALL 8 heads in one edge walk ----------
__global__ __launch_bounds__(256) void k_aggx(
    const int* __restrict__ rp, const int* __restrict__ edge_dst,
    const f16* __restrict__ xh, const float* __restrict__ ssrc8,
    const f16* __restrict__ sdst8h, f16* __restrict__ msgx, int c0, int c1) {
  __shared__ __half wbuf[4][64][8];   // per-wave slice, no cross-wave sharing
  int wv4 = threadIdx.x >> 6;
  int lane = threadIdx.x & 63;
  int node = c0 + blockIdx.x * 4 + wv4;
  if (node >= c1) return;             // safe: no __syncthreads below
  int e0 = rp[node], e1 = rp[node + 1];
  int hi = lane >> 5, li = lane & 31;
  float4 sA = *(const float4*)(ssrc8 + (size_t)node * 8);
  float4 sB = *(const float4*)(ssrc8 + (size_t)node * 8 + 4);
  float acc[8][4];
#pragma unroll
  for (int h = 0; h < 8; ++h)
#pragma unroll
    for (int cc = 0; cc < 4; ++cc) acc[h][cc] = 0.f;
  float rs[8];
#pragma unroll
  for (int h = 0; h < 8; ++h) rs[h] = 0.f;
  __half* wb = &wbuf[wv4][0][0];

  for (int base = e0; base < e1; base += 64) {
    int cnt = e1 - base; if (cnt > 64) cnt = 64;
    int d = 0;
    float w0 = 0.f, w1 = 0.f, w2 = 0.f, w3 = 0.f, w4 = 0.f, w5 = 0.f, w6 = 0.f, w7 = 0.f;
    if (lane < cnt) {
      d = edge_dst[base + lane];
      f16x8 dv = *(const f16x8*)(sdst8h + (size_t)d * 8);
      w0 = edge_w(sA.x + (float)dv[0]); w1 = edge_w(sA.y + (float)dv[1]);
      w2 = edge_w(sA.z + (float)dv[2]); w3 = edge_w(sA.w + (float)dv[3]);
      w4 = edge_w(sB.x + (float)dv[4]); w5 = edge_w(sB.y + (float)dv[5]);
      w6 = edge_w(sB.z + (float)dv[6]); w7 = edge_w(sB.w + (float)dv[7]);
      rs[0] += w0; rs[1] += w1; rs[2] += w2; rs[3] += w3;
      rs[4] += w4; rs[5] += w5; rs[6] += w6; rs[7] += w7;
    }
    float4 pk;
    ((__half2*)&pk)[0] = __float22half2_rn(make_float2(w0, w1));
    ((__half2*)&pk)[1] = __float22half2_rn(make_float2(w2, w3));
    ((__half2*)&pk)[2] = __float22half2_rn(make_float2(w4, w5));
    ((__half2*)&pk)[3] = __float22half2_rn(make_float2(w6, w7));
    *(float4*)(wb + lane * 8) = pk;
    __threadfence_block();            // order per-wave LDS write -> read

    int jj = 0;
    for (; jj + 2 <= cnt; jj += 2) {
      int e = jj + hi;                // half-wave 0 -> edge jj, 1 -> jj+1
      int de = __shfl(d, e);
      float4 wk = *(const float4*)(wb + e * 8);
      float2 wA = __half22float2(((__half2*)&wk)[0]);
      float2 wB = __half22float2(((__half2*)&wk)[1]);
      float2 wC = __half22float2(((__half2*)&wk)[2]);
      float2 wD = __half22float2(((__half2*)&wk)[3]);
      float2 xraw = *(const float2*)(xh + (size_t)de * 128 + li * 4);
      float2 x01 = __half22float2(((__half2*)&xraw)[0]);
      float2 x23 = __half22float2(((__half2*)&xraw)[1]);
      acc[0][0] += wA.x * x01.x; acc[0][1] += wA.x * x01.y; acc[0][2] += wA.x * x23.x; acc[0][3] += wA.x * x23.y;
      acc[1][0] += wA.y * x01.x; acc[1][1] += wA.y * x01.y; acc[1][2] += wA.y * x23.x; acc[1][3] += wA.y * x23.y;
      acc[2][0] += wB.x * x01.x; acc[2][1] += wB.x * x01.y; acc[2][2] += wB.x * x23.x; acc[2][3] += wB.x * x23.y;
      acc[3][0] += wB.y * x01.x; acc[3][1] += wB.y * x01.y; acc[3][2] += wB.y * x23.x; acc[3][3] += wB.y * x23.y;
      acc[4][0] += wC.x * x01.x; acc[4][1] += wC.x * x01.y; acc[4][2] += wC.x * x23.x; acc[4][3] += wC.x * x23.y;
      acc[5][0] += wC.y * x01.x; acc[5][1] += wC.y * x01.y; acc[5][2] += wC.y * x23.x; acc[5][3] += wC.y * x23.y;
      acc[6][0] += wD.x * x01.x; acc[6][1] += wD.x * x01.y; acc[6][2] += wD.x * x23.x; acc[6][3] += wD.x * x23.y;
      acc[7][0] += wD.y * x01.x; acc[7][1] += wD.y * x01.y; acc[7][2] += wD.y * x23.x; acc[7][3] += wD.y * x23.y;
    }
    if (jj < cnt) {                   // odd tail edge: half-wave 0 only
      int de = __shfl(d, jj);
      float4 wk = *(const float4*)(wb + jj * 8);
      if (hi == 0) {
        float2 wA = __half22float2(((__half2*)&wk)[0]);
        float2 wB = __half22float2(((__half2*)&wk)[1]);
        float2 wC = __half22float2(((__half2*)&wk)[2]);
        float2 wD = __half22float2(((__half2*)&wk)[3]);
        float2 xraw = *(const float2*)(xh + (size_t)de * 128 + li * 4);
        float2 x01 = __half22float2(((__half2*)&xraw)[0]);
        float2 x23 = __half22float2(((__half2*)&xraw)[1]);
        acc[0][0] += wA.x * x01.x; acc[0][1] += wA.x * x01.y; acc[0][2] += wA.x * x23.x; acc[0][3] += wA.x * x23.y;
        acc[1][0] += wA.y * x01.x; acc[1][1] += wA.y * x01.y; acc[1][2] += wA.y * x23.x; acc[1][3] += wA.y * x23.y;
        acc[2][0] += wB.x * x01.x; acc[2][1] += wB.x * x01.y; acc[2][2] += wB.x * x23.x; acc[2][3] += wB.x * x23.y;
        acc[3][0] += wB.y * x01.x; acc[3][1] += wB.y * x01.y; acc[3][2] += wB.y * x23.x; acc[3][3] += wB.y * x23.y;
        acc[4][0] += wC.x * x01.x; acc[4][1] += wC.x * x01.y; acc[4][2] += wC.x * x23.x; acc[4][3] += wC.x * x23.y;
        acc[5][0] += wC.y * x01.x; acc[5][1] += wC.y * x01.y; acc[5][2] += wC.y * x23.x; acc[5][3] += wC.y * x23.y;
        acc[6][0] += wD.x * x01.x; acc[6][1] += wD.x * x01.y; acc[6][2] += wD.x * x23.x; acc[6][3] += wD.x * x23.y;
        acc[7][0] += wD.y * x01.x; acc[7][1] += wD.y * x01.y; acc[7][2] += wD.y * x23.x; acc[7][3] += wD.y * x23.y;
      }
    }
  }

#pragma unroll
  for (int h = 0; h < 8; ++h)
#pragma unroll
    for (int cc = 0; cc < 4; ++cc) acc[h][cc] += __shfl_xor(acc[h][cc], 32);
#pragma unroll
  for (int off = 32; off > 0; off >>= 1)
#pragma unroll
    for (int h = 0; h < 8; ++h) rs[h] += __shfl_xor(rs[h], off);

  if (hi == 0) {
    f16* mp = msgx + (size_t)(node - c0) * 1024 + li * 4;
#pragma unroll
    for (int h = 0; h < 8; ++h) {
      float inv = 1.f / (rs[h] + EPS_DENOM);
      float2 st;
      ((__half2*)&st)[0] = __float22half2_rn(make_float2(acc[h][0] * inv, acc[h][1] * inv));
      ((__half2*)&st)[1] = __float22half2_rn(make_float2(acc[h][2] * inv, acc[h][3] * inv));
      *(float2*)(mp + h * 128) = st;
    }
  }
}

// ---------------- hout[n][h*64+c] = ELU( msgx[n][h] @ W1[h] ) (MFMA, per head) --------
__global__ __launch_bounds__(256) void k_houtgemm(
    const f16* __restrict__ msgx, const f16* __restrict__ w1t,
    f16* __restrict__ hout, int c0, int c1) {
  int h = blockIdx.y;
  int wave = threadIdx.x >> 6, lane = threadIdx.x & 63;
  int c = lane & 15, g = lane >> 4;
  int row0 = c0 + blockIdx.x * 64 + wave * 16;
  int arow = row0 + c; if (arow > c1 - 1) arow = c1 - 1;
  const f16* ap = msgx + ((size_t)(arow - c0) * 8 + h) * 128 + g * 8;
  const f16* bp = w1t + (size_t)h * 8192;
  f32x4 acc[4];
#pragma unroll
  for (int t = 0; t < 4; ++t) acc[t] = (f32x4){0.f, 0.f, 0.f, 0.f};
#pragma unroll
  for (int ks = 0; ks < 4; ++ks) {
    f16x8 af = *(const f16x8*)(ap + ks * 32);
#pragma unroll
    for (int t = 0; t < 4; ++t) {
      f16x8 bf = *(const f16x8*)(bp + (t * 16 + c) * 128 + ks * 32 + g * 8);
      acc[t] = __builtin_amdgcn_mfma_f32_16x16x32_f16(af, bf, acc[t], 0, 0, 0);
    }
  }
#pragma unroll
  for (int j = 0; j < 4; ++j) {
    int r = row0 + g * 4 + j;
    if (r < c1) {
#pragma unroll
      for (int t = 0; t < 4; ++t)
        hout[(size_t)(r - c0) * 512 + h * 64 + t * 16 + c] = (f16)elu_f(acc[t][j]);
    }
  }
}

// ---------------- h2 = hout @ W2 (K=512, MFMA) + fused s2 scores + fp16 h2h -----------
__global__ __launch_bounds__(256) void k_gemm2full(
    const f16* __restrict__ hout, const f16* __restrict__ w2t,
    const float* __restrict__ a2, f16* __restrict__ h2h,
    float* __restrict__ s2src, float* __restrict__ s2dst, int c0, int c1) {
  int wave = threadIdx.x >> 6, lane = threadIdx.x & 63;
  int c = lane & 15, g = lane >> 4;
  int row0 = c0 + blockIdx.x * 64 + wave * 16;
  int arow = row0 + c; if (arow > c1 - 1) arow = c1 - 1;
  const f16* ap = hout + (size_t)(arow - c0) * 512 + g * 8;
  f32x4 acc[8];
#pragma unroll
  for (int t = 0; t < 8; ++t) acc[t] = (f32x4){0.f, 0.f, 0.f, 0.f};
#pragma unroll
  for (int ks = 0; ks < 16; ++ks) {
    f16x8 af = *(const f16x8*)(ap + ks * 32);
#pragma unroll
    for (int t = 0; t < 8; ++t) {
      f16x8 bf = *(const f16x8*)(w2t + (size_t)(t * 16 + c) * 512 + ks * 32 + g * 8);
      acc[t] = __builtin_amdgcn_mfma_f32_16x16x32_f16(af, bf, acc[t], 0, 0, 0);
    }
  }
  float av0[8], av1[8];
#pragma unroll
  for (int t = 0; t < 8; ++t) {
    av0[t] = a2[t * 16 + c];
    av1[t] = a2[128 + t * 16 + c];
  }
#pragma unroll
  for (int j = 0; j < 4; ++j) {
    int r = row0 + g * 4 + j;
    float s0 = 0.f, s1 = 0.f;
#pragma unroll
    for (int t = 0; t < 8; ++t) {
      float v = acc[t][j];
      if (r < c1) h2h[(size_t)r * 128 + t * 16 + c] = (f16)v;
      s0 += v * av0[t];
      s1 += v * av1[t];
    }
    s0 += __shfl_xor(s0, 1); s0 += __shfl_xor(s0, 2);
    s0 += __shfl_xor(s0, 4); s0 += __shfl_xor(s0, 8);
    s1 += __shfl_xor(s1, 1); s1 += __shfl_xor(s1, 2);
    s1 += __shfl_xor(s1, 4); s1 += __shfl_xor(s1, 8);
    if (c == 0 && r < c1) { s2src[r] = s0; s2dst[r] = s1; }
  }
}

// ---------------- layer-2 aggregation: cooperative-edge + deg==0 fallback + ELU -------
__global__ void k_agg2(const int* __restrict__ rp, const int* __restrict__ edge_dst,
                       const __half* __restrict__ h2h, const float* __restrict__ ssrc,
                       const float* __restrict__ sdst, const float* __restrict__ x,
                       float* __restrict__ out, int N) {
  int wv = (blockIdx.x * blockDim.x + threadIdx.x) >> 6;
  int lane = threadIdx.x & 63;
  if (wv >= N) return;
  int e0 = rp[wv], e1 = rp[wv + 1];
  if (e0 == e1) {
    float2 xv = *(const float2*)(x + (size_t)wv * 128 + 2 * lane);
    *(float2*)(out + (size_t)wv * 128 + 2 * lane) = make_float2(elu_f(xv.x), elu_f(xv.y));
    return;
  }
  float ss = ssrc[wv];
  int hi = lane >> 5;
  int colB = (lane & 31) << 2;
  float a0 = 0.f, a1 = 0.f, a2v = 0.f, a3 = 0.f, rsumL = 0.f;
  for (int base = e0; base < e1; base += 64) {
    int cnt = e1 - base; if (cnt > 64) cnt = 64;
    int d = 0; float w = 0.f;
    if (lane < cnt) {
      d = edge_dst[base + lane];
      w = edge_w(ss + sdst[d]);
    }
    rsumL += w;
    int jj = 0;
#pragma unroll 4
    for (; jj + 2 <= cnt; jj += 2) {
      int sel = jj + hi;
      int dj = __shfl(d, sel);
      float wj = __shfl(w, sel);
      float2 raw = *(const float2*)(h2h + ((size_t)dj << 7) + colB);
      float2 f01 = __half22float2(*(const __half2*)&raw.x);
      float2 f23 = __half22float2(*(const __half2*)&raw.y);
      a0 += wj * f01.x; a1 += wj * f01.y; a2v += wj * f23.x; a3 += wj * f23.y;
    }
    if (jj < cnt) {
      int dj = __shfl(d, jj);
      float wj = __shfl(w, jj);
      if (hi == 0) {
        float2 raw = *(const float2*)(h2h + ((size_t)dj << 7) + colB);
        float2 f01 = __half22float2(*(const __half2*)&raw.x);
        float2 f23 = __half22float2(*(const __half2*)&raw.y);
        a0 += wj * f01.x; a1 += wj * f01.y; a2v += wj * f23.x; a3 += wj * f23.y;
      }
    }
  }
  a0 += __shfl_xor(a0, 32); a1 += __shfl_xor(a1, 32);
  a2v += __shfl_xor(a2v, 32); a3 += __shfl_xor(a3, 32);
  float rsum = rsumL;
#pragma unroll
  for (int off = 32; off > 0; off >>= 1) rsum += __shfl_xor(rsum, off);
  float inv = 1.f / (rsum + EPS_DENOM);
  if (hi == 0) {
    *(float4*)(out + (size_t)wv * 128 + colB) =
        make_float4(elu_f(a0 * inv), elu_f(a1 * inv), elu_f(a2v * inv), elu_f(a3 * inv));
  }
}

extern "C" void kernel_launch(void* const* d_in, const int* in_sizes, int n_in,
                              void* d_out, int out_size, void* d_ws, size_t ws_size,
                              hipStream_t stream) {
  (void)n_in; (void)out_size;
  const float* x  = (const float*)d_in[0];
  const int*   ei = (const int*)d_in[1];
  const float* W1 = (const float*)d_in[2];
  const float* a1 = (const float*)d_in[3];
  const float* W2 = (const float*)d_in[4];
  const float* a2 = (const float*)d_in[5];
  float* out = (float*)d_out;
  const int N = in_sizes[0] / NFEAT;
  const int E = in_sizes[1] / 2;
  const int* src  = ei;
  const int* dstv = ei + E;

  int shift = 7;
  while ((((N - 1) >> shift) + 1) > MAXNB) ++shift;
  const int NB = ((N - 1) >> shift) + 1;

  // adaptive chunk count: smallest nc in {4,8,16,32} whose footprint fits ws_size
  int nc = 4;
  for (;;) {
    int cN = (N + nc - 1) / nc;
    size_t sz[16] = {
      (size_t)E * 8 > (size_t)cN * 2048 ? (size_t)E * 8 : (size_t)cN * 2048, // msgx/staging
      (size_t)cN * 1024,              // hout
      (size_t)N * 256,                // h2h
      (size_t)N * 256,                // xh
      (size_t)E * 4,                  // edge_dst
      (size_t)N * 32,                 // ssrc8
      (size_t)N * 16,                 // sdst8h
      (size_t)N * 4, (size_t)N * 4,   // s2src, s2dst
      (size_t)(N + 1) * 4,            // rp
      (size_t)(NB + 1) * 4, (size_t)(NB + 1) * 4, (size_t)(NB + 1) * 4,
      (size_t)NHEADS * 64 * 128 * 2,  // w1t
      (size_t)128 * 512 * 2,          // w2t
      (size_t)16 * 128 * 2            // uv16
    };
    size_t need = 0;
    for (int i = 0; i < 16; ++i) need += (sz[i] + 255) & ~(size_t)255;
    need += 4096;
    if (need <= ws_size || nc >= 32) break;
    nc <<= 1;
  }
  const int chunkN = (N + nc - 1) / nc;

  char* wp = (char*)d_ws;
  size_t off = 0;
  auto mk = [&](size_t bytes) -> void* {
    void* p = wp + off;
    off += (bytes + 255) & ~(size_t)255;
    return p;
  };
  size_t szR0 = (size_t)E * 8;
  if ((size_t)chunkN * 2048 > szR0) szR0 = (size_t)chunkN * 2048;
  f16*  msgx     = (f16*)mk(szR0);                   // aliases CSR staging
  int2* staging  = (int2*)msgx;
  f16*  hout     = (f16*)mk((size_t)chunkN * 512 * 2);
  f16*  h2h      = (f16*)mk((size_t)N * 128 * 2);
  f16*  xh       = (f16*)mk((size_t)N * 128 * 2);
  int*  edge_dst = (int*)mk((size_t)E * 4);
  float* ssrc8   = (float*)mk((size_t)N * 8 * 4);
  f16*  sdst8h   = (f16*)mk((size_t)N * 8 * 2);
  float* s2src   = (float*)mk((size_t)N * 4);
  float* s2dst   = (float*)mk((size_t)N * 4);
  int*  rp       = (int*)mk((size_t)(N + 1) * 4);
  int*  bhist    = (int*)mk((size_t)(NB + 1) * 4);
  int*  bbase    = (int*)mk((size_t)(NB + 1) * 4);
  int*  bcur     = (int*)mk((size_t)(NB + 1) * 4);
  f16*  w1t      = (f16*)mk((size_t)NHEADS * 64 * 128 * 2);
  f16*  w2t      = (f16*)mk((size_t)128 * 512 * 2);
  f16*  uv16     = (f16*)mk((size_t)16 * 128 * 2);

  // dtype prep + score precompute (uv folded into cvt_w; 516 blocks cover w1+w2+uv)
  k_cvt_x<<<1024, 256, 0, stream>>>(x, xh, (long)N * 16);
  k_cvt_w<<<516, 256, 0, stream>>>(W1, W2, a1, w1t, w2t, uv16);
  k_score8<<<(N + 63) / 64, 256, 0, stream>>>(xh, uv16, ssrc8, sdst8h, N);

  // CSR build
  (void)hipMemsetAsync(bhist, 0, (size_t)NB * 4, stream);
  int binBlocks = (E + BIN_EPB - 1) / BIN_EPB;
  k_bhist<<<binBlocks, 256, 0, stream>>>(src, bhist, E, NB, shift);
  k_bscan<<<1, 1024, 0, stream>>>(bhist, bbase, bcur, rp, NB, N, E);
  k_binA<<<binBlocks, 256, 0, stream>>>(src, dstv, bcur, staging, E, NB, shift);
  k_binB<<<NB, 256, 0, stream>>>(staging, bbase, rp, edge_dst, N, shift);

  // layer 1 (all 8 heads) + layer-2 GEMM, per node-chunk
  for (int ch = 0; ch < nc; ++ch) {
    int c0 = ch * chunkN;
    if (c0 >= N) break;
    int c1 = c0 + chunkN; if (c1 > N) c1 = N;
    int cn = c1 - c0;
    k_aggx<<<(cn + 3) / 4, 256, 0, stream>>>(rp, edge_dst, xh, ssrc8, sdst8h, msgx, c0, c1);
    k_houtgemm<<<dim3((cn + 63) / 64, NHEADS), 256, 0, stream>>>(msgx, w1t, hout, c0, c1);
    k_gemm2full<<<(cn + 63) / 64, 256, 0, stream>>>(hout, w2t, a2, h2h, s2src, s2dst, c0, c1);
  }

  // layer-2 aggregation
  int wb = (N + 3) / 4;
  k_agg2<<<wb, 256, 0, stream>>>(rp, edge_dst, (const __half*)h2h, s2src, s2dst, x, out, N);
}

// Round 12
// 795.542 us; speedup vs baseline: 2.9207x; 1.0406x over previous
//
#include <hip/hip_runtime.h>
#include <hip/hip_fp16.h>

#define NFEAT 128
#define NHID 64
#define NOUT 128
#define NHEADS 8
#define ALPHA_SLOPE 0.2f
#define EPS_DENOM 1e-16f

#define MAXNB 1024
#define BIN_EPB 12288
#define BIN_CAP 6144

typedef _Float16 f16;
typedef f16 f16x8 __attribute__((ext_vector_type(8)));
typedef float f32x4 __attribute__((ext_vector_type(4)));

static __device__ __forceinline__ float elu_f(float v) {
  return v > 0.f ? v : __expf(v) - 1.f;
}
static __device__ __forceinline__ float edge_w(float sc) {
  float lr = sc > 0.f ? sc : ALPHA_SLOPE * sc;
  return __expf(-lr);
}

// region 0: W1 [8][128][64] -> w1t [8][64][128] fp16; region 1: W2 -> w2t [128][512] fp16;
// region 2: uv16[16][128] = {W1[h]@a1[h][:64], W1[h]@a1[h][64:]} (score identity)
__global__ void k_cvt_w(const float* __restrict__ W1, const float* __restrict__ W2,
                        const float* __restrict__ a1,
                        f16* __restrict__ w1t, f16* __restrict__ w2t,
                        f16* __restrict__ uv16) {
  int idx = blockIdx.x * 256 + threadIdx.x;
  if (idx < NHEADS * 128 * 64) {
    int h = idx >> 13, rem = idx & 8191, c = rem >> 7, k = rem & 127;
    w1t[idx] = (f16)W1[h * 8192 + k * 64 + c];
  } else if (idx < 2 * NHEADS * 128 * 64) {
    int j = idx - NHEADS * 128 * 64;
    int c = j >> 9, k = j & 511;
    w2t[j] = (f16)W2[k * 128 + c];
  } else {
    int id = idx - 2 * NHEADS * 128 * 64;
    if (id < 1024) {
      int h = id >> 7, k = id & 127;
      const float* wrow = W1 + h * 8192 + k * 64;
      const float* ah = a1 + h * 128;
      float u = 0.f, v = 0.f;
      for (int c = 0; c < 64; ++c) {
        float wv_ = wrow[c];
        u += wv_ * ah[c];
        v += wv_ * ah[64 + c];
      }
      uv16[h * 128 + k] = (f16)u;
      uv16[(8 + h) * 128 + k] = (f16)v;
    }
  }
}

// fused: x f32 -> xh fp16 AND [N,128]@[128,16] MFMA -> ssrc8 f32 / sdst8h fp16
__global__ __launch_bounds__(256) void k_prep_x(
    const float* __restrict__ x, const f16* __restrict__ uv16,
    f16* __restrict__ xh, float* __restrict__ ssrc8, f16* __restrict__ sdst8h, int N) {
  int wave = threadIdx.x >> 6, lane = threadIdx.x & 63;
  int c = lane & 15, g = lane >> 4;
  int row0 = blockIdx.x * 64 + wave * 16;
  f16x8 bf[4];
#pragma unroll
  for (int ks = 0; ks < 4; ++ks)
    bf[ks] = *(const f16x8*)(uv16 + c * 128 + ks * 32 + g * 8);
  int arow = row0 + c; if (arow > N - 1) arow = N - 1;
  const float* xp = x + (size_t)arow * 128 + g * 8;
  f16* xhp = xh + (size_t)arow * 128 + g * 8;
  f32x4 acc = (f32x4){0.f, 0.f, 0.f, 0.f};
#pragma unroll
  for (int ks = 0; ks < 4; ++ks) {
    float4 v0 = *(const float4*)(xp + ks * 32);
    float4 v1 = *(const float4*)(xp + ks * 32 + 4);
    f16x8 af;
    af[0] = (f16)v0.x; af[1] = (f16)v0.y; af[2] = (f16)v0.z; af[3] = (f16)v0.w;
    af[4] = (f16)v1.x; af[5] = (f16)v1.y; af[6] = (f16)v1.z; af[7] = (f16)v1.w;
    *(f16x8*)(xhp + ks * 32) = af;   // duplicate tail writes benign (same data)
    acc = __builtin_amdgcn_mfma_f32_16x16x32_f16(af, bf[ks], acc, 0, 0, 0);
  }
#pragma unroll
  for (int j = 0; j < 4; ++j) {
    int r = row0 + g * 4 + j;
    if (r < N) {
      if (c < 8) ssrc8[(size_t)r * 8 + c] = acc[j];
      else       sdst8h[(size_t)r * 8 + c - 8] = (f16)acc[j];
    }
  }
}

// ---------------- CSR build: 2-pass bucketed counting sort ----------------
__global__ __launch_bounds__(256) void k_bhist(const int* __restrict__ src,
                                               int* __restrict__ bhist,
                                               int E, int NB, int shift) {
  __shared__ int h[MAXNB];
  int tid = threadIdx.x;
  for (int i = tid; i < NB; i += 256) h[i] = 0;
  __syncthreads();
  int base = blockIdx.x * BIN_EPB;
#pragma unroll 4
  for (int j = 0; j < BIN_EPB / 256; ++j) {
    int e = base + tid + j * 256;
    if (e < E) atomicAdd(&h[src[e] >> shift], 1);
  }
  __syncthreads();
  for (int i = tid; i < NB; i += 256)
    if (h[i]) atomicAdd(&bhist[i], h[i]);
}

__global__ __launch_bounds__(1024) void k_bscan(const int* __restrict__ bhist,
                                                int* __restrict__ bucket_base,
                                                int* __restrict__ bucket_cursor,
                                                int* __restrict__ rp,
                                                int NB, int N, int E) {
  __shared__ int sh[1024];
  int i = threadIdx.x;
  int v = (i < NB) ? bhist[i] : 0;
  sh[i] = v;
  __syncthreads();
  for (int off = 1; off < 1024; off <<= 1) {
    int add = (i >= off) ? sh[i - off] : 0;
    __syncthreads();
    sh[i] += add;
    __syncthreads();
  }
  if (i < NB) {
    int ex = sh[i] - v;
    bucket_base[i] = ex;
    bucket_cursor[i] = ex;
  }
  if (i == 0) {
    bucket_base[NB] = E;
    rp[N] = E;
  }
}

__global__ __launch_bounds__(256) void k_binA(const int* __restrict__ src,
                                              const int* __restrict__ dst,
                                              int* __restrict__ bucket_cursor,
                                              int2* __restrict__ staging,
                                              int E, int NB, int shift) {
  __shared__ int h[MAXNB];
  int tid = threadIdx.x;
  for (int i = tid; i < NB; i += 256) h[i] = 0;
  __syncthreads();
  int base = blockIdx.x * BIN_EPB;
#pragma unroll 4
  for (int j = 0; j < BIN_EPB / 256; ++j) {
    int e = base + tid + j * 256;
    if (e < E) atomicAdd(&h[src[e] >> shift], 1);
  }
  __syncthreads();
  for (int i = tid; i < NB; i += 256)
    if (h[i]) h[i] = atomicAdd(&bucket_cursor[i], h[i]);
  __syncthreads();
#pragma unroll 4
  for (int j = 0; j < BIN_EPB / 256; ++j) {
    int e = base + tid + j * 256;
    if (e < E) {
      int s = src[e];
      int slot = atomicAdd(&h[s >> shift], 1);
      staging[slot] = make_int2(s, dst[e]);
    }
  }
}

__global__ __launch_bounds__(256) void k_binB(const int2* __restrict__ staging,
                                              const int* __restrict__ bucket_base,
                                              int* __restrict__ rp,
                                              int* __restrict__ edge_dst,
                                              int N, int shift) {
  __shared__ int2 buf[BIN_CAP];
  __shared__ int rcnt[256], rsc[256];
  int tid = threadIdx.x;
  int b = blockIdx.x;
  int lo = bucket_base[b], hi = bucket_base[b + 1];
  int S = hi - lo;
  if (S > BIN_CAP) S = BIN_CAP;
  int R = 1 << shift;
  int rmask = R - 1;
  for (int i = tid; i < S; i += 256) buf[i] = staging[lo + i];
  if (tid < R) rcnt[tid] = 0;
  __syncthreads();
  for (int i = tid; i < S; i += 256) atomicAdd(&rcnt[buf[i].x & rmask], 1);
  __syncthreads();
  if (tid < R) rsc[tid] = rcnt[tid];
  __syncthreads();
  for (int off = 1; off < 256; off <<= 1) {
    int add = (tid >= off && tid < R) ? rsc[tid - off] : 0;
    __syncthreads();
    if (tid < R) rsc[tid] += add;
    __syncthreads();
  }
  int row0 = b << shift;
  if (tid < R) {
    int ex = rsc[tid] - rcnt[tid];
    rcnt[tid] = ex;
    if (row0 + tid < N) rp[row0 + tid] = lo + ex;
  }
  __syncthreads();
  for (int i = tid; i < S; i += 256) {
    int r = buf[i].x & rmask;
    int k = atomicAdd(&rcnt[r], 1);
    edge_dst[lo + k] = buf[i].y;
  }
}

// ---------------- layer-1 shared-x aggregation: ALL 8 heads in one edge walk ----------
__global__ __launch_bounds__(256) void k_aggx(
    const int* __restrict__ rp, const int* __restrict__ edge_dst,
    const f16* __restrict__ xh, const float* __restrict__ ssrc8,
    const f16* __restrict__ sdst8h, f16* __restrict__ msgx, int c0, int c1) {
  __shared__ __half wbuf[4][64][8];   // per-wave slice, no cross-wave sharing
  int wv4 = threadIdx.x >> 6;
  int lane = threadIdx.x & 63;
  int node = c0 + blockIdx.x * 4 + wv4;
  if (node >= c1) return;             // safe: no __syncthreads below
  int e0 = rp[node], e1 = rp[node + 1];
  int hi = lane >> 5, li = lane & 31;
  float4 sA = *(const float4*)(ssrc8 + (size_t)node * 8);
  float4 sB = *(const float4*)(ssrc8 + (size_t)node * 8 + 4);
  float acc[8][4];
#pragma unroll
  for (int h = 0; h < 8; ++h)
#pragma unroll
    for (int cc = 0; cc < 4; ++cc) acc[h][cc] = 0.f;
  float rs[8];
#pragma unroll
  for (int h = 0; h < 8; ++h) rs[h] = 0.f;
  __half* wb = &wbuf[wv4][0][0];

  for (int base = e0; base < e1; base += 64) {
    int cnt = e1 - base; if (cnt > 64) cnt = 64;
    int d = 0;
    float w0 = 0.f, w1 = 0.f, w2 = 0.f, w3 = 0.f, w4 = 0.f, w5 = 0.f, w6 = 0.f, w7 = 0.f;
    if (lane < cnt) {
      d = edge_dst[base + lane];
      f16x8 dv = *(const f16x8*)(sdst8h + (size_t)d * 8);
      w0 = edge_w(sA.x + (float)dv[0]); w1 = edge_w(sA.y + (float)dv[1]);
      w2 = edge_w(sA.z + (float)dv[2]); w3 = edge_w(sA.w + (float)dv[3]);
      w4 = edge_w(sB.x + (float)dv[4]); w5 = edge_w(sB.y + (float)dv[5]);
      w6 = edge_w(sB.z + (float)dv[6]); w7 = edge_w(sB.w + (float)dv[7]);
      rs[0] += w0; rs[1] += w1; rs[2] += w2; rs[3] += w3;
      rs[4] += w4; rs[5] += w5; rs[6] += w6; rs[7] += w7;
    }
    float4 pk;
    ((__half2*)&pk)[0] = __float22half2_rn(make_float2(w0, w1));
    ((__half2*)&pk)[1] = __float22half2_rn(make_float2(w2, w3));
    ((__half2*)&pk)[2] = __float22half2_rn(make_float2(w4, w5));
    ((__half2*)&pk)[3] = __float22half2_rn(make_float2(w6, w7));
    *(float4*)(wb + lane * 8) = pk;
    __threadfence_block();            // order per-wave LDS write -> read

    int jj = 0;
    for (; jj + 2 <= cnt; jj += 2) {
      int e = jj + hi;                // half-wave 0 -> edge jj, 1 -> jj+1
      int de = __shfl(d, e);
      float4 wk = *(const float4*)(wb + e * 8);
      float2 wA = __half22float2(((__half2*)&wk)[0]);
      float2 wB = __half22float2(((__half2*)&wk)[1]);
      float2 wC = __half22float2(((__half2*)&wk)[2]);
      float2 wD = __half22float2(((__half2*)&wk)[3]);
      float2 xraw = *(const float2*)(xh + (size_t)de * 128 + li * 4);
      float2 x01 = __half22float2(((__half2*)&xraw)[0]);
      float2 x23 = __half22float2(((__half2*)&xraw)[1]);
      acc[0][0] += wA.x * x01.x; acc[0][1] += wA.x * x01.y; acc[0][2] += wA.x * x23.x; acc[0][3] += wA.x * x23.y;
      acc[1][0] += wA.y * x01.x; acc[1][1] += wA.y * x01.y; acc[1][2] += wA.y * x23.x; acc[1][3] += wA.y * x23.y;
      acc[2][0] += wB.x * x01.x; acc[2][1] += wB.x * x01.y; acc[2][2] += wB.x * x23.x; acc[2][3] += wB.x * x23.y;
      acc[3][0] += wB.y * x01.x; acc[3][1] += wB.y * x01.y; acc[3][2] += wB.y * x23.x; acc[3][3] += wB.y * x23.y;
      acc[4][0] += wC.x * x01.x; acc[4][1] += wC.x * x01.y; acc[4][2] += wC.x * x23.x; acc[4][3] += wC.x * x23.y;
      acc[5][0] += wC.y * x01.x; acc[5][1] += wC.y * x01.y; acc[5][2] += wC.y * x23.x; acc[5][3] += wC.y * x23.y;
      acc[6][0] += wD.x * x01.x; acc[6][1] += wD.x * x01.y; acc[6][2] += wD.x * x23.x; acc[6][3] += wD.x * x23.y;
      acc[7][0] += wD.y * x01.x; acc[7][1] += wD.y * x01.y; acc[7][2] += wD.y * x23.x; acc[7][3] += wD.y * x23.y;
    }
    if (jj < cnt) {                   // odd tail edge: half-wave 0 only
      int de = __shfl(d, jj);
      float4 wk = *(const float4*)(wb + jj * 8);
      if (hi == 0) {
        float2 wA = __half22float2(((__half2*)&wk)[0]);
        float2 wB = __half22float2(((__half2*)&wk)[1]);
        float2 wC = __half22float2(((__half2*)&wk)[2]);
        float2 wD = __half22float2(((__half2*)&wk)[3]);
        float2 xraw = *(const float2*)(xh + (size_t)de * 128 + li * 4);
        float2 x01 = __half22float2(((__half2*)&xraw)[0]);
        float2 x23 = __half22float2(((__half2*)&xraw)[1]);
        acc[0][0] += wA.x * x01.x; acc[0][1] += wA.x * x01.y; acc[0][2] += wA.x * x23.x; acc[0][3] += wA.x * x23.y;
        acc[1][0] += wA.y * x01.x; acc[1][1] += wA.y * x01.y; acc[1][2] += wA.y * x23.x; acc[1][3] += wA.y * x23.y;
        acc[2][0] += wB.x * x01.x; acc[2][1] += wB.x * x01.y; acc[2][2] += wB.x * x23.x; acc[2][3] += wB.x * x23.y;
        acc[3][0] += wB.y * x01.x; acc[3][1] += wB.y * x01.y; acc[3][2] += wB.y * x23.x; acc[3][3] += wB.y * x23.y;
        acc[4][0] += wC.x * x01.x; acc[4][1] += wC.x * x01.y; acc[4][2] += wC.x * x23.x; acc[4][3] += wC.x * x23.y;
        acc[5][0] += wC.y * x01.x; acc[5][1] += wC.y * x01.y; acc[5][2] += wC.y * x23.x; acc[5][3] += wC.y * x23.y;
        acc[6][0] += wD.x * x01.x; acc[6][1] += wD.x * x01.y; acc[6][2] += wD.x * x23.x; acc[6][3] += wD.x * x23.y;
        acc[7][0] += wD.y * x01.x; acc[7][1] += wD.y * x01.y; acc[7][2] += wD.y * x23.x; acc[7][3] += wD.y * x23.y;
      }
    }
  }

#pragma unroll
  for (int h = 0; h < 8; ++h)
#pragma unroll
    for (int cc = 0; cc < 4; ++cc) acc[h][cc] += __shfl_xor(acc[h][cc], 32);
#pragma unroll
  for (int off = 32; off > 0; off >>= 1)
#pragma unroll
    for (int h = 0; h < 8; ++h) rs[h] += __shfl_xor(rs[h], off);

  if (hi == 0) {
    f16* mp = msgx + (size_t)(node - c0) * 1024 + li * 4;
#pragma unroll
    for (int h = 0; h < 8; ++h) {
      float inv = 1.f / (rs[h] + EPS_DENOM);
      float2 st;
      ((__half2*)&st)[0] = __float22half2_rn(make_float2(acc[h][0] * inv, acc[h][1] * inv));
      ((__half2*)&st)[1] = __float22half2_rn(make_float2(acc[h][2] * inv, acc[h][3] * inv));
      *(float2*)(mp + h * 128) = st;
    }
  }
}

// ---------------- fused layer-1 GEMM + ELU (LDS tile) + layer-2 K=512 GEMM ------------
// block: 256 thr = 4 waves, 64 rows. Stage 1: hout tile [64][512] fp16 in LDS (+8 pad).
// Stage 2: A-frags from LDS; fused s2 scores + fp16 h2h output.
__global__ __launch_bounds__(256) void k_fusedgemm(
    const f16* __restrict__ msgx, const f16* __restrict__ w1t,
    const f16* __restrict__ w2t, const float* __restrict__ a2,
    f16* __restrict__ h2h, float* __restrict__ s2src, float* __restrict__ s2dst,
    int c0, int c1) {
  __shared__ f16 hl[64][520];   // 64 rows x 512 + 8 pad (bank-spread for stage-2 reads)
  int wave = threadIdx.x >> 6, lane = threadIdx.x & 63;
  int c = lane & 15, g = lane >> 4;
  int row0 = c0 + blockIdx.x * 64 + wave * 16;
  int arow = row0 + c; if (arow > c1 - 1) arow = c1 - 1;

  // stage 1: hout[r][h*64+col] = ELU(msgx[r][h] @ W1[h])
#pragma unroll
  for (int h = 0; h < 8; ++h) {
    const f16* ap = msgx + ((size_t)(arow - c0) * 8 + h) * 128 + g * 8;
    const f16* bp = w1t + (size_t)h * 8192;
    f32x4 acc[4];
#pragma unroll
    for (int t = 0; t < 4; ++t) acc[t] = (f32x4){0.f, 0.f, 0.f, 0.f};
#pragma unroll
    for (int ks = 0; ks < 4; ++ks) {
      f16x8 af = *(const f16x8*)(ap + ks * 32);
#pragma unroll
      for (int t = 0; t < 4; ++t) {
        f16x8 bf = *(const f16x8*)(bp + (t * 16 + c) * 128 + ks * 32 + g * 8);
        acc[t] = __builtin_amdgcn_mfma_f32_16x16x32_f16(af, bf, acc[t], 0, 0, 0);
      }
    }
#pragma unroll
    for (int j = 0; j < 4; ++j) {
      int lr = wave * 16 + g * 4 + j;
#pragma unroll
      for (int t = 0; t < 4; ++t)
        hl[lr][h * 64 + t * 16 + c] = (f16)elu_f(acc[t][j]);
    }
  }
  __syncthreads();

  // stage 2: h2 = hout @ W2 (K=512) from LDS
  f32x4 acc2[8];
#pragma unroll
  for (int t = 0; t < 8; ++t) acc2[t] = (f32x4){0.f, 0.f, 0.f, 0.f};
#pragma unroll
  for (int ks = 0; ks < 16; ++ks) {
    f16x8 af = *(const f16x8*)&hl[wave * 16 + c][ks * 32 + g * 8];
#pragma unroll
    for (int t = 0; t < 8; ++t) {
      f16x8 bf = *(const f16x8*)(w2t + (size_t)(t * 16 + c) * 512 + ks * 32 + g * 8);
      acc2[t] = __builtin_amdgcn_mfma_f32_16x16x32_f16(af, bf, acc2[t], 0, 0, 0);
    }
  }
  float av0[8], av1[8];
#pragma unroll
  for (int t = 0; t < 8; ++t) {
    av0[t] = a2[t * 16 + c];
    av1[t] = a2[128 + t * 16 + c];
  }
#pragma unroll
  for (int j = 0; j < 4; ++j) {
    int r = row0 + g * 4 + j;
    float s0 = 0.f, s1 = 0.f;
#pragma unroll
    for (int t = 0; t < 8; ++t) {
      float v = acc2[t][j];
      if (r < c1) h2h[(size_t)r * 128 + t * 16 + c] = (f16)v;
      s0 += v * av0[t];
      s1 += v * av1[t];
    }
    s0 += __shfl_xor(s0, 1); s0 += __shfl_xor(s0, 2);
    s0 += __shfl_xor(s0, 4); s0 += __shfl_xor(s0, 8);
    s1 += __shfl_xor(s1, 1); s1 += __shfl_xor(s1, 2);
    s1 += __shfl_xor(s1, 4); s1 += __shfl_xor(s1, 8);
    if (c == 0 && r < c1) { s2src[r] = s0; s2dst[r] = s1; }
  }
}

// ---------------- layer-2 aggregation: cooperative-edge + deg==0 fallback + ELU -------
__global__ void k_agg2(const int* __restrict__ rp, const int* __restrict__ edge_dst,
                       const __half* __restrict__ h2h, const float* __restrict__ ssrc,
                       const float* __restrict__ sdst, const float* __restrict__ x,
                       float* __restrict__ out, int N) {
  int wv = (blockIdx.x * blockDim.x + threadIdx.x) >> 6;
  int lane = threadIdx.x & 63;
  if (wv >= N) return;
  int e0 = rp[wv], e1 = rp[wv + 1];
  if (e0 == e1) {
    float2 xv = *(const float2*)(x + (size_t)wv * 128 + 2 * lane);
    *(float2*)(out + (size_t)wv * 128 + 2 * lane) = make_float2(elu_f(xv.x), elu_f(xv.y));
    return;
  }
  float ss = ssrc[wv];
  int hi = lane >> 5;
  int colB = (lane & 31) << 2;
  float a0 = 0.f, a1 = 0.f, a2v = 0.f, a3 = 0.f, rsumL = 0.f;
  for (int base = e0; base < e1; base += 64) {
    int cnt = e1 - base; if (cnt > 64) cnt = 64;
    int d = 0; float w = 0.f;
    if (lane < cnt) {
      d = edge_dst[base + lane];
      w = edge_w(ss + sdst[d]);
    }
    rsumL += w;
    int jj = 0;
#pragma unroll 4
    for (; jj + 2 <= cnt; jj += 2) {
      int sel = jj + hi;
      int dj = __shfl(d, sel);
      float wj = __shfl(w, sel);
      float2 raw = *(const float2*)(h2h + ((size_t)dj << 7) + colB);
      float2 f01 = __half22float2(*(const __half2*)&raw.x);
      float2 f23 = __half22float2(*(const __half2*)&raw.y);
      a0 += wj * f01.x; a1 += wj * f01.y; a2v += wj * f23.x; a3 += wj * f23.y;
    }
    if (jj < cnt) {
      int dj = __shfl(d, jj);
      float wj = __shfl(w, jj);
      if (hi == 0) {
        float2 raw = *(const float2*)(h2h + ((size_t)dj << 7) + colB);
        float2 f01 = __half22float2(*(const __half2*)&raw.x);
        float2 f23 = __half22float2(*(const __half2*)&raw.y);
        a0 += wj * f01.x; a1 += wj * f01.y; a2v += wj * f23.x; a3 += wj * f23.y;
      }
    }
  }
  a0 += __shfl_xor(a0, 32); a1 += __shfl_xor(a1, 32);
  a2v += __shfl_xor(a2v, 32); a3 += __shfl_xor(a3, 32);
  float rsum = rsumL;
#pragma unroll
  for (int off = 32; off > 0; off >>= 1) rsum += __shfl_xor(rsum, off);
  float inv = 1.f / (rsum + EPS_DENOM);
  if (hi == 0) {
    *(float4*)(out + (size_t)wv * 128 + colB) =
        make_float4(elu_f(a0 * inv), elu_f(a1 * inv), elu_f(a2v * inv), elu_f(a3 * inv));
  }
}

extern "C" void kernel_launch(void* const* d_in, const int* in_sizes, int n_in,
                              void* d_out, int out_size, void* d_ws, size_t ws_size,
                              hipStream_t stream) {
  (void)n_in; (void)out_size;
  const float* x  = (const float*)d_in[0];
  const int*   ei = (const int*)d_in[1];
  const float* W1 = (const float*)d_in[2];
  const float* a1 = (const float*)d_in[3];
  const float* W2 = (const float*)d_in[4];
  const float* a2 = (const float*)d_in[5];
  float* out = (float*)d_out;
  const int N = in_sizes[0] / NFEAT;
  const int E = in_sizes[1] / 2;
  const int* src  = ei;
  const int* dstv = ei + E;

  int shift = 7;
  while ((((N - 1) >> shift) + 1) > MAXNB) ++shift;
  const int NB = ((N - 1) >> shift) + 1;

  // adaptive chunk count: smallest nc in {2,4,8,16,32} whose footprint fits ws_size
  int nc = 2;
  for (;;) {
    int cN = (N + nc - 1) / nc;
    size_t sz[15] = {
      (size_t)E * 8 > (size_t)cN * 2048 ? (size_t)E * 8 : (size_t)cN * 2048, // msgx/staging
      (size_t)N * 256,                // h2h
      (size_t)N * 256,                // xh
      (size_t)E * 4,                  // edge_dst
      (size_t)N * 32,                 // ssrc8
      (size_t)N * 16,                 // sdst8h
      (size_t)N * 4, (size_t)N * 4,   // s2src, s2dst
      (size_t)(N + 1) * 4,            // rp
      (size_t)(NB + 1) * 4, (size_t)(NB + 1) * 4, (size_t)(NB + 1) * 4,
      (size_t)NHEADS * 64 * 128 * 2,  // w1t
      (size_t)128 * 512 * 2,          // w2t
      (size_t)16 * 128 * 2            // uv16
    };
    size_t need = 0;
    for (int i = 0; i < 15; ++i) need += (sz[i] + 255) & ~(size_t)255;
    need += 4096;
    if (need <= ws_size || nc >= 32) break;
    nc <<= 1;
  }
  const int chunkN = (N + nc - 1) / nc;

  char* wp = (char*)d_ws;
  size_t off = 0;
  auto mk = [&](size_t bytes) -> void* {
    void* p = wp + off;
    off += (bytes + 255) & ~(size_t)255;
    return p;
  };
  size_t szR0 = (size_t)E * 8;
  if ((size_t)chunkN * 2048 > szR0) szR0 = (size_t)chunkN * 2048;
  f16*  msgx     = (f16*)mk(szR0);                   // aliases CSR staging
  int2* staging  = (int2*)msgx;
  f16*  h2h      = (f16*)mk((size_t)N * 128 * 2);
  f16*  xh       = (f16*)mk((size_t)N * 128 * 2);
  int*  edge_dst = (int*)mk((size_t)E * 4);
  float* ssrc8   = (float*)mk((size_t)N * 8 * 4);
  f16*  sdst8h   = (f16*)mk((size_t)N * 8 * 2);
  float* s2src   = (float*)mk((size_t)N * 4);
  float* s2dst   = (float*)mk((size_t)N * 4);
  int*  rp       = (int*)mk((size_t)(N + 1) * 4);
  int*  bhist    = (int*)mk((size_t)(NB + 1) * 4);
  int*  bbase    = (int*)mk((size_t)(NB + 1) * 4);
  int*  bcur     = (int*)mk((size_t)(NB + 1) * 4);
  f16*  w1t      = (f16*)mk((size_t)NHEADS * 64 * 128 * 2);
  f16*  w2t      = (f16*)mk((size_t)128 * 512 * 2);
  f16*  uv16     = (f16*)mk((size_t)16 * 128 * 2);

  // weight prep, then fused x-convert + scores (needs uv16)
  k_cvt_w<<<516, 256, 0, stream>>>(W1, W2, a1, w1t, w2t, uv16);
  k_prep_x<<<(N + 63) / 64, 256, 0, stream>>>(x, uv16, xh, ssrc8, sdst8h, N);

  // CSR build
  (void)hipMemsetAsync(bhist, 0, (size_t)NB * 4, stream);
  int binBlocks = (E + BIN_EPB - 1) / BIN_EPB;
  k_bhist<<<binBlocks, 256, 0, stream>>>(src, bhist, E, NB, shift);
  k_bscan<<<1, 1024, 0, stream>>>(bhist, bbase, bcur, rp, NB, N, E);
  k_binA<<<binBlocks, 256, 0, stream>>>(src, dstv, bcur, staging, E, NB, shift);
  k_binB<<<NB, 256, 0, stream>>>(staging, bbase, rp, edge_dst, N, shift);

  // layer 1 (all 8 heads) + fused GEMMs, per node-chunk
  for (int ch = 0; ch < nc; ++ch) {
    int c0 = ch * chunkN;
    if (c0 >= N) break;
    int c1 = c0 + chunkN; if (c1 > N) c1 = N;
    int cn = c1 - c0;
    k_aggx<<<(cn + 3) / 4, 256, 0, stream>>>(rp, edge_dst, xh, ssrc8, sdst8h, msgx, c0, c1);
    k_fusedgemm<<<(cn + 63) / 64, 256, 0, stream>>>(msgx, w1t, w2t, a2, h2h,
                                                    s2src, s2dst, c0, c1);
  }

  // layer-2 aggregation
  int wb = (N + 3) / 4;
  k_agg2<<<wb, 256, 0, stream>>>(rp, edge_dst, (const __half*)h2h, s2src, s2dst, x, out, N);
}